// Round 3
// baseline (1541.482 us; speedup 1.0000x reference)
//
#include <hip/hip_runtime.h>

#define DD 128

// ---- bf16 helpers (RNE) ----------------------------------------------------
__device__ inline unsigned short f2bf(float f) {
    unsigned int u = __float_as_uint(f);
    u += 0x7FFFu + ((u >> 16) & 1u);
    return (unsigned short)(u >> 16);
}
__device__ inline float bf2f(unsigned short s) {
    return __uint_as_float(((unsigned int)s) << 16);
}

template <typename T> __device__ inline T cvt(float f);
template <> __device__ inline float cvt<float>(float f) { return f; }
template <> __device__ inline unsigned short cvt<unsigned short>(float f) { return f2bf(f); }

// ---------------------------------------------------------------------------
// Kernel 1: fused node projections.
//   kbuf[n][c]      = (x @ Wk + bk)[n][c]           (type T)
//   qvbuf[n][c]     = (x @ Wq + bq)[n][c]           (type T, c in 0..127)
//   qvbuf[n][128+c] = (x @ Wv + bv)[n][c]           (type T)
//   agg[n][c]       = (x @ Wskip)[n][c]             (fp32, lives in d_out)
// 32-row x-tile in LDS; 256 threads; thread t<128 -> (K,V) col t,
// t>=128 -> (Q,Skip) col t-128. 1 broadcast ds_read_b128 feeds 8 FMAs.
// ---------------------------------------------------------------------------
template <typename T>
__global__ __launch_bounds__(256) void proj_kernel(
    const float* __restrict__ x,
    const float* __restrict__ Wk, const float* __restrict__ bk,
    const float* __restrict__ Wq, const float* __restrict__ bq,
    const float* __restrict__ Wv, const float* __restrict__ bv,
    const float* __restrict__ Ws,
    T* __restrict__ kbuf, T* __restrict__ qvbuf, float* __restrict__ agg,
    int N)
{
    __shared__ float xt[32][DD];
    const int row0 = blockIdx.x * 32;
    const int t = threadIdx.x;

    for (int i = t; i < 32 * (DD / 4); i += 256) {
        const int r  = i >> 5;
        const int c4 = (i & 31) << 2;
        const int gr = row0 + r;
        float4 v = make_float4(0.f, 0.f, 0.f, 0.f);
        if (gr < N) v = *reinterpret_cast<const float4*>(&x[(long)gr * DD + c4]);
        *reinterpret_cast<float4*>(&xt[r][c4]) = v;
    }
    __syncthreads();

    const int c0 = t & 127;
    const int hi = t >> 7;                       // 0 -> (K,V), 1 -> (Q,Skip); wave-uniform
    const float* __restrict__ W0 = hi ? Wq : Wk;
    const float* __restrict__ W1 = hi ? Ws : Wv;
    const float b0 = hi ? bq[c0] : bk[c0];
    const float b1 = hi ? 0.f    : bv[c0];

    float acc0[32], acc1[32];
#pragma unroll
    for (int r = 0; r < 32; ++r) { acc0[r] = 0.f; acc1[r] = 0.f; }

    for (int k4 = 0; k4 < DD; k4 += 4) {
        const float w00 = W0[(k4 + 0) * DD + c0];
        const float w01 = W0[(k4 + 1) * DD + c0];
        const float w02 = W0[(k4 + 2) * DD + c0];
        const float w03 = W0[(k4 + 3) * DD + c0];
        const float w10 = W1[(k4 + 0) * DD + c0];
        const float w11 = W1[(k4 + 1) * DD + c0];
        const float w12 = W1[(k4 + 2) * DD + c0];
        const float w13 = W1[(k4 + 3) * DD + c0];
#pragma unroll
        for (int r = 0; r < 32; ++r) {
            const float4 xv = *reinterpret_cast<const float4*>(&xt[r][k4]);
            acc0[r] = fmaf(xv.x, w00, fmaf(xv.y, w01, fmaf(xv.z, w02, fmaf(xv.w, w03, acc0[r]))));
            acc1[r] = fmaf(xv.x, w10, fmaf(xv.y, w11, fmaf(xv.z, w12, fmaf(xv.w, w13, acc1[r]))));
        }
    }

    // predicated, fully-unrolled stores (static acc indexing only)
#pragma unroll
    for (int r = 0; r < 32; ++r) {
        const long gr = row0 + r;
        if (gr < N) {
            if (hi == 0) {
                kbuf [gr * 128 + c0]       = cvt<T>(acc0[r] + b0);   // K
                qvbuf[gr * 256 + 128 + c0] = cvt<T>(acc1[r] + b1);   // V
            } else {
                qvbuf[gr * 256 + c0]       = cvt<T>(acc0[r] + b0);   // Q
                agg  [gr * 128 + c0]       = acc1[r];                // Skip (no bias)
            }
        }
    }
}

// ---------------------------------------------------------------------------
// Kernel 2: edge phase. One 32-lane group per edge; lane handles 4 channels.
//   msg = relu(k[dst] + q[src]) * v[src];  agg[dst] += msg (native f32 atomic)
// NOTE: edge_index arrives as int32 from the harness (integer inputs -> int*).
// ---------------------------------------------------------------------------
template <typename T>
__global__ __launch_bounds__(256) void edge_kernel(
    const int* __restrict__ ei,
    const T* __restrict__ kbuf, const T* __restrict__ qvbuf,
    float* __restrict__ agg, int E)
{
    const int g = (blockIdx.x << 3) + (threadIdx.x >> 5);   // 32-lane group id
    if (g >= E) return;
    const int lane = threadIdx.x & 31;
    const long src = (long)ei[g];
    const long dst = (long)ei[E + g];
    const int c = lane << 2;

    float kd[4], qs[4], vs[4];
    if constexpr (sizeof(T) == 4) {
        const float4 a = *reinterpret_cast<const float4*>(&kbuf[dst * 128 + c]);
        const float4 b = *reinterpret_cast<const float4*>(&qvbuf[src * 256 + c]);
        const float4 d = *reinterpret_cast<const float4*>(&qvbuf[src * 256 + 128 + c]);
        kd[0] = a.x; kd[1] = a.y; kd[2] = a.z; kd[3] = a.w;
        qs[0] = b.x; qs[1] = b.y; qs[2] = b.z; qs[3] = b.w;
        vs[0] = d.x; vs[1] = d.y; vs[2] = d.z; vs[3] = d.w;
    } else {
        const ushort4 a = *reinterpret_cast<const ushort4*>(&kbuf[dst * 128 + c]);
        const ushort4 b = *reinterpret_cast<const ushort4*>(&qvbuf[src * 256 + c]);
        const ushort4 d = *reinterpret_cast<const ushort4*>(&qvbuf[src * 256 + 128 + c]);
        kd[0] = bf2f(a.x); kd[1] = bf2f(a.y); kd[2] = bf2f(a.z); kd[3] = bf2f(a.w);
        qs[0] = bf2f(b.x); qs[1] = bf2f(b.y); qs[2] = bf2f(b.z); qs[3] = bf2f(b.w);
        vs[0] = bf2f(d.x); vs[1] = bf2f(d.y); vs[2] = bf2f(d.z); vs[3] = bf2f(d.w);
    }

    float* p = agg + dst * 128 + c;
#pragma unroll
    for (int j = 0; j < 4; ++j) {
        const float m = fmaxf(kd[j] + qs[j], 0.f) * vs[j];
        unsafeAtomicAdd(p + j, m);   // native global_atomic_add_f32, fire-and-forget
    }
}

// ---------------------------------------------------------------------------
// Kernel 3: out = leaky_relu(agg + b_conv) @ Wlin + blin
// agg ALIASES out (both in d_out): each block stages its own 32 rows into LDS
// (completes before barrier) and only then overwrites those same rows.
// ---------------------------------------------------------------------------
__global__ __launch_bounds__(64) void out_kernel(
    const float* agg, const float* __restrict__ bconv,
    const float* __restrict__ Wlin, const float* __restrict__ blin,
    float* out, int N)
{
    __shared__ float xt[32][DD];
    const int row0 = blockIdx.x * 32;
    const int t = threadIdx.x;

    for (int i = t; i < 32 * (DD / 4); i += 64) {
        const int r  = i >> 5;
        const int c4 = (i & 31) << 2;
        const int gr = row0 + r;
        float4 a = make_float4(0.f, 0.f, 0.f, 0.f);
        if (gr < N) a = *reinterpret_cast<const float4*>(&agg[(long)gr * DD + c4]);
        const float4 b = *reinterpret_cast<const float4*>(&bconv[c4]);
        float4 v;
        const float x0 = a.x + b.x; v.x = x0 >= 0.f ? x0 : 0.01f * x0;
        const float x1 = a.y + b.y; v.y = x1 >= 0.f ? x1 : 0.01f * x1;
        const float x2 = a.z + b.z; v.z = x2 >= 0.f ? x2 : 0.01f * x2;
        const float x3 = a.w + b.w; v.w = x3 >= 0.f ? x3 : 0.01f * x3;
        *reinterpret_cast<float4*>(&xt[r][c4]) = v;
    }
    __syncthreads();

    const int c0 = t;
    const int c1 = t + 64;
    float acc0[32], acc1[32];
#pragma unroll
    for (int r = 0; r < 32; ++r) { acc0[r] = 0.f; acc1[r] = 0.f; }

    for (int k4 = 0; k4 < DD; k4 += 4) {
        const float w00 = Wlin[(k4 + 0) * DD + c0];
        const float w01 = Wlin[(k4 + 1) * DD + c0];
        const float w02 = Wlin[(k4 + 2) * DD + c0];
        const float w03 = Wlin[(k4 + 3) * DD + c0];
        const float w10 = Wlin[(k4 + 0) * DD + c1];
        const float w11 = Wlin[(k4 + 1) * DD + c1];
        const float w12 = Wlin[(k4 + 2) * DD + c1];
        const float w13 = Wlin[(k4 + 3) * DD + c1];
#pragma unroll
        for (int r = 0; r < 32; ++r) {
            const float4 xv = *reinterpret_cast<const float4*>(&xt[r][k4]);
            acc0[r] = fmaf(xv.x, w00, fmaf(xv.y, w01, fmaf(xv.z, w02, fmaf(xv.w, w03, acc0[r]))));
            acc1[r] = fmaf(xv.x, w10, fmaf(xv.y, w11, fmaf(xv.z, w12, fmaf(xv.w, w13, acc1[r]))));
        }
    }

    const float bb0 = blin[c0];
    const float bb1 = blin[c1];
#pragma unroll
    for (int r = 0; r < 32; ++r) {
        const long gr = row0 + r;
        if (gr < N) {
            out[gr * DD + c0] = acc0[r] + bb0;
            out[gr * DD + c1] = acc1[r] + bb1;
        }
    }
}

// ---------------------------------------------------------------------------
extern "C" void kernel_launch(void* const* d_in, const int* in_sizes, int n_in,
                              void* d_out, int out_size, void* d_ws, size_t ws_size,
                              hipStream_t stream)
{
    const float* x     = (const float*)d_in[0];
    const int*   ei    = (const int*)d_in[1];      // int32! (harness converts int64 -> int32)
    const float* Wk    = (const float*)d_in[2];
    const float* bk    = (const float*)d_in[3];
    const float* Wq    = (const float*)d_in[4];
    const float* bq    = (const float*)d_in[5];
    const float* Wv    = (const float*)d_in[6];
    const float* bv    = (const float*)d_in[7];
    const float* Ws    = (const float*)d_in[8];
    const float* bconv = (const float*)d_in[9];
    const float* Wlin  = (const float*)d_in[10];
    const float* blin  = (const float*)d_in[11];

    const int N = in_sizes[0] / DD;
    const int E = in_sizes[1] / 2;

    float* aggf = (float*)d_out;             // agg lives in d_out (fully overwritten)
    const int nblk = (N + 31) / 32;
    const int eblk = (E + 7) / 8;

    const size_t needF32  = (size_t)N * 384 * sizeof(float);          // k + q|v fp32
    const size_t needBF16 = (size_t)N * 384 * sizeof(unsigned short); // k + q|v bf16

    if (ws_size >= needF32) {
        float* kbuf  = (float*)d_ws;
        float* qvbuf = kbuf + (size_t)N * 128;
        proj_kernel<float><<<nblk, 256, 0, stream>>>(x, Wk, bk, Wq, bq, Wv, bv, Ws,
                                                     kbuf, qvbuf, aggf, N);
        edge_kernel<float><<<eblk, 256, 0, stream>>>(ei, kbuf, qvbuf, aggf, E);
    } else if (ws_size >= needBF16) {
        unsigned short* kbuf  = (unsigned short*)d_ws;
        unsigned short* qvbuf = kbuf + (size_t)N * 128;
        proj_kernel<unsigned short><<<nblk, 256, 0, stream>>>(x, Wk, bk, Wq, bq, Wv, bv, Ws,
                                                              kbuf, qvbuf, aggf, N);
        edge_kernel<unsigned short><<<eblk, 256, 0, stream>>>(ei, kbuf, qvbuf, aggf, E);
    } else {
        // ws too small for any viable plan: emit zeros (diagnostic signature)
        hipMemsetAsync(d_out, 0, (size_t)out_size * sizeof(float), stream);
        return;
    }

    out_kernel<<<nblk, 64, 0, stream>>>(aggf, bconv, Wlin, blin, (float*)d_out, N);
}

// Round 4
// 481.812 us; speedup vs baseline: 3.1993x; 3.1993x over previous
//
#include <hip/hip_runtime.h>

#define DD 128

// ---- bf16 helpers (RNE) ----------------------------------------------------
__device__ inline unsigned short f2bf(float f) {
    unsigned int u = __float_as_uint(f);
    u += 0x7FFFu + ((u >> 16) & 1u);
    return (unsigned short)(u >> 16);
}
__device__ inline float bf2f(unsigned short s) {
    return __uint_as_float(((unsigned int)s) << 16);
}

template <typename T> __device__ inline T cvt(float f);
template <> __device__ inline float cvt<float>(float f) { return f; }
template <> __device__ inline unsigned short cvt<unsigned short>(float f) { return f2bf(f); }

template <typename T> __device__ inline float2 ld2(const T* p);
template <> __device__ inline float2 ld2<float>(const float* p) {
    return *reinterpret_cast<const float2*>(p);
}
template <> __device__ inline float2 ld2<unsigned short>(const unsigned short* p) {
    const ushort2 u = *reinterpret_cast<const ushort2*>(p);
    return make_float2(bf2f(u.x), bf2f(u.y));
}

// ---------------------------------------------------------------------------
// Kernel 1: fused node projections (unchanged from round 3; correct+adequate).
//   kbuf[n][c]      = (x @ Wk + bk)[n][c]   (T)
//   qvbuf[n][c]     = (x @ Wq + bq)[n][c]   (T)   qvbuf[n][128+c] = v
//   agg[n][c]       = (x @ Wskip)[n][c]     (fp32, lives in d_out)
// ---------------------------------------------------------------------------
template <typename T>
__global__ __launch_bounds__(256) void proj_kernel(
    const float* __restrict__ x,
    const float* __restrict__ Wk, const float* __restrict__ bk,
    const float* __restrict__ Wq, const float* __restrict__ bq,
    const float* __restrict__ Wv, const float* __restrict__ bv,
    const float* __restrict__ Ws,
    T* __restrict__ kbuf, T* __restrict__ qvbuf, float* __restrict__ agg,
    int N)
{
    __shared__ float xt[32][DD];
    const int row0 = blockIdx.x * 32;
    const int t = threadIdx.x;

    for (int i = t; i < 32 * (DD / 4); i += 256) {
        const int r  = i >> 5;
        const int c4 = (i & 31) << 2;
        const int gr = row0 + r;
        float4 v = make_float4(0.f, 0.f, 0.f, 0.f);
        if (gr < N) v = *reinterpret_cast<const float4*>(&x[(long)gr * DD + c4]);
        *reinterpret_cast<float4*>(&xt[r][c4]) = v;
    }
    __syncthreads();

    const int c0 = t & 127;
    const int hi = t >> 7;                       // 0 -> (K,V), 1 -> (Q,Skip)
    const float* __restrict__ W0 = hi ? Wq : Wk;
    const float* __restrict__ W1 = hi ? Ws : Wv;
    const float b0 = hi ? bq[c0] : bk[c0];
    const float b1 = hi ? 0.f    : bv[c0];

    float acc0[32], acc1[32];
#pragma unroll
    for (int r = 0; r < 32; ++r) { acc0[r] = 0.f; acc1[r] = 0.f; }

    for (int k4 = 0; k4 < DD; k4 += 4) {
        const float w00 = W0[(k4 + 0) * DD + c0];
        const float w01 = W0[(k4 + 1) * DD + c0];
        const float w02 = W0[(k4 + 2) * DD + c0];
        const float w03 = W0[(k4 + 3) * DD + c0];
        const float w10 = W1[(k4 + 0) * DD + c0];
        const float w11 = W1[(k4 + 1) * DD + c0];
        const float w12 = W1[(k4 + 2) * DD + c0];
        const float w13 = W1[(k4 + 3) * DD + c0];
#pragma unroll
        for (int r = 0; r < 32; ++r) {
            const float4 xv = *reinterpret_cast<const float4*>(&xt[r][k4]);
            acc0[r] = fmaf(xv.x, w00, fmaf(xv.y, w01, fmaf(xv.z, w02, fmaf(xv.w, w03, acc0[r]))));
            acc1[r] = fmaf(xv.x, w10, fmaf(xv.y, w11, fmaf(xv.z, w12, fmaf(xv.w, w13, acc1[r]))));
        }
    }

#pragma unroll
    for (int r = 0; r < 32; ++r) {
        const long gr = row0 + r;
        if (gr < N) {
            if (hi == 0) {
                kbuf [gr * 128 + c0]       = cvt<T>(acc0[r] + b0);
                qvbuf[gr * 256 + 128 + c0] = cvt<T>(acc1[r] + b1);
            } else {
                qvbuf[gr * 256 + c0]       = cvt<T>(acc0[r] + b0);
                agg  [gr * 128 + c0]       = acc1[r];
            }
        }
    }
}

// ---------------------------------------------------------------------------
// CSR construction: zero -> histogram -> block scan -> scatter
// ---------------------------------------------------------------------------
__global__ __launch_bounds__(256) void zero_kernel(int* __restrict__ p, int n) {
    const int i = blockIdx.x * 256 + threadIdx.x;
    if (i < n) p[i] = 0;
}

__global__ __launch_bounds__(256) void hist_kernel(
    const int* __restrict__ ei, int* __restrict__ deg, int E)
{
    const int e = blockIdx.x * 256 + threadIdx.x;
    if (e < E) atomicAdd(&deg[ei[E + e]], 1);   // dst
}

// single 1024-thread block; exclusive scan of deg[0..N) -> off, cursor
__global__ __launch_bounds__(1024) void scan_kernel(
    const int* __restrict__ deg, int* __restrict__ off,
    int* __restrict__ cursor, int N)
{
    __shared__ int sm[1024];
    __shared__ int carry_sm;
    const int t = threadIdx.x;
    if (t == 0) carry_sm = 0;
    __syncthreads();
    for (int base = 0; base < N; base += 1024) {
        const int i = base + t;
        const int v = (i < N) ? deg[i] : 0;
        int x = v;
        sm[t] = x;
        __syncthreads();
#pragma unroll
        for (int ofs = 1; ofs < 1024; ofs <<= 1) {
            const int y = (t >= ofs) ? sm[t - ofs] : 0;
            __syncthreads();
            x += y;
            sm[t] = x;
            __syncthreads();
        }
        const int carry = carry_sm;          // read by all before update below
        if (i < N) {
            const int excl = carry + x - v;
            off[i]    = excl;
            cursor[i] = excl;
        }
        __syncthreads();
        if (t == 1023) carry_sm = carry + x; // inclusive total of this chunk
        __syncthreads();
    }
}

__global__ __launch_bounds__(256) void scatter_kernel(
    const int* __restrict__ ei, int* __restrict__ cursor,
    int* __restrict__ ssrc, int E)
{
    const int e = blockIdx.x * 256 + threadIdx.x;
    if (e >= E) return;
    const int s = ei[e];
    const int d = ei[E + e];
    const int pos = atomicAdd(&cursor[d], 1);
    ssrc[pos] = s;
}

// ---------------------------------------------------------------------------
// Gather kernel: one 64-lane wave per dst node; lane owns channels (2L, 2L+1).
//   agg[n] += sum_{e in CSR[n]} relu(k[n] + q[src]) * v[src]
// No atomics: the wave exclusively owns row n. 4-way edge unroll for ILP.
// ---------------------------------------------------------------------------
template <typename T>
__global__ __launch_bounds__(256) void gather_kernel(
    const int* __restrict__ off, const int* __restrict__ deg,
    const int* __restrict__ ssrc,
    const T* __restrict__ kbuf, const T* __restrict__ qvbuf,
    float* __restrict__ agg, int N)
{
    const int n = blockIdx.x * 4 + (threadIdx.x >> 6);
    if (n >= N) return;
    const int lane = threadIdx.x & 63;
    const int c = lane << 1;

    const int dg = deg[n];
    if (dg == 0) return;                       // agg already holds skip
    const int s0 = off[n];
    const int s1 = s0 + dg;

    const float2 k2 = ld2<T>(&kbuf[(long)n * 128 + c]);
    float a0 = 0.f, a1 = 0.f, b0 = 0.f, b1 = 0.f;

    int e = s0;
    for (; e + 4 <= s1; e += 4) {
        const long sa = ssrc[e + 0];
        const long sb = ssrc[e + 1];
        const long sc = ssrc[e + 2];
        const long sd = ssrc[e + 3];
        const float2 qa = ld2<T>(&qvbuf[sa * 256 + c]);
        const float2 va = ld2<T>(&qvbuf[sa * 256 + 128 + c]);
        const float2 qb = ld2<T>(&qvbuf[sb * 256 + c]);
        const float2 vb = ld2<T>(&qvbuf[sb * 256 + 128 + c]);
        const float2 qc = ld2<T>(&qvbuf[sc * 256 + c]);
        const float2 vc = ld2<T>(&qvbuf[sc * 256 + 128 + c]);
        const float2 qd = ld2<T>(&qvbuf[sd * 256 + c]);
        const float2 vd = ld2<T>(&qvbuf[sd * 256 + 128 + c]);
        a0 = fmaf(fmaxf(k2.x + qa.x, 0.f), va.x, a0);
        a1 = fmaf(fmaxf(k2.y + qa.y, 0.f), va.y, a1);
        b0 = fmaf(fmaxf(k2.x + qb.x, 0.f), vb.x, b0);
        b1 = fmaf(fmaxf(k2.y + qb.y, 0.f), vb.y, b1);
        a0 = fmaf(fmaxf(k2.x + qc.x, 0.f), vc.x, a0);
        a1 = fmaf(fmaxf(k2.y + qc.y, 0.f), vc.y, a1);
        b0 = fmaf(fmaxf(k2.x + qd.x, 0.f), vd.x, b0);
        b1 = fmaf(fmaxf(k2.y + qd.y, 0.f), vd.y, b1);
    }
    for (; e < s1; ++e) {
        const long s = ssrc[e];
        const float2 q = ld2<T>(&qvbuf[s * 256 + c]);
        const float2 v = ld2<T>(&qvbuf[s * 256 + 128 + c]);
        a0 = fmaf(fmaxf(k2.x + q.x, 0.f), v.x, a0);
        a1 = fmaf(fmaxf(k2.y + q.y, 0.f), v.y, a1);
    }

    float2* ap = reinterpret_cast<float2*>(&agg[(long)n * 128 + c]);
    const float2 old = *ap;
    *ap = make_float2(old.x + a0 + b0, old.y + a1 + b1);
}

// ---------------------------------------------------------------------------
// Fallback edge kernel (round-3 atomic path), used only if ws can't fit CSR.
// ---------------------------------------------------------------------------
template <typename T>
__global__ __launch_bounds__(256) void edge_kernel(
    const int* __restrict__ ei,
    const T* __restrict__ kbuf, const T* __restrict__ qvbuf,
    float* __restrict__ agg, int E)
{
    const int g = (blockIdx.x << 3) + (threadIdx.x >> 5);
    if (g >= E) return;
    const int lane = threadIdx.x & 31;
    const long src = (long)ei[g];
    const long dst = (long)ei[E + g];
    const int c = lane << 2;

    float kd[4], qs[4], vs[4];
    if constexpr (sizeof(T) == 4) {
        const float4 a = *reinterpret_cast<const float4*>(&kbuf[dst * 128 + c]);
        const float4 b = *reinterpret_cast<const float4*>(&qvbuf[src * 256 + c]);
        const float4 d = *reinterpret_cast<const float4*>(&qvbuf[src * 256 + 128 + c]);
        kd[0] = a.x; kd[1] = a.y; kd[2] = a.z; kd[3] = a.w;
        qs[0] = b.x; qs[1] = b.y; qs[2] = b.z; qs[3] = b.w;
        vs[0] = d.x; vs[1] = d.y; vs[2] = d.z; vs[3] = d.w;
    } else {
        const ushort4 a = *reinterpret_cast<const ushort4*>(&kbuf[dst * 128 + c]);
        const ushort4 b = *reinterpret_cast<const ushort4*>(&qvbuf[src * 256 + c]);
        const ushort4 d = *reinterpret_cast<const ushort4*>(&qvbuf[src * 256 + 128 + c]);
        kd[0] = bf2f(a.x); kd[1] = bf2f(a.y); kd[2] = bf2f(a.z); kd[3] = bf2f(a.w);
        qs[0] = bf2f(b.x); qs[1] = bf2f(b.y); qs[2] = bf2f(b.z); qs[3] = bf2f(b.w);
        vs[0] = bf2f(d.x); vs[1] = bf2f(d.y); vs[2] = bf2f(d.z); vs[3] = bf2f(d.w);
    }

    float* p = agg + dst * 128 + c;
#pragma unroll
    for (int j = 0; j < 4; ++j) {
        const float m = fmaxf(kd[j] + qs[j], 0.f) * vs[j];
        unsafeAtomicAdd(p + j, m);
    }
}

// ---------------------------------------------------------------------------
// Kernel: out = leaky_relu(agg + b_conv) @ Wlin + blin   (agg aliases out)
// ---------------------------------------------------------------------------
__global__ __launch_bounds__(64) void out_kernel(
    const float* agg, const float* __restrict__ bconv,
    const float* __restrict__ Wlin, const float* __restrict__ blin,
    float* out, int N)
{
    __shared__ float xt[32][DD];
    const int row0 = blockIdx.x * 32;
    const int t = threadIdx.x;

    for (int i = t; i < 32 * (DD / 4); i += 64) {
        const int r  = i >> 5;
        const int c4 = (i & 31) << 2;
        const int gr = row0 + r;
        float4 a = make_float4(0.f, 0.f, 0.f, 0.f);
        if (gr < N) a = *reinterpret_cast<const float4*>(&agg[(long)gr * DD + c4]);
        const float4 b = *reinterpret_cast<const float4*>(&bconv[c4]);
        float4 v;
        const float x0 = a.x + b.x; v.x = x0 >= 0.f ? x0 : 0.01f * x0;
        const float x1 = a.y + b.y; v.y = x1 >= 0.f ? x1 : 0.01f * x1;
        const float x2 = a.z + b.z; v.z = x2 >= 0.f ? x2 : 0.01f * x2;
        const float x3 = a.w + b.w; v.w = x3 >= 0.f ? x3 : 0.01f * x3;
        *reinterpret_cast<float4*>(&xt[r][c4]) = v;
    }
    __syncthreads();

    const int c0 = t;
    const int c1 = t + 64;
    float acc0[32], acc1[32];
#pragma unroll
    for (int r = 0; r < 32; ++r) { acc0[r] = 0.f; acc1[r] = 0.f; }

    for (int k4 = 0; k4 < DD; k4 += 4) {
        const float w00 = Wlin[(k4 + 0) * DD + c0];
        const float w01 = Wlin[(k4 + 1) * DD + c0];
        const float w02 = Wlin[(k4 + 2) * DD + c0];
        const float w03 = Wlin[(k4 + 3) * DD + c0];
        const float w10 = Wlin[(k4 + 0) * DD + c1];
        const float w11 = Wlin[(k4 + 1) * DD + c1];
        const float w12 = Wlin[(k4 + 2) * DD + c1];
        const float w13 = Wlin[(k4 + 3) * DD + c1];
#pragma unroll
        for (int r = 0; r < 32; ++r) {
            const float4 xv = *reinterpret_cast<const float4*>(&xt[r][k4]);
            acc0[r] = fmaf(xv.x, w00, fmaf(xv.y, w01, fmaf(xv.z, w02, fmaf(xv.w, w03, acc0[r]))));
            acc1[r] = fmaf(xv.x, w10, fmaf(xv.y, w11, fmaf(xv.z, w12, fmaf(xv.w, w13, acc1[r]))));
        }
    }

    const float bb0 = blin[c0];
    const float bb1 = blin[c1];
#pragma unroll
    for (int r = 0; r < 32; ++r) {
        const long gr = row0 + r;
        if (gr < N) {
            out[gr * DD + c0] = acc0[r] + bb0;
            out[gr * DD + c1] = acc1[r] + bb1;
        }
    }
}

// ---------------------------------------------------------------------------
extern "C" void kernel_launch(void* const* d_in, const int* in_sizes, int n_in,
                              void* d_out, int out_size, void* d_ws, size_t ws_size,
                              hipStream_t stream)
{
    const float* x     = (const float*)d_in[0];
    const int*   ei    = (const int*)d_in[1];      // int32 (harness converts int64 -> int32)
    const float* Wk    = (const float*)d_in[2];
    const float* bk    = (const float*)d_in[3];
    const float* Wq    = (const float*)d_in[4];
    const float* bq    = (const float*)d_in[5];
    const float* Wv    = (const float*)d_in[6];
    const float* bv    = (const float*)d_in[7];
    const float* Ws    = (const float*)d_in[8];
    const float* bconv = (const float*)d_in[9];
    const float* Wlin  = (const float*)d_in[10];
    const float* blin  = (const float*)d_in[11];

    const int N = in_sizes[0] / DD;
    const int E = in_sizes[1] / 2;

    float* aggf = (float*)d_out;                 // agg lives in d_out
    const int nblk  = (N + 31) / 32;
    const int eblk1 = (E + 255) / 256;
    const int nblk1 = (N + 255) / 256;
    const int gblk  = (N + 3) / 4;

    // CSR region: deg | off | cursor | ssrc  (rounded to 16B)
    size_t csr_ints = (size_t)3 * N + E;
    csr_ints = (csr_ints + 3) & ~(size_t)3;
    const size_t csr_bytes = csr_ints * sizeof(int);

    const size_t projF32  = (size_t)N * 384 * sizeof(float);
    const size_t projBF16 = (size_t)N * 384 * sizeof(unsigned short);

    if (ws_size >= csr_bytes + projF32) {
        int* deg    = (int*)d_ws;
        int* off    = deg + N;
        int* cursor = off + N;
        int* ssrc   = cursor + N;
        float* kbuf  = (float*)((char*)d_ws + csr_bytes);
        float* qvbuf = kbuf + (size_t)N * 128;

        proj_kernel<float><<<nblk, 256, 0, stream>>>(x, Wk, bk, Wq, bq, Wv, bv, Ws,
                                                     kbuf, qvbuf, aggf, N);
        zero_kernel<<<nblk1, 256, 0, stream>>>(deg, N);
        hist_kernel<<<eblk1, 256, 0, stream>>>(ei, deg, E);
        scan_kernel<<<1, 1024, 0, stream>>>(deg, off, cursor, N);
        scatter_kernel<<<eblk1, 256, 0, stream>>>(ei, cursor, ssrc, E);
        gather_kernel<float><<<gblk, 256, 0, stream>>>(off, deg, ssrc, kbuf, qvbuf, aggf, N);
    } else if (ws_size >= csr_bytes + projBF16) {
        int* deg    = (int*)d_ws;
        int* off    = deg + N;
        int* cursor = off + N;
        int* ssrc   = cursor + N;
        unsigned short* kbuf  = (unsigned short*)((char*)d_ws + csr_bytes);
        unsigned short* qvbuf = kbuf + (size_t)N * 128;

        proj_kernel<unsigned short><<<nblk, 256, 0, stream>>>(x, Wk, bk, Wq, bq, Wv, bv, Ws,
                                                              kbuf, qvbuf, aggf, N);
        zero_kernel<<<nblk1, 256, 0, stream>>>(deg, N);
        hist_kernel<<<eblk1, 256, 0, stream>>>(ei, deg, E);
        scan_kernel<<<1, 1024, 0, stream>>>(deg, off, cursor, N);
        scatter_kernel<<<eblk1, 256, 0, stream>>>(ei, cursor, ssrc, E);
        gather_kernel<unsigned short><<<gblk, 256, 0, stream>>>(off, deg, ssrc, kbuf, qvbuf, aggf, N);
    } else if (ws_size >= projBF16) {
        // round-3 fallback: bf16 + fp32 atomics
        unsigned short* kbuf  = (unsigned short*)d_ws;
        unsigned short* qvbuf = kbuf + (size_t)N * 128;
        const int eblk8 = (E + 7) / 8;
        proj_kernel<unsigned short><<<nblk, 256, 0, stream>>>(x, Wk, bk, Wq, bq, Wv, bv, Ws,
                                                              kbuf, qvbuf, aggf, N);
        edge_kernel<unsigned short><<<eblk8, 256, 0, stream>>>(ei, kbuf, qvbuf, aggf, E);
    } else {
        hipMemsetAsync(d_out, 0, (size_t)out_size * sizeof(float), stream);
        return;
    }

    out_kernel<<<nblk, 64, 0, stream>>>(aggf, bconv, Wlin, blin, (float*)d_out, N);
}

// Round 5
// 400.698 us; speedup vs baseline: 3.8470x; 1.2024x over previous
//
#include <hip/hip_runtime.h>

#define DD 128

// ---- bf16 helpers (RNE) ----------------------------------------------------
__device__ inline unsigned short f2bf(float f) {
    unsigned int u = __float_as_uint(f);
    u += 0x7FFFu + ((u >> 16) & 1u);
    return (unsigned short)(u >> 16);
}
__device__ inline float bf2f(unsigned short s) {
    return __uint_as_float(((unsigned int)s) << 16);
}

template <typename T> __device__ inline T cvt(float f);
template <> __device__ inline float cvt<float>(float f) { return f; }
template <> __device__ inline unsigned short cvt<unsigned short>(float f) { return f2bf(f); }

template <typename T> __device__ inline float2 ld2(const T* p);
template <> __device__ inline float2 ld2<float>(const float* p) {
    return *reinterpret_cast<const float2*>(p);
}
template <> __device__ inline float2 ld2<unsigned short>(const unsigned short* p) {
    const ushort2 u = *reinterpret_cast<const ushort2*>(p);
    return make_float2(bf2f(u.x), bf2f(u.y));
}

// ---------------------------------------------------------------------------
// Kernel 1: fused node projections (unchanged; 133us, 31% of fp32 peak).
// ---------------------------------------------------------------------------
template <typename T>
__global__ __launch_bounds__(256) void proj_kernel(
    const float* __restrict__ x,
    const float* __restrict__ Wk, const float* __restrict__ bk,
    const float* __restrict__ Wq, const float* __restrict__ bq,
    const float* __restrict__ Wv, const float* __restrict__ bv,
    const float* __restrict__ Ws,
    T* __restrict__ kbuf, T* __restrict__ qvbuf, float* __restrict__ agg,
    int N)
{
    __shared__ float xt[32][DD];
    const int row0 = blockIdx.x * 32;
    const int t = threadIdx.x;

    for (int i = t; i < 32 * (DD / 4); i += 256) {
        const int r  = i >> 5;
        const int c4 = (i & 31) << 2;
        const int gr = row0 + r;
        float4 v = make_float4(0.f, 0.f, 0.f, 0.f);
        if (gr < N) v = *reinterpret_cast<const float4*>(&x[(long)gr * DD + c4]);
        *reinterpret_cast<float4*>(&xt[r][c4]) = v;
    }
    __syncthreads();

    const int c0 = t & 127;
    const int hi = t >> 7;                       // 0 -> (K,V), 1 -> (Q,Skip)
    const float* __restrict__ W0 = hi ? Wq : Wk;
    const float* __restrict__ W1 = hi ? Ws : Wv;
    const float b0 = hi ? bq[c0] : bk[c0];
    const float b1 = hi ? 0.f    : bv[c0];

    float acc0[32], acc1[32];
#pragma unroll
    for (int r = 0; r < 32; ++r) { acc0[r] = 0.f; acc1[r] = 0.f; }

    for (int k4 = 0; k4 < DD; k4 += 4) {
        const float w00 = W0[(k4 + 0) * DD + c0];
        const float w01 = W0[(k4 + 1) * DD + c0];
        const float w02 = W0[(k4 + 2) * DD + c0];
        const float w03 = W0[(k4 + 3) * DD + c0];
        const float w10 = W1[(k4 + 0) * DD + c0];
        const float w11 = W1[(k4 + 1) * DD + c0];
        const float w12 = W1[(k4 + 2) * DD + c0];
        const float w13 = W1[(k4 + 3) * DD + c0];
#pragma unroll
        for (int r = 0; r < 32; ++r) {
            const float4 xv = *reinterpret_cast<const float4*>(&xt[r][k4]);
            acc0[r] = fmaf(xv.x, w00, fmaf(xv.y, w01, fmaf(xv.z, w02, fmaf(xv.w, w03, acc0[r]))));
            acc1[r] = fmaf(xv.x, w10, fmaf(xv.y, w11, fmaf(xv.z, w12, fmaf(xv.w, w13, acc1[r]))));
        }
    }

#pragma unroll
    for (int r = 0; r < 32; ++r) {
        const long gr = row0 + r;
        if (gr < N) {
            if (hi == 0) {
                kbuf [gr * 128 + c0]       = cvt<T>(acc0[r] + b0);
                qvbuf[gr * 256 + 128 + c0] = cvt<T>(acc1[r] + b1);
            } else {
                qvbuf[gr * 256 + c0]       = cvt<T>(acc0[r] + b0);
                agg  [gr * 128 + c0]       = acc1[r];
            }
        }
    }
}

// ---------------------------------------------------------------------------
// CSR construction: zero -> histogram -> 3-phase multi-block scan -> scatter
// (round 4 used a single-block scan: ~49 sequential chunks on ONE CU, ~140us.
//  This replaces it with parallel per-chunk scans + a tiny top-level scan.)
// ---------------------------------------------------------------------------
__global__ __launch_bounds__(256) void zero_kernel(int* __restrict__ p, int n) {
    const int i = blockIdx.x * 256 + threadIdx.x;
    if (i < n) p[i] = 0;
}

__global__ __launch_bounds__(256) void hist_kernel(
    const int* __restrict__ ei, int* __restrict__ deg, int E)
{
    const int e = blockIdx.x * 256 + threadIdx.x;
    if (e < E) atomicAdd(&deg[ei[E + e]], 1);   // dst
}

// Phase A: each 1024-block scans its chunk; off[i] = exclusive-within-chunk,
// bsum[b] = chunk total.
__global__ __launch_bounds__(1024) void scanA_kernel(
    const int* __restrict__ deg, int* __restrict__ off,
    int* __restrict__ bsum, int N)
{
    __shared__ int sm[1024];
    const int t = threadIdx.x;
    const int i = blockIdx.x * 1024 + t;
    const int v = (i < N) ? deg[i] : 0;
    int x = v;
    sm[t] = x;
    __syncthreads();
#pragma unroll
    for (int ofs = 1; ofs < 1024; ofs <<= 1) {
        const int y = (t >= ofs) ? sm[t - ofs] : 0;
        __syncthreads();
        x += y;
        sm[t] = x;
        __syncthreads();
    }
    if (i < N) off[i] = x - v;
    if (t == 1023) bsum[blockIdx.x] = x;
}

// Phase B: one block, exclusive scan of nb (<=1024) chunk totals in place.
__global__ __launch_bounds__(1024) void scanB_kernel(int* __restrict__ bsum, int nb)
{
    __shared__ int sm[1024];
    const int t = threadIdx.x;
    const int v = (t < nb) ? bsum[t] : 0;
    int x = v;
    sm[t] = x;
    __syncthreads();
#pragma unroll
    for (int ofs = 1; ofs < 1024; ofs <<= 1) {
        const int y = (t >= ofs) ? sm[t - ofs] : 0;
        __syncthreads();
        x += y;
        sm[t] = x;
        __syncthreads();
    }
    if (t < nb) bsum[t] = x - v;    // exclusive
}

// Phase C: add chunk offsets; produce final off + cursor copy.
__global__ __launch_bounds__(256) void scanC_kernel(
    int* __restrict__ off, int* __restrict__ cursor,
    const int* __restrict__ bsum, int N)
{
    const int i = blockIdx.x * 256 + threadIdx.x;
    if (i < N) {
        const int o = off[i] + bsum[i >> 10];
        off[i]    = o;
        cursor[i] = o;
    }
}

__global__ __launch_bounds__(256) void scatter_kernel(
    const int* __restrict__ ei, int* __restrict__ cursor,
    int* __restrict__ ssrc, int E)
{
    const int e = blockIdx.x * 256 + threadIdx.x;
    if (e >= E) return;
    const int s = ei[e];
    const int d = ei[E + e];
    const int pos = atomicAdd(&cursor[d], 1);
    ssrc[pos] = s;
}

// ---------------------------------------------------------------------------
// Gather kernel: one 64-lane wave per dst node (unchanged).
// ---------------------------------------------------------------------------
template <typename T>
__global__ __launch_bounds__(256) void gather_kernel(
    const int* __restrict__ off, const int* __restrict__ deg,
    const int* __restrict__ ssrc,
    const T* __restrict__ kbuf, const T* __restrict__ qvbuf,
    float* __restrict__ agg, int N)
{
    const int n = blockIdx.x * 4 + (threadIdx.x >> 6);
    if (n >= N) return;
    const int lane = threadIdx.x & 63;
    const int c = lane << 1;

    const int dg = deg[n];
    if (dg == 0) return;
    const int s0 = off[n];
    const int s1 = s0 + dg;

    const float2 k2 = ld2<T>(&kbuf[(long)n * 128 + c]);
    float a0 = 0.f, a1 = 0.f, b0 = 0.f, b1 = 0.f;

    int e = s0;
    for (; e + 4 <= s1; e += 4) {
        const long sa = ssrc[e + 0];
        const long sb = ssrc[e + 1];
        const long sc = ssrc[e + 2];
        const long sd = ssrc[e + 3];
        const float2 qa = ld2<T>(&qvbuf[sa * 256 + c]);
        const float2 va = ld2<T>(&qvbuf[sa * 256 + 128 + c]);
        const float2 qb = ld2<T>(&qvbuf[sb * 256 + c]);
        const float2 vb = ld2<T>(&qvbuf[sb * 256 + 128 + c]);
        const float2 qc = ld2<T>(&qvbuf[sc * 256 + c]);
        const float2 vc = ld2<T>(&qvbuf[sc * 256 + 128 + c]);
        const float2 qd = ld2<T>(&qvbuf[sd * 256 + c]);
        const float2 vd = ld2<T>(&qvbuf[sd * 256 + 128 + c]);
        a0 = fmaf(fmaxf(k2.x + qa.x, 0.f), va.x, a0);
        a1 = fmaf(fmaxf(k2.y + qa.y, 0.f), va.y, a1);
        b0 = fmaf(fmaxf(k2.x + qb.x, 0.f), vb.x, b0);
        b1 = fmaf(fmaxf(k2.y + qb.y, 0.f), vb.y, b1);
        a0 = fmaf(fmaxf(k2.x + qc.x, 0.f), vc.x, a0);
        a1 = fmaf(fmaxf(k2.y + qc.y, 0.f), vc.y, a1);
        b0 = fmaf(fmaxf(k2.x + qd.x, 0.f), vd.x, b0);
        b1 = fmaf(fmaxf(k2.y + qd.y, 0.f), vd.y, b1);
    }
    for (; e < s1; ++e) {
        const long s = ssrc[e];
        const float2 q = ld2<T>(&qvbuf[s * 256 + c]);
        const float2 v = ld2<T>(&qvbuf[s * 256 + 128 + c]);
        a0 = fmaf(fmaxf(k2.x + q.x, 0.f), v.x, a0);
        a1 = fmaf(fmaxf(k2.y + q.y, 0.f), v.y, a1);
    }

    float2* ap = reinterpret_cast<float2*>(&agg[(long)n * 128 + c]);
    const float2 old = *ap;
    *ap = make_float2(old.x + a0 + b0, old.y + a1 + b1);
}

// ---------------------------------------------------------------------------
// Fallback edge kernel (atomic path) — only if ws can't fit CSR.
// ---------------------------------------------------------------------------
template <typename T>
__global__ __launch_bounds__(256) void edge_kernel(
    const int* __restrict__ ei,
    const T* __restrict__ kbuf, const T* __restrict__ qvbuf,
    float* __restrict__ agg, int E)
{
    const int g = (blockIdx.x << 3) + (threadIdx.x >> 5);
    if (g >= E) return;
    const int lane = threadIdx.x & 31;
    const long src = (long)ei[g];
    const long dst = (long)ei[E + g];
    const int c = lane << 2;

    float kd[4], qs[4], vs[4];
    if constexpr (sizeof(T) == 4) {
        const float4 a = *reinterpret_cast<const float4*>(&kbuf[dst * 128 + c]);
        const float4 b = *reinterpret_cast<const float4*>(&qvbuf[src * 256 + c]);
        const float4 d = *reinterpret_cast<const float4*>(&qvbuf[src * 256 + 128 + c]);
        kd[0] = a.x; kd[1] = a.y; kd[2] = a.z; kd[3] = a.w;
        qs[0] = b.x; qs[1] = b.y; qs[2] = b.z; qs[3] = b.w;
        vs[0] = d.x; vs[1] = d.y; vs[2] = d.z; vs[3] = d.w;
    } else {
        const ushort4 a = *reinterpret_cast<const ushort4*>(&kbuf[dst * 128 + c]);
        const ushort4 b = *reinterpret_cast<const ushort4*>(&qvbuf[src * 256 + c]);
        const ushort4 d = *reinterpret_cast<const ushort4*>(&qvbuf[src * 256 + 128 + c]);
        kd[0] = bf2f(a.x); kd[1] = bf2f(a.y); kd[2] = bf2f(a.z); kd[3] = bf2f(a.w);
        qs[0] = bf2f(b.x); qs[1] = bf2f(b.y); qs[2] = bf2f(b.z); qs[3] = bf2f(b.w);
        vs[0] = bf2f(d.x); vs[1] = bf2f(d.y); vs[2] = bf2f(d.z); vs[3] = bf2f(d.w);
    }

    float* p = agg + dst * 128 + c;
#pragma unroll
    for (int j = 0; j < 4; ++j) {
        const float m = fmaxf(kd[j] + qs[j], 0.f) * vs[j];
        unsafeAtomicAdd(p + j, m);
    }
}

// ---------------------------------------------------------------------------
// Kernel: out = leaky_relu(agg + b_conv) @ Wlin + blin   (agg aliases out)
// ---------------------------------------------------------------------------
__global__ __launch_bounds__(64) void out_kernel(
    const float* agg, const float* __restrict__ bconv,
    const float* __restrict__ Wlin, const float* __restrict__ blin,
    float* out, int N)
{
    __shared__ float xt[32][DD];
    const int row0 = blockIdx.x * 32;
    const int t = threadIdx.x;

    for (int i = t; i < 32 * (DD / 4); i += 64) {
        const int r  = i >> 5;
        const int c4 = (i & 31) << 2;
        const int gr = row0 + r;
        float4 a = make_float4(0.f, 0.f, 0.f, 0.f);
        if (gr < N) a = *reinterpret_cast<const float4*>(&agg[(long)gr * DD + c4]);
        const float4 b = *reinterpret_cast<const float4*>(&bconv[c4]);
        float4 v;
        const float x0 = a.x + b.x; v.x = x0 >= 0.f ? x0 : 0.01f * x0;
        const float x1 = a.y + b.y; v.y = x1 >= 0.f ? x1 : 0.01f * x1;
        const float x2 = a.z + b.z; v.z = x2 >= 0.f ? x2 : 0.01f * x2;
        const float x3 = a.w + b.w; v.w = x3 >= 0.f ? x3 : 0.01f * x3;
        *reinterpret_cast<float4*>(&xt[r][c4]) = v;
    }
    __syncthreads();

    const int c0 = t;
    const int c1 = t + 64;
    float acc0[32], acc1[32];
#pragma unroll
    for (int r = 0; r < 32; ++r) { acc0[r] = 0.f; acc1[r] = 0.f; }

    for (int k4 = 0; k4 < DD; k4 += 4) {
        const float w00 = Wlin[(k4 + 0) * DD + c0];
        const float w01 = Wlin[(k4 + 1) * DD + c0];
        const float w02 = Wlin[(k4 + 2) * DD + c0];
        const float w03 = Wlin[(k4 + 3) * DD + c0];
        const float w10 = Wlin[(k4 + 0) * DD + c1];
        const float w11 = Wlin[(k4 + 1) * DD + c1];
        const float w12 = Wlin[(k4 + 2) * DD + c1];
        const float w13 = Wlin[(k4 + 3) * DD + c1];
#pragma unroll
        for (int r = 0; r < 32; ++r) {
            const float4 xv = *reinterpret_cast<const float4*>(&xt[r][k4]);
            acc0[r] = fmaf(xv.x, w00, fmaf(xv.y, w01, fmaf(xv.z, w02, fmaf(xv.w, w03, acc0[r]))));
            acc1[r] = fmaf(xv.x, w10, fmaf(xv.y, w11, fmaf(xv.z, w12, fmaf(xv.w, w13, acc1[r]))));
        }
    }

    const float bb0 = blin[c0];
    const float bb1 = blin[c1];
#pragma unroll
    for (int r = 0; r < 32; ++r) {
        const long gr = row0 + r;
        if (gr < N) {
            out[gr * DD + c0] = acc0[r] + bb0;
            out[gr * DD + c1] = acc1[r] + bb1;
        }
    }
}

// ---------------------------------------------------------------------------
extern "C" void kernel_launch(void* const* d_in, const int* in_sizes, int n_in,
                              void* d_out, int out_size, void* d_ws, size_t ws_size,
                              hipStream_t stream)
{
    const float* x     = (const float*)d_in[0];
    const int*   ei    = (const int*)d_in[1];      // int32 (harness converts int64 -> int32)
    const float* Wk    = (const float*)d_in[2];
    const float* bk    = (const float*)d_in[3];
    const float* Wq    = (const float*)d_in[4];
    const float* bq    = (const float*)d_in[5];
    const float* Wv    = (const float*)d_in[6];
    const float* bv    = (const float*)d_in[7];
    const float* Ws    = (const float*)d_in[8];
    const float* bconv = (const float*)d_in[9];
    const float* Wlin  = (const float*)d_in[10];
    const float* blin  = (const float*)d_in[11];

    const int N = in_sizes[0] / DD;
    const int E = in_sizes[1] / 2;

    float* aggf = (float*)d_out;                 // agg lives in d_out
    const int nblk  = (N + 31) / 32;
    const int eblk1 = (E + 255) / 256;
    const int nblk1 = (N + 255) / 256;
    const int gblk  = (N + 3) / 4;
    const int nchunks = (N + 1023) / 1024;       // <= 1024 required by scanB

    // CSR region: deg | off | cursor | bsum(nchunks, padded) | ssrc
    const int bsum_pad = (nchunks + 255) & ~255;
    size_t csr_ints = (size_t)3 * N + bsum_pad + E;
    csr_ints = (csr_ints + 3) & ~(size_t)3;
    const size_t csr_bytes = csr_ints * sizeof(int);

    const size_t projF32  = (size_t)N * 384 * sizeof(float);
    const size_t projBF16 = (size_t)N * 384 * sizeof(unsigned short);

    if (ws_size >= csr_bytes + projF32) {
        int* deg    = (int*)d_ws;
        int* off    = deg + N;
        int* cursor = off + N;
        int* bsum   = cursor + N;
        int* ssrc   = bsum + bsum_pad;
        float* kbuf  = (float*)((char*)d_ws + csr_bytes);
        float* qvbuf = kbuf + (size_t)N * 128;

        proj_kernel<float><<<nblk, 256, 0, stream>>>(x, Wk, bk, Wq, bq, Wv, bv, Ws,
                                                     kbuf, qvbuf, aggf, N);
        zero_kernel<<<nblk1, 256, 0, stream>>>(deg, N);
        hist_kernel<<<eblk1, 256, 0, stream>>>(ei, deg, E);
        scanA_kernel<<<nchunks, 1024, 0, stream>>>(deg, off, bsum, N);
        scanB_kernel<<<1, 1024, 0, stream>>>(bsum, nchunks);
        scanC_kernel<<<nblk1, 256, 0, stream>>>(off, cursor, bsum, N);
        scatter_kernel<<<eblk1, 256, 0, stream>>>(ei, cursor, ssrc, E);
        gather_kernel<float><<<gblk, 256, 0, stream>>>(off, deg, ssrc, kbuf, qvbuf, aggf, N);
    } else if (ws_size >= csr_bytes + projBF16) {
        int* deg    = (int*)d_ws;
        int* off    = deg + N;
        int* cursor = off + N;
        int* bsum   = cursor + N;
        int* ssrc   = bsum + bsum_pad;
        unsigned short* kbuf  = (unsigned short*)((char*)d_ws + csr_bytes);
        unsigned short* qvbuf = kbuf + (size_t)N * 128;

        proj_kernel<unsigned short><<<nblk, 256, 0, stream>>>(x, Wk, bk, Wq, bq, Wv, bv, Ws,
                                                              kbuf, qvbuf, aggf, N);
        zero_kernel<<<nblk1, 256, 0, stream>>>(deg, N);
        hist_kernel<<<eblk1, 256, 0, stream>>>(ei, deg, E);
        scanA_kernel<<<nchunks, 1024, 0, stream>>>(deg, off, bsum, N);
        scanB_kernel<<<1, 1024, 0, stream>>>(bsum, nchunks);
        scanC_kernel<<<nblk1, 256, 0, stream>>>(off, cursor, bsum, N);
        scatter_kernel<<<eblk1, 256, 0, stream>>>(ei, cursor, ssrc, E);
        gather_kernel<unsigned short><<<gblk, 256, 0, stream>>>(off, deg, ssrc, kbuf, qvbuf, aggf, N);
    } else if (ws_size >= projBF16) {
        unsigned short* kbuf  = (unsigned short*)d_ws;
        unsigned short* qvbuf = kbuf + (size_t)N * 128;
        const int eblk8 = (E + 7) / 8;
        proj_kernel<unsigned short><<<nblk, 256, 0, stream>>>(x, Wk, bk, Wq, bq, Wv, bv, Ws,
                                                              kbuf, qvbuf, aggf, N);
        edge_kernel<unsigned short><<<eblk8, 256, 0, stream>>>(ei, kbuf, qvbuf, aggf, E);
    } else {
        hipMemsetAsync(d_out, 0, (size_t)out_size * sizeof(float), stream);
        return;
    }

    out_kernel<<<nblk, 64, 0, stream>>>(aggf, bconv, Wlin, blin, (float*)d_out, N);
}

// Round 6
// 398.694 us; speedup vs baseline: 3.8663x; 1.0050x over previous
//
#include <hip/hip_runtime.h>

#define DD 128

typedef __attribute__((ext_vector_type(8))) short bf16x8;
typedef __attribute__((ext_vector_type(4))) float f32x4;

// ---- bf16 helpers (RNE) ----------------------------------------------------
__device__ inline unsigned short f2bf(float f) {
    unsigned int u = __float_as_uint(f);
    u += 0x7FFFu + ((u >> 16) & 1u);
    return (unsigned short)(u >> 16);
}
__device__ inline float bf2f(unsigned short s) {
    return __uint_as_float(((unsigned int)s) << 16);
}

template <typename T> __device__ inline T cvt(float f);
template <> __device__ inline float cvt<float>(float f) { return f; }
template <> __device__ inline unsigned short cvt<unsigned short>(float f) { return f2bf(f); }

template <typename T> __device__ inline float2 ld2(const T* p);
template <> __device__ inline float2 ld2<float>(const float* p) {
    return *reinterpret_cast<const float2*>(p);
}
template <> __device__ inline float2 ld2<unsigned short>(const unsigned short* p) {
    const ushort2 u = *reinterpret_cast<const ushort2*>(p);
    return make_float2(bf2f(u.x), bf2f(u.y));
}

// ---------------------------------------------------------------------------
// Split-precision MFMA GEMM machinery.
// x (fp32) is split x = hi + lo (both bf16, split exact in fp32);
// W likewise per-fragment. x@W ~= hi@Whi + hi@Wlo + lo@Whi  (error ~2^-17).
// mfma_f32_16x16x32_bf16 layouts (m89-verified D; canonical A/B):
//   A(m,k): lane=(m&15)+16*(k>>3), reg=k&7
//   B(k,n): lane=(n&15)+16*(k>>3), reg=k&7
//   D(m,n): lane=(n&15)+16*(m>>2 within tile), reg=m&3
// Block stages 64 rows x 128 cols of A as hi/lo fragments in LDS.
// ---------------------------------------------------------------------------
template <bool XFORM>
__device__ inline void stage_rows(const float* __restrict__ src,
                                  const float* __restrict__ addv,
                                  int row0, int N, int t,
                                  unsigned short* __restrict__ ldsHi,
                                  unsigned short* __restrict__ ldsLo)
{
    const int m  = t >> 2;            // 0..63 local row
    const int gr = row0 + m;
#pragma unroll
    for (int j = 0; j < 4; ++j) {
        const int o = (t & 3) + j * 4;   // k-octet 0..15
        float v[8];
        if (gr < N) {
            const float4 a = *reinterpret_cast<const float4*>(&src[(long)gr * DD + o * 8]);
            const float4 b = *reinterpret_cast<const float4*>(&src[(long)gr * DD + o * 8 + 4]);
            v[0] = a.x; v[1] = a.y; v[2] = a.z; v[3] = a.w;
            v[4] = b.x; v[5] = b.y; v[6] = b.z; v[7] = b.w;
        } else {
#pragma unroll
            for (int e = 0; e < 8; ++e) v[e] = 0.f;
        }
        if (XFORM) {   // leaky_relu(src + addv) fused into staging
#pragma unroll
            for (int e = 0; e < 8; ++e) {
                const float s = v[e] + addv[o * 8 + e];
                v[e] = s >= 0.f ? s : 0.01f * s;
            }
        }
        bf16x8 h8, l8;
#pragma unroll
        for (int e = 0; e < 8; ++e) {
            const unsigned short h = f2bf(v[e]);
            h8[e] = (short)h;
            l8[e] = (short)f2bf(v[e] - bf2f(h));   // v - hi exact in fp32
        }
        const int rt   = m >> 4;
        const int ks   = o >> 2;
        const int lane = (m & 15) + (o & 3) * 16;
        const int base = ((rt * 4 + ks) * 64 + lane) * 8;
        *reinterpret_cast<bf16x8*>(&ldsHi[base]) = h8;
        *reinterpret_cast<bf16x8*>(&ldsLo[base]) = l8;
    }
}

__device__ inline void load_B_frag(const float* __restrict__ W, int ks, int n0,
                                   int lr, int lg, bf16x8& hi, bf16x8& lo)
{
    const float* p = W + (ks * 32 + lg * 8) * DD + n0 + lr;
#pragma unroll
    for (int r = 0; r < 8; ++r) {
        const float w = p[r * DD];
        const unsigned short h = f2bf(w);
        hi[r] = (short)h;
        lo[r] = (short)f2bf(w - bf2f(h));
    }
}

// ---------------------------------------------------------------------------
// Kernel 1 (MFMA): fused node projections, fp32-equivalent precision.
// 64 rows/block, 256 threads = 4 waves; wave wv owns one 128-col projection:
//   wv=0 -> K(kbuf), 1 -> Q(qvbuf[:128]), 2 -> V(qvbuf[128:]), 3 -> Skip(agg)
// ---------------------------------------------------------------------------
__global__ __launch_bounds__(256) void proj_mfma_kernel(
    const float* __restrict__ x,
    const float* __restrict__ Wk, const float* __restrict__ bk,
    const float* __restrict__ Wq, const float* __restrict__ bq,
    const float* __restrict__ Wv, const float* __restrict__ bv,
    const float* __restrict__ Ws,
    float* __restrict__ kbuf, float* __restrict__ qvbuf, float* __restrict__ agg,
    int N)
{
    __shared__ unsigned short ldsHi[16 * 64 * 8];
    __shared__ unsigned short ldsLo[16 * 64 * 8];
    const int t = threadIdx.x;
    const int row0 = blockIdx.x * 64;

    stage_rows<false>(x, nullptr, row0, N, t, ldsHi, ldsLo);
    __syncthreads();

    const int wv   = t >> 6;
    const int lane = t & 63;
    const int lr = lane & 15;
    const int lg = lane >> 4;
    const float* __restrict__ W = (wv == 0) ? Wk : (wv == 1) ? Wq : (wv == 2) ? Wv : Ws;
    const float* bias = (wv == 0) ? bk : (wv == 1) ? bq : (wv == 2) ? bv : nullptr;

    for (int cc = 0; cc < 2; ++cc) {            // two 64-col chunks
        f32x4 acc[4][4];
#pragma unroll
        for (int rt = 0; rt < 4; ++rt)
#pragma unroll
            for (int ct = 0; ct < 4; ++ct) acc[rt][ct] = (f32x4){0.f, 0.f, 0.f, 0.f};

#pragma unroll
        for (int ks = 0; ks < 4; ++ks) {
            bf16x8 Ahi[4], Alo[4];
#pragma unroll
            for (int rt = 0; rt < 4; ++rt) {
                const int base = ((rt * 4 + ks) * 64 + lane) * 8;
                Ahi[rt] = *reinterpret_cast<const bf16x8*>(&ldsHi[base]);
                Alo[rt] = *reinterpret_cast<const bf16x8*>(&ldsLo[base]);
            }
#pragma unroll
            for (int ct = 0; ct < 4; ++ct) {
                bf16x8 Bhi, Blo;
                load_B_frag(W, ks, cc * 64 + ct * 16, lr, lg, Bhi, Blo);
#pragma unroll
                for (int rt = 0; rt < 4; ++rt) {
                    acc[rt][ct] = __builtin_amdgcn_mfma_f32_16x16x32_bf16(Ahi[rt], Bhi, acc[rt][ct], 0, 0, 0);
                    acc[rt][ct] = __builtin_amdgcn_mfma_f32_16x16x32_bf16(Ahi[rt], Blo, acc[rt][ct], 0, 0, 0);
                    acc[rt][ct] = __builtin_amdgcn_mfma_f32_16x16x32_bf16(Alo[rt], Bhi, acc[rt][ct], 0, 0, 0);
                }
            }
        }
        // epilogue: bias + route to kbuf/qvbuf/agg
#pragma unroll
        for (int ct = 0; ct < 4; ++ct) {
            const int n_l = cc * 64 + ct * 16 + lr;
            const float bv_ = bias ? bias[n_l] : 0.f;
#pragma unroll
            for (int rt = 0; rt < 4; ++rt) {
#pragma unroll
                for (int r = 0; r < 4; ++r) {
                    const int m = row0 + rt * 16 + lg * 4 + r;
                    if (m < N) {
                        const float val = acc[rt][ct][r] + bv_;
                        if      (wv == 0) kbuf [(long)m * 128 + n_l]       = val;
                        else if (wv == 1) qvbuf[(long)m * 256 + n_l]       = val;
                        else if (wv == 2) qvbuf[(long)m * 256 + 128 + n_l] = val;
                        else              agg  [(long)m * 128 + n_l]       = val;
                    }
                }
            }
        }
    }
}

// ---------------------------------------------------------------------------
// Kernel (MFMA): out = leaky_relu(agg + b_conv) @ Wlin + blin
// agg aliases out: block stages its own 64 rows (with fused leaky) into LDS
// before overwriting them. Wave wv owns cols [wv*32, wv*32+32).
// ---------------------------------------------------------------------------
__global__ __launch_bounds__(256) void out_mfma_kernel(
    const float* agg, const float* __restrict__ bconv,
    const float* __restrict__ Wlin, const float* __restrict__ blin,
    float* out, int N)
{
    __shared__ unsigned short ldsHi[16 * 64 * 8];
    __shared__ unsigned short ldsLo[16 * 64 * 8];
    const int t = threadIdx.x;
    const int row0 = blockIdx.x * 64;

    stage_rows<true>(agg, bconv, row0, N, t, ldsHi, ldsLo);
    __syncthreads();

    const int wv   = t >> 6;
    const int lane = t & 63;
    const int lr = lane & 15;
    const int lg = lane >> 4;

    f32x4 acc[4][2];
#pragma unroll
    for (int rt = 0; rt < 4; ++rt)
#pragma unroll
        for (int ct = 0; ct < 2; ++ct) acc[rt][ct] = (f32x4){0.f, 0.f, 0.f, 0.f};

#pragma unroll
    for (int ks = 0; ks < 4; ++ks) {
        bf16x8 Ahi[4], Alo[4];
#pragma unroll
        for (int rt = 0; rt < 4; ++rt) {
            const int base = ((rt * 4 + ks) * 64 + lane) * 8;
            Ahi[rt] = *reinterpret_cast<const bf16x8*>(&ldsHi[base]);
            Alo[rt] = *reinterpret_cast<const bf16x8*>(&ldsLo[base]);
        }
#pragma unroll
        for (int ct = 0; ct < 2; ++ct) {
            bf16x8 Bhi, Blo;
            load_B_frag(Wlin, ks, wv * 32 + ct * 16, lr, lg, Bhi, Blo);
#pragma unroll
            for (int rt = 0; rt < 4; ++rt) {
                acc[rt][ct] = __builtin_amdgcn_mfma_f32_16x16x32_bf16(Ahi[rt], Bhi, acc[rt][ct], 0, 0, 0);
                acc[rt][ct] = __builtin_amdgcn_mfma_f32_16x16x32_bf16(Ahi[rt], Blo, acc[rt][ct], 0, 0, 0);
                acc[rt][ct] = __builtin_amdgcn_mfma_f32_16x16x32_bf16(Alo[rt], Bhi, acc[rt][ct], 0, 0, 0);
            }
        }
    }
#pragma unroll
    for (int ct = 0; ct < 2; ++ct) {
        const int n = wv * 32 + ct * 16 + lr;
        const float bb = blin[n];
#pragma unroll
        for (int rt = 0; rt < 4; ++rt) {
#pragma unroll
            for (int r = 0; r < 4; ++r) {
                const int m = row0 + rt * 16 + lg * 4 + r;
                if (m < N) out[(long)m * 128 + n] = acc[rt][ct][r] + bb;
            }
        }
    }
}

// ---------------------------------------------------------------------------
// VALU proj kernel — kept only for the bf16 low-workspace fallback branch.
// ---------------------------------------------------------------------------
template <typename T>
__global__ __launch_bounds__(256) void proj_kernel(
    const float* __restrict__ x,
    const float* __restrict__ Wk, const float* __restrict__ bk,
    const float* __restrict__ Wq, const float* __restrict__ bq,
    const float* __restrict__ Wv, const float* __restrict__ bv,
    const float* __restrict__ Ws,
    T* __restrict__ kbuf, T* __restrict__ qvbuf, float* __restrict__ agg,
    int N)
{
    __shared__ float xt[32][DD];
    const int row0 = blockIdx.x * 32;
    const int t = threadIdx.x;

    for (int i = t; i < 32 * (DD / 4); i += 256) {
        const int r  = i >> 5;
        const int c4 = (i & 31) << 2;
        const int gr = row0 + r;
        float4 v = make_float4(0.f, 0.f, 0.f, 0.f);
        if (gr < N) v = *reinterpret_cast<const float4*>(&x[(long)gr * DD + c4]);
        *reinterpret_cast<float4*>(&xt[r][c4]) = v;
    }
    __syncthreads();

    const int c0 = t & 127;
    const int hi = t >> 7;
    const float* __restrict__ W0 = hi ? Wq : Wk;
    const float* __restrict__ W1 = hi ? Ws : Wv;
    const float b0 = hi ? bq[c0] : bk[c0];
    const float b1 = hi ? 0.f    : bv[c0];

    float acc0[32], acc1[32];
#pragma unroll
    for (int r = 0; r < 32; ++r) { acc0[r] = 0.f; acc1[r] = 0.f; }

    for (int k4 = 0; k4 < DD; k4 += 4) {
        const float w00 = W0[(k4 + 0) * DD + c0];
        const float w01 = W0[(k4 + 1) * DD + c0];
        const float w02 = W0[(k4 + 2) * DD + c0];
        const float w03 = W0[(k4 + 3) * DD + c0];
        const float w10 = W1[(k4 + 0) * DD + c0];
        const float w11 = W1[(k4 + 1) * DD + c0];
        const float w12 = W1[(k4 + 2) * DD + c0];
        const float w13 = W1[(k4 + 3) * DD + c0];
#pragma unroll
        for (int r = 0; r < 32; ++r) {
            const float4 xv = *reinterpret_cast<const float4*>(&xt[r][k4]);
            acc0[r] = fmaf(xv.x, w00, fmaf(xv.y, w01, fmaf(xv.z, w02, fmaf(xv.w, w03, acc0[r]))));
            acc1[r] = fmaf(xv.x, w10, fmaf(xv.y, w11, fmaf(xv.z, w12, fmaf(xv.w, w13, acc1[r]))));
        }
    }

#pragma unroll
    for (int r = 0; r < 32; ++r) {
        const long gr = row0 + r;
        if (gr < N) {
            if (hi == 0) {
                kbuf [gr * 128 + c0]       = cvt<T>(acc0[r] + b0);
                qvbuf[gr * 256 + 128 + c0] = cvt<T>(acc1[r] + b1);
            } else {
                qvbuf[gr * 256 + c0]       = cvt<T>(acc0[r] + b0);
                agg  [gr * 128 + c0]       = acc1[r];
            }
        }
    }
}

// ---------------------------------------------------------------------------
// CSR construction: zero -> histogram -> 3-phase multi-block scan -> scatter
// ---------------------------------------------------------------------------
__global__ __launch_bounds__(256) void zero_kernel(int* __restrict__ p, int n) {
    const int i = blockIdx.x * 256 + threadIdx.x;
    if (i < n) p[i] = 0;
}

__global__ __launch_bounds__(256) void hist_kernel(
    const int* __restrict__ ei, int* __restrict__ deg, int E)
{
    const int e = blockIdx.x * 256 + threadIdx.x;
    if (e < E) atomicAdd(&deg[ei[E + e]], 1);   // dst
}

__global__ __launch_bounds__(1024) void scanA_kernel(
    const int* __restrict__ deg, int* __restrict__ off,
    int* __restrict__ bsum, int N)
{
    __shared__ int sm[1024];
    const int t = threadIdx.x;
    const int i = blockIdx.x * 1024 + t;
    const int v = (i < N) ? deg[i] : 0;
    int x = v;
    sm[t] = x;
    __syncthreads();
#pragma unroll
    for (int ofs = 1; ofs < 1024; ofs <<= 1) {
        const int y = (t >= ofs) ? sm[t - ofs] : 0;
        __syncthreads();
        x += y;
        sm[t] = x;
        __syncthreads();
    }
    if (i < N) off[i] = x - v;
    if (t == 1023) bsum[blockIdx.x] = x;
}

__global__ __launch_bounds__(1024) void scanB_kernel(int* __restrict__ bsum, int nb)
{
    __shared__ int sm[1024];
    const int t = threadIdx.x;
    const int v = (t < nb) ? bsum[t] : 0;
    int x = v;
    sm[t] = x;
    __syncthreads();
#pragma unroll
    for (int ofs = 1; ofs < 1024; ofs <<= 1) {
        const int y = (t >= ofs) ? sm[t - ofs] : 0;
        __syncthreads();
        x += y;
        sm[t] = x;
        __syncthreads();
    }
    if (t < nb) bsum[t] = x - v;
}

__global__ __launch_bounds__(256) void scanC_kernel(
    int* __restrict__ off, int* __restrict__ cursor,
    const int* __restrict__ bsum, int N)
{
    const int i = blockIdx.x * 256 + threadIdx.x;
    if (i < N) {
        const int o = off[i] + bsum[i >> 10];
        off[i]    = o;
        cursor[i] = o;
    }
}

__global__ __launch_bounds__(256) void scatter_kernel(
    const int* __restrict__ ei, int* __restrict__ cursor,
    int* __restrict__ ssrc, int E)
{
    const int e = blockIdx.x * 256 + threadIdx.x;
    if (e >= E) return;
    const int s = ei[e];
    const int d = ei[E + e];
    const int pos = atomicAdd(&cursor[d], 1);
    ssrc[pos] = s;
}

// ---------------------------------------------------------------------------
// Gather kernel: one 64-lane wave per dst node (unchanged).
// ---------------------------------------------------------------------------
template <typename T>
__global__ __launch_bounds__(256) void gather_kernel(
    const int* __restrict__ off, const int* __restrict__ deg,
    const int* __restrict__ ssrc,
    const T* __restrict__ kbuf, const T* __restrict__ qvbuf,
    float* __restrict__ agg, int N)
{
    const int n = blockIdx.x * 4 + (threadIdx.x >> 6);
    if (n >= N) return;
    const int lane = threadIdx.x & 63;
    const int c = lane << 1;

    const int dg = deg[n];
    if (dg == 0) return;
    const int s0 = off[n];
    const int s1 = s0 + dg;

    const float2 k2 = ld2<T>(&kbuf[(long)n * 128 + c]);
    float a0 = 0.f, a1 = 0.f, b0 = 0.f, b1 = 0.f;

    int e = s0;
    for (; e + 4 <= s1; e += 4) {
        const long sa = ssrc[e + 0];
        const long sb = ssrc[e + 1];
        const long sc = ssrc[e + 2];
        const long sd = ssrc[e + 3];
        const float2 qa = ld2<T>(&qvbuf[sa * 256 + c]);
        const float2 va = ld2<T>(&qvbuf[sa * 256 + 128 + c]);
        const float2 qb = ld2<T>(&qvbuf[sb * 256 + c]);
        const float2 vb = ld2<T>(&qvbuf[sb * 256 + 128 + c]);
        const float2 qc = ld2<T>(&qvbuf[sc * 256 + c]);
        const float2 vc = ld2<T>(&qvbuf[sc * 256 + 128 + c]);
        const float2 qd = ld2<T>(&qvbuf[sd * 256 + c]);
        const float2 vd = ld2<T>(&qvbuf[sd * 256 + 128 + c]);
        a0 = fmaf(fmaxf(k2.x + qa.x, 0.f), va.x, a0);
        a1 = fmaf(fmaxf(k2.y + qa.y, 0.f), va.y, a1);
        b0 = fmaf(fmaxf(k2.x + qb.x, 0.f), vb.x, b0);
        b1 = fmaf(fmaxf(k2.y + qb.y, 0.f), vb.y, b1);
        a0 = fmaf(fmaxf(k2.x + qc.x, 0.f), vc.x, a0);
        a1 = fmaf(fmaxf(k2.y + qc.y, 0.f), vc.y, a1);
        b0 = fmaf(fmaxf(k2.x + qd.x, 0.f), vd.x, b0);
        b1 = fmaf(fmaxf(k2.y + qd.y, 0.f), vd.y, b1);
    }
    for (; e < s1; ++e) {
        const long s = ssrc[e];
        const float2 q = ld2<T>(&qvbuf[s * 256 + c]);
        const float2 v = ld2<T>(&qvbuf[s * 256 + 128 + c]);
        a0 = fmaf(fmaxf(k2.x + q.x, 0.f), v.x, a0);
        a1 = fmaf(fmaxf(k2.y + q.y, 0.f), v.y, a1);
    }

    float2* ap = reinterpret_cast<float2*>(&agg[(long)n * 128 + c]);
    const float2 old = *ap;
    *ap = make_float2(old.x + a0 + b0, old.y + a1 + b1);
}

// ---------------------------------------------------------------------------
// Fallback edge kernel (atomic path) — only if ws can't fit CSR.
// ---------------------------------------------------------------------------
template <typename T>
__global__ __launch_bounds__(256) void edge_kernel(
    const int* __restrict__ ei,
    const T* __restrict__ kbuf, const T* __restrict__ qvbuf,
    float* __restrict__ agg, int E)
{
    const int g = (blockIdx.x << 3) + (threadIdx.x >> 5);
    if (g >= E) return;
    const int lane = threadIdx.x & 31;
    const long src = (long)ei[g];
    const long dst = (long)ei[E + g];
    const int c = lane << 2;

    float kd[4], qs[4], vs[4];
    if constexpr (sizeof(T) == 4) {
        const float4 a = *reinterpret_cast<const float4*>(&kbuf[dst * 128 + c]);
        const float4 b = *reinterpret_cast<const float4*>(&qvbuf[src * 256 + c]);
        const float4 d = *reinterpret_cast<const float4*>(&qvbuf[src * 256 + 128 + c]);
        kd[0] = a.x; kd[1] = a.y; kd[2] = a.z; kd[3] = a.w;
        qs[0] = b.x; qs[1] = b.y; qs[2] = b.z; qs[3] = b.w;
        vs[0] = d.x; vs[1] = d.y; vs[2] = d.z; vs[3] = d.w;
    } else {
        const ushort4 a = *reinterpret_cast<const ushort4*>(&kbuf[dst * 128 + c]);
        const ushort4 b = *reinterpret_cast<const ushort4*>(&qvbuf[src * 256 + c]);
        const ushort4 d = *reinterpret_cast<const ushort4*>(&qvbuf[src * 256 + 128 + c]);
        kd[0] = bf2f(a.x); kd[1] = bf2f(a.y); kd[2] = bf2f(a.z); kd[3] = bf2f(a.w);
        qs[0] = bf2f(b.x); qs[1] = bf2f(b.y); qs[2] = bf2f(b.z); qs[3] = bf2f(b.w);
        vs[0] = bf2f(d.x); vs[1] = bf2f(d.y); vs[2] = bf2f(d.z); vs[3] = bf2f(d.w);
    }

    float* p = agg + dst * 128 + c;
#pragma unroll
    for (int j = 0; j < 4; ++j) {
        const float m = fmaxf(kd[j] + qs[j], 0.f) * vs[j];
        unsafeAtomicAdd(p + j, m);
    }
}

// ---------------------------------------------------------------------------
// VALU out kernel — kept for fallback branches.
// ---------------------------------------------------------------------------
__global__ __launch_bounds__(64) void out_kernel(
    const float* agg, const float* __restrict__ bconv,
    const float* __restrict__ Wlin, const float* __restrict__ blin,
    float* out, int N)
{
    __shared__ float xt[32][DD];
    const int row0 = blockIdx.x * 32;
    const int t = threadIdx.x;

    for (int i = t; i < 32 * (DD / 4); i += 64) {
        const int r  = i >> 5;
        const int c4 = (i & 31) << 2;
        const int gr = row0 + r;
        float4 a = make_float4(0.f, 0.f, 0.f, 0.f);
        if (gr < N) a = *reinterpret_cast<const float4*>(&agg[(long)gr * DD + c4]);
        const float4 b = *reinterpret_cast<const float4*>(&bconv[c4]);
        float4 v;
        const float x0 = a.x + b.x; v.x = x0 >= 0.f ? x0 : 0.01f * x0;
        const float x1 = a.y + b.y; v.y = x1 >= 0.f ? x1 : 0.01f * x1;
        const float x2 = a.z + b.z; v.z = x2 >= 0.f ? x2 : 0.01f * x2;
        const float x3 = a.w + b.w; v.w = x3 >= 0.f ? x3 : 0.01f * x3;
        *reinterpret_cast<float4*>(&xt[r][c4]) = v;
    }
    __syncthreads();

    const int c0 = t;
    const int c1 = t + 64;
    float acc0[32], acc1[32];
#pragma unroll
    for (int r = 0; r < 32; ++r) { acc0[r] = 0.f; acc1[r] = 0.f; }

    for (int k4 = 0; k4 < DD; k4 += 4) {
        const float w00 = Wlin[(k4 + 0) * DD + c0];
        const float w01 = Wlin[(k4 + 1) * DD + c0];
        const float w02 = Wlin[(k4 + 2) * DD + c0];
        const float w03 = Wlin[(k4 + 3) * DD + c0];
        const float w10 = Wlin[(k4 + 0) * DD + c1];
        const float w11 = Wlin[(k4 + 1) * DD + c1];
        const float w12 = Wlin[(k4 + 2) * DD + c1];
        const float w13 = Wlin[(k4 + 3) * DD + c1];
#pragma unroll
        for (int r = 0; r < 32; ++r) {
            const float4 xv = *reinterpret_cast<const float4*>(&xt[r][k4]);
            acc0[r] = fmaf(xv.x, w00, fmaf(xv.y, w01, fmaf(xv.z, w02, fmaf(xv.w, w03, acc0[r]))));
            acc1[r] = fmaf(xv.x, w10, fmaf(xv.y, w11, fmaf(xv.z, w12, fmaf(xv.w, w13, acc1[r]))));
        }
    }

    const float bb0 = blin[c0];
    const float bb1 = blin[c1];
#pragma unroll
    for (int r = 0; r < 32; ++r) {
        const long gr = row0 + r;
        if (gr < N) {
            out[gr * DD + c0] = acc0[r] + bb0;
            out[gr * DD + c1] = acc1[r] + bb1;
        }
    }
}

// ---------------------------------------------------------------------------
extern "C" void kernel_launch(void* const* d_in, const int* in_sizes, int n_in,
                              void* d_out, int out_size, void* d_ws, size_t ws_size,
                              hipStream_t stream)
{
    const float* x     = (const float*)d_in[0];
    const int*   ei    = (const int*)d_in[1];      // int32 (harness converts int64 -> int32)
    const float* Wk    = (const float*)d_in[2];
    const float* bk    = (const float*)d_in[3];
    const float* Wq    = (const float*)d_in[4];
    const float* bq    = (const float*)d_in[5];
    const float* Wv    = (const float*)d_in[6];
    const float* bv    = (const float*)d_in[7];
    const float* Ws    = (const float*)d_in[8];
    const float* bconv = (const float*)d_in[9];
    const float* Wlin  = (const float*)d_in[10];
    const float* blin  = (const float*)d_in[11];

    const int N = in_sizes[0] / DD;
    const int E = in_sizes[1] / 2;

    float* aggf = (float*)d_out;                 // agg lives in d_out
    const int nblk   = (N + 31) / 32;
    const int mblk   = (N + 63) / 64;            // MFMA kernels: 64 rows/block
    const int eblk1  = (E + 255) / 256;
    const int nblk1  = (N + 255) / 256;
    const int gblk   = (N + 3) / 4;
    const int nchunks = (N + 1023) / 1024;

    const int bsum_pad = (nchunks + 255) & ~255;
    size_t csr_ints = (size_t)3 * N + bsum_pad + E;
    csr_ints = (csr_ints + 3) & ~(size_t)3;
    const size_t csr_bytes = csr_ints * sizeof(int);

    const size_t projF32  = (size_t)N * 384 * sizeof(float);
    const size_t projBF16 = (size_t)N * 384 * sizeof(unsigned short);

    if (ws_size >= csr_bytes + projF32) {
        int* deg    = (int*)d_ws;
        int* off    = deg + N;
        int* cursor = off + N;
        int* bsum   = cursor + N;
        int* ssrc   = bsum + bsum_pad;
        float* kbuf  = (float*)((char*)d_ws + csr_bytes);
        float* qvbuf = kbuf + (size_t)N * 128;

        proj_mfma_kernel<<<mblk, 256, 0, stream>>>(x, Wk, bk, Wq, bq, Wv, bv, Ws,
                                                   kbuf, qvbuf, aggf, N);
        zero_kernel<<<nblk1, 256, 0, stream>>>(deg, N);
        hist_kernel<<<eblk1, 256, 0, stream>>>(ei, deg, E);
        scanA_kernel<<<nchunks, 1024, 0, stream>>>(deg, off, bsum, N);
        scanB_kernel<<<1, 1024, 0, stream>>>(bsum, nchunks);
        scanC_kernel<<<nblk1, 256, 0, stream>>>(off, cursor, bsum, N);
        scatter_kernel<<<eblk1, 256, 0, stream>>>(ei, cursor, ssrc, E);
        gather_kernel<float><<<gblk, 256, 0, stream>>>(off, deg, ssrc, kbuf, qvbuf, aggf, N);
        out_mfma_kernel<<<mblk, 256, 0, stream>>>(aggf, bconv, Wlin, blin, (float*)d_out, N);
    } else if (ws_size >= csr_bytes + projBF16) {
        int* deg    = (int*)d_ws;
        int* off    = deg + N;
        int* cursor = off + N;
        int* bsum   = cursor + N;
        int* ssrc   = bsum + bsum_pad;
        unsigned short* kbuf  = (unsigned short*)((char*)d_ws + csr_bytes);
        unsigned short* qvbuf = kbuf + (size_t)N * 128;

        proj_kernel<unsigned short><<<nblk, 256, 0, stream>>>(x, Wk, bk, Wq, bq, Wv, bv, Ws,
                                                              kbuf, qvbuf, aggf, N);
        zero_kernel<<<nblk1, 256, 0, stream>>>(deg, N);
        hist_kernel<<<eblk1, 256, 0, stream>>>(ei, deg, E);
        scanA_kernel<<<nchunks, 1024, 0, stream>>>(deg, off, bsum, N);
        scanB_kernel<<<1, 1024, 0, stream>>>(bsum, nchunks);
        scanC_kernel<<<nblk1, 256, 0, stream>>>(off, cursor, bsum, N);
        scatter_kernel<<<eblk1, 256, 0, stream>>>(ei, cursor, ssrc, E);
        gather_kernel<unsigned short><<<gblk, 256, 0, stream>>>(off, deg, ssrc, kbuf, qvbuf, aggf, N);
        out_kernel<<<nblk, 64, 0, stream>>>(aggf, bconv, Wlin, blin, (float*)d_out, N);
    } else if (ws_size >= projBF16) {
        unsigned short* kbuf  = (unsigned short*)d_ws;
        unsigned short* qvbuf = kbuf + (size_t)N * 128;
        const int eblk8 = (E + 7) / 8;
        proj_kernel<unsigned short><<<nblk, 256, 0, stream>>>(x, Wk, bk, Wq, bq, Wv, bv, Ws,
                                                              kbuf, qvbuf, aggf, N);
        edge_kernel<unsigned short><<<eblk8, 256, 0, stream>>>(ei, kbuf, qvbuf, aggf, E);
        out_kernel<<<nblk, 64, 0, stream>>>(aggf, bconv, Wlin, blin, (float*)d_out, N);
    } else {
        hipMemsetAsync(d_out, 0, (size_t)out_size * sizeof(float), stream);
        return;
    }
}

// Round 7
// 333.396 us; speedup vs baseline: 4.6236x; 1.1959x over previous
//
#include <hip/hip_runtime.h>

#define DD 128

typedef __attribute__((ext_vector_type(8))) short bf16x8;
typedef __attribute__((ext_vector_type(4))) float f32x4;

// ---- bf16 helpers (RNE) ----------------------------------------------------
__device__ inline unsigned short f2bf(float f) {
    unsigned int u = __float_as_uint(f);
    u += 0x7FFFu + ((u >> 16) & 1u);
    return (unsigned short)(u >> 16);
}
__device__ inline float bf2f(unsigned short s) {
    return __uint_as_float(((unsigned int)s) << 16);
}

template <typename T> __device__ inline T cvt(float f);
template <> __device__ inline float cvt<float>(float f) { return f; }
template <> __device__ inline unsigned short cvt<unsigned short>(float f) { return f2bf(f); }

template <typename T> __device__ inline float2 ld2(const T* p);
template <> __device__ inline float2 ld2<float>(const float* p) {
    return *reinterpret_cast<const float2*>(p);
}
template <> __device__ inline float2 ld2<unsigned short>(const unsigned short* p) {
    const ushort2 u = *reinterpret_cast<const ushort2*>(p);
    return make_float2(bf2f(u.x), bf2f(u.y));
}

// ---------------------------------------------------------------------------
// Split-precision MFMA GEMM: x@W ~= hi@Whi + hi@Wlo + lo@Whi (error ~2^-17).
// mfma_f32_16x16x32_bf16 fragment layouts (validated end-to-end in round 6):
//   A(m,k): lane=(m&15)+16*((k>>3)&3), reg=k&7   (k-slice ks=k>>5)
//   B(k,n): lane=(n&15)+16*((k>>3)&3), reg=k&7
//   D(m,n): lane=(n&15)+16*lg, rows lg*4+r
// ---------------------------------------------------------------------------

// One-shot: convert 5 weight matrices (Wk,Wq,Wv,Ws,Wlin) to bf16 hi/lo in
// B-fragment-ready layout: frag index = ((mat*4+ks)*8 + nt)*64 + lane, 8 regs.
// Hot kernels then load B fragments as single coalesced bf16x8 (L2-resident,
// reused by all blocks) instead of 8 stride-512B scalar loads + 16 cvts.
__global__ __launch_bounds__(256) void split_w_kernel(
    const float* __restrict__ W0, const float* __restrict__ W1,
    const float* __restrict__ W2, const float* __restrict__ W3,
    const float* __restrict__ W4,
    unsigned short* __restrict__ whi, unsigned short* __restrict__ wlo)
{
    const int idx = blockIdx.x * 256 + threadIdx.x;   // 5 * 2048 frags
    if (idx >= 5 * 2048) return;
    const int mat  = idx >> 11;
    const int rem  = idx & 2047;
    const int ks   = rem >> 9;
    const int nt   = (rem >> 6) & 7;
    const int lane = rem & 63;
    const int lr = lane & 15, lg = lane >> 4;
    const float* __restrict__ W = mat == 0 ? W0 : mat == 1 ? W1 : mat == 2 ? W2
                                 : mat == 3 ? W3 : W4;
    const int n = nt * 16 + lr;
    bf16x8 h8, l8;
#pragma unroll
    for (int r = 0; r < 8; ++r) {
        const int k = ks * 32 + lg * 8 + r;
        const float w = W[k * DD + n];
        const unsigned short h = f2bf(w);
        h8[r] = (short)h;
        l8[r] = (short)f2bf(w - bf2f(h));   // exact residual in fp32
    }
    const long base = (long)idx * 8;
    *reinterpret_cast<bf16x8*>(&whi[base]) = h8;
    *reinterpret_cast<bf16x8*>(&wlo[base]) = l8;
}

// Stage 64 rows x 128 cols of fp32 A as hi/lo bf16 fragments in LDS.
template <bool XFORM>
__device__ inline void stage_rows(const float* __restrict__ src,
                                  const float* __restrict__ addv,
                                  int row0, int N, int t,
                                  unsigned short* __restrict__ ldsHi,
                                  unsigned short* __restrict__ ldsLo)
{
    const int m  = t >> 2;            // 0..63 local row
    const int gr = row0 + m;
#pragma unroll
    for (int j = 0; j < 4; ++j) {
        const int o = (t & 3) + j * 4;   // k-octet 0..15
        float v[8];
        if (gr < N) {
            const float4 a = *reinterpret_cast<const float4*>(&src[(long)gr * DD + o * 8]);
            const float4 b = *reinterpret_cast<const float4*>(&src[(long)gr * DD + o * 8 + 4]);
            v[0] = a.x; v[1] = a.y; v[2] = a.z; v[3] = a.w;
            v[4] = b.x; v[5] = b.y; v[6] = b.z; v[7] = b.w;
        } else {
#pragma unroll
            for (int e = 0; e < 8; ++e) v[e] = 0.f;
        }
        if (XFORM) {   // leaky_relu(src + addv) fused into staging
#pragma unroll
            for (int e = 0; e < 8; ++e) {
                const float s = v[e] + addv[o * 8 + e];
                v[e] = s >= 0.f ? s : 0.01f * s;
            }
        }
        bf16x8 h8, l8;
#pragma unroll
        for (int e = 0; e < 8; ++e) {
            const unsigned short h = f2bf(v[e]);
            h8[e] = (short)h;
            l8[e] = (short)f2bf(v[e] - bf2f(h));
        }
        const int rt   = m >> 4;
        const int ks   = o >> 2;
        const int lane = (m & 15) + (o & 3) * 16;
        const int base = ((rt * 4 + ks) * 64 + lane) * 8;
        *reinterpret_cast<bf16x8*>(&ldsHi[base]) = h8;
        *reinterpret_cast<bf16x8*>(&ldsLo[base]) = l8;
    }
}

// ---------------------------------------------------------------------------
// Kernel 1 (MFMA): fused node projections. 64 rows/block, 4 waves; wave wv
// owns matrix wv: 0->K(kbuf), 1->Q(qvbuf[:128]), 2->V(qvbuf[128:]), 3->Skip(agg)
// ---------------------------------------------------------------------------
__global__ __launch_bounds__(256) void proj_mfma_kernel(
    const float* __restrict__ x,
    const unsigned short* __restrict__ whi, const unsigned short* __restrict__ wlo,
    const float* __restrict__ bk, const float* __restrict__ bq,
    const float* __restrict__ bv,
    float* __restrict__ kbuf, float* __restrict__ qvbuf, float* __restrict__ agg,
    int N)
{
    __shared__ unsigned short ldsHi[16 * 64 * 8];
    __shared__ unsigned short ldsLo[16 * 64 * 8];
    const int t = threadIdx.x;
    const int row0 = blockIdx.x * 64;

    stage_rows<false>(x, nullptr, row0, N, t, ldsHi, ldsLo);
    __syncthreads();

    const int wv   = t >> 6;
    const int lane = t & 63;
    const int lr = lane & 15;
    const int lg = lane >> 4;
    const float* bias = (wv == 0) ? bk : (wv == 1) ? bq : (wv == 2) ? bv : nullptr;

    for (int cc = 0; cc < 2; ++cc) {            // two 64-col chunks
        f32x4 acc[4][4];
#pragma unroll
        for (int rt = 0; rt < 4; ++rt)
#pragma unroll
            for (int ct = 0; ct < 4; ++ct) acc[rt][ct] = (f32x4){0.f, 0.f, 0.f, 0.f};

#pragma unroll
        for (int ks = 0; ks < 4; ++ks) {
            bf16x8 Ahi[4], Alo[4];
#pragma unroll
            for (int rt = 0; rt < 4; ++rt) {
                const int base = ((rt * 4 + ks) * 64 + lane) * 8;
                Ahi[rt] = *reinterpret_cast<const bf16x8*>(&ldsHi[base]);
                Alo[rt] = *reinterpret_cast<const bf16x8*>(&ldsLo[base]);
            }
#pragma unroll
            for (int ct = 0; ct < 4; ++ct) {
                const long fb = ((long)((wv * 4 + ks) * 8 + (cc * 4 + ct)) * 64 + lane) * 8;
                const bf16x8 Bhi = *reinterpret_cast<const bf16x8*>(&whi[fb]);
                const bf16x8 Blo = *reinterpret_cast<const bf16x8*>(&wlo[fb]);
#pragma unroll
                for (int rt = 0; rt < 4; ++rt) {
                    acc[rt][ct] = __builtin_amdgcn_mfma_f32_16x16x32_bf16(Ahi[rt], Bhi, acc[rt][ct], 0, 0, 0);
                    acc[rt][ct] = __builtin_amdgcn_mfma_f32_16x16x32_bf16(Ahi[rt], Blo, acc[rt][ct], 0, 0, 0);
                    acc[rt][ct] = __builtin_amdgcn_mfma_f32_16x16x32_bf16(Alo[rt], Bhi, acc[rt][ct], 0, 0, 0);
                }
            }
        }
#pragma unroll
        for (int ct = 0; ct < 4; ++ct) {
            const int n_l = cc * 64 + ct * 16 + lr;
            const float bv_ = bias ? bias[n_l] : 0.f;
#pragma unroll
            for (int rt = 0; rt < 4; ++rt) {
#pragma unroll
                for (int r = 0; r < 4; ++r) {
                    const int m = row0 + rt * 16 + lg * 4 + r;
                    if (m < N) {
                        const float val = acc[rt][ct][r] + bv_;
                        if      (wv == 0) kbuf [(long)m * 128 + n_l]       = val;
                        else if (wv == 1) qvbuf[(long)m * 256 + n_l]       = val;
                        else if (wv == 2) qvbuf[(long)m * 256 + 128 + n_l] = val;
                        else              agg  [(long)m * 128 + n_l]       = val;
                    }
                }
            }
        }
    }
}

// ---------------------------------------------------------------------------
// Kernel (MFMA): out = leaky_relu(agg + b_conv) @ Wlin + blin  (agg aliases out)
// Wave wv owns cols [wv*32, wv*32+32). Wlin = split-matrix index 4.
// ---------------------------------------------------------------------------
__global__ __launch_bounds__(256) void out_mfma_kernel(
    const float* agg, const float* __restrict__ bconv,
    const unsigned short* __restrict__ whi, const unsigned short* __restrict__ wlo,
    const float* __restrict__ blin,
    float* out, int N)
{
    __shared__ unsigned short ldsHi[16 * 64 * 8];
    __shared__ unsigned short ldsLo[16 * 64 * 8];
    const int t = threadIdx.x;
    const int row0 = blockIdx.x * 64;

    stage_rows<true>(agg, bconv, row0, N, t, ldsHi, ldsLo);
    __syncthreads();

    const int wv   = t >> 6;
    const int lane = t & 63;
    const int lr = lane & 15;
    const int lg = lane >> 4;

    f32x4 acc[4][2];
#pragma unroll
    for (int rt = 0; rt < 4; ++rt)
#pragma unroll
        for (int ct = 0; ct < 2; ++ct) acc[rt][ct] = (f32x4){0.f, 0.f, 0.f, 0.f};

#pragma unroll
    for (int ks = 0; ks < 4; ++ks) {
        bf16x8 Ahi[4], Alo[4];
#pragma unroll
        for (int rt = 0; rt < 4; ++rt) {
            const int base = ((rt * 4 + ks) * 64 + lane) * 8;
            Ahi[rt] = *reinterpret_cast<const bf16x8*>(&ldsHi[base]);
            Alo[rt] = *reinterpret_cast<const bf16x8*>(&ldsLo[base]);
        }
#pragma unroll
        for (int ct = 0; ct < 2; ++ct) {
            const long fb = ((long)((16 + ks) * 8 + (wv * 2 + ct)) * 64 + lane) * 8;
            const bf16x8 Bhi = *reinterpret_cast<const bf16x8*>(&whi[fb]);
            const bf16x8 Blo = *reinterpret_cast<const bf16x8*>(&wlo[fb]);
#pragma unroll
            for (int rt = 0; rt < 4; ++rt) {
                acc[rt][ct] = __builtin_amdgcn_mfma_f32_16x16x32_bf16(Ahi[rt], Bhi, acc[rt][ct], 0, 0, 0);
                acc[rt][ct] = __builtin_amdgcn_mfma_f32_16x16x32_bf16(Ahi[rt], Blo, acc[rt][ct], 0, 0, 0);
                acc[rt][ct] = __builtin_amdgcn_mfma_f32_16x16x32_bf16(Alo[rt], Bhi, acc[rt][ct], 0, 0, 0);
            }
        }
    }
#pragma unroll
    for (int ct = 0; ct < 2; ++ct) {
        const int n = wv * 32 + ct * 16 + lr;
        const float bb = blin[n];
#pragma unroll
        for (int rt = 0; rt < 4; ++rt) {
#pragma unroll
            for (int r = 0; r < 4; ++r) {
                const int m = row0 + rt * 16 + lg * 4 + r;
                if (m < N) out[(long)m * 128 + n] = acc[rt][ct][r] + bb;
            }
        }
    }
}

// ---------------------------------------------------------------------------
// VALU proj kernel — fallback branches only.
// ---------------------------------------------------------------------------
template <typename T>
__global__ __launch_bounds__(256) void proj_kernel(
    const float* __restrict__ x,
    const float* __restrict__ Wk, const float* __restrict__ bk,
    const float* __restrict__ Wq, const float* __restrict__ bq,
    const float* __restrict__ Wv, const float* __restrict__ bv,
    const float* __restrict__ Ws,
    T* __restrict__ kbuf, T* __restrict__ qvbuf, float* __restrict__ agg,
    int N)
{
    __shared__ float xt[32][DD];
    const int row0 = blockIdx.x * 32;
    const int t = threadIdx.x;

    for (int i = t; i < 32 * (DD / 4); i += 256) {
        const int r  = i >> 5;
        const int c4 = (i & 31) << 2;
        const int gr = row0 + r;
        float4 v = make_float4(0.f, 0.f, 0.f, 0.f);
        if (gr < N) v = *reinterpret_cast<const float4*>(&x[(long)gr * DD + c4]);
        *reinterpret_cast<float4*>(&xt[r][c4]) = v;
    }
    __syncthreads();

    const int c0 = t & 127;
    const int hi = t >> 7;
    const float* __restrict__ W0 = hi ? Wq : Wk;
    const float* __restrict__ W1 = hi ? Ws : Wv;
    const float b0 = hi ? bq[c0] : bk[c0];
    const float b1 = hi ? 0.f    : bv[c0];

    float acc0[32], acc1[32];
#pragma unroll
    for (int r = 0; r < 32; ++r) { acc0[r] = 0.f; acc1[r] = 0.f; }

    for (int k4 = 0; k4 < DD; k4 += 4) {
        const float w00 = W0[(k4 + 0) * DD + c0];
        const float w01 = W0[(k4 + 1) * DD + c0];
        const float w02 = W0[(k4 + 2) * DD + c0];
        const float w03 = W0[(k4 + 3) * DD + c0];
        const float w10 = W1[(k4 + 0) * DD + c0];
        const float w11 = W1[(k4 + 1) * DD + c0];
        const float w12 = W1[(k4 + 2) * DD + c0];
        const float w13 = W1[(k4 + 3) * DD + c0];
#pragma unroll
        for (int r = 0; r < 32; ++r) {
            const float4 xv = *reinterpret_cast<const float4*>(&xt[r][k4]);
            acc0[r] = fmaf(xv.x, w00, fmaf(xv.y, w01, fmaf(xv.z, w02, fmaf(xv.w, w03, acc0[r]))));
            acc1[r] = fmaf(xv.x, w10, fmaf(xv.y, w11, fmaf(xv.z, w12, fmaf(xv.w, w13, acc1[r]))));
        }
    }

#pragma unroll
    for (int r = 0; r < 32; ++r) {
        const long gr = row0 + r;
        if (gr < N) {
            if (hi == 0) {
                kbuf [gr * 128 + c0]       = cvt<T>(acc0[r] + b0);
                qvbuf[gr * 256 + 128 + c0] = cvt<T>(acc1[r] + b1);
            } else {
                qvbuf[gr * 256 + c0]       = cvt<T>(acc0[r] + b0);
                agg  [gr * 128 + c0]       = acc1[r];
            }
        }
    }
}

// ---------------------------------------------------------------------------
// CSR construction: zero -> histogram -> 3-phase multi-block scan -> scatter
// ---------------------------------------------------------------------------
__global__ __launch_bounds__(256) void zero_kernel(int* __restrict__ p, int n) {
    const int i = blockIdx.x * 256 + threadIdx.x;
    if (i < n) p[i] = 0;
}

__global__ __launch_bounds__(256) void hist_kernel(
    const int* __restrict__ ei, int* __restrict__ deg, int E)
{
    const int e = blockIdx.x * 256 + threadIdx.x;
    if (e < E) atomicAdd(&deg[ei[E + e]], 1);   // dst
}

__global__ __launch_bounds__(1024) void scanA_kernel(
    const int* __restrict__ deg, int* __restrict__ off,
    int* __restrict__ bsum, int N)
{
    __shared__ int sm[1024];
    const int t = threadIdx.x;
    const int i = blockIdx.x * 1024 + t;
    const int v = (i < N) ? deg[i] : 0;
    int x = v;
    sm[t] = x;
    __syncthreads();
#pragma unroll
    for (int ofs = 1; ofs < 1024; ofs <<= 1) {
        const int y = (t >= ofs) ? sm[t - ofs] : 0;
        __syncthreads();
        x += y;
        sm[t] = x;
        __syncthreads();
    }
    if (i < N) off[i] = x - v;
    if (t == 1023) bsum[blockIdx.x] = x;
}

__global__ __launch_bounds__(1024) void scanB_kernel(int* __restrict__ bsum, int nb)
{
    __shared__ int sm[1024];
    const int t = threadIdx.x;
    const int v = (t < nb) ? bsum[t] : 0;
    int x = v;
    sm[t] = x;
    __syncthreads();
#pragma unroll
    for (int ofs = 1; ofs < 1024; ofs <<= 1) {
        const int y = (t >= ofs) ? sm[t - ofs] : 0;
        __syncthreads();
        x += y;
        sm[t] = x;
        __syncthreads();
    }
    if (t < nb) bsum[t] = x - v;
}

__global__ __launch_bounds__(256) void scanC_kernel(
    int* __restrict__ off, int* __restrict__ cursor,
    const int* __restrict__ bsum, int N)
{
    const int i = blockIdx.x * 256 + threadIdx.x;
    if (i < N) {
        const int o = off[i] + bsum[i >> 10];
        off[i]    = o;
        cursor[i] = o;
    }
}

__global__ __launch_bounds__(256) void scatter_kernel(
    const int* __restrict__ ei, int* __restrict__ cursor,
    int* __restrict__ ssrc, int E)
{
    const int e = blockIdx.x * 256 + threadIdx.x;
    if (e >= E) return;
    const int s = ei[e];
    const int d = ei[E + e];
    const int pos = atomicAdd(&cursor[d], 1);
    ssrc[pos] = s;
}

// ---------------------------------------------------------------------------
// Gather kernel: one 64-lane wave per dst node (unchanged).
// ---------------------------------------------------------------------------
template <typename T>
__global__ __launch_bounds__(256) void gather_kernel(
    const int* __restrict__ off, const int* __restrict__ deg,
    const int* __restrict__ ssrc,
    const T* __restrict__ kbuf, const T* __restrict__ qvbuf,
    float* __restrict__ agg, int N)
{
    const int n = blockIdx.x * 4 + (threadIdx.x >> 6);
    if (n >= N) return;
    const int lane = threadIdx.x & 63;
    const int c = lane << 1;

    const int dg = deg[n];
    if (dg == 0) return;
    const int s0 = off[n];
    const int s1 = s0 + dg;

    const float2 k2 = ld2<T>(&kbuf[(long)n * 128 + c]);
    float a0 = 0.f, a1 = 0.f, b0 = 0.f, b1 = 0.f;

    int e = s0;
    for (; e + 4 <= s1; e += 4) {
        const long sa = ssrc[e + 0];
        const long sb = ssrc[e + 1];
        const long sc = ssrc[e + 2];
        const long sd = ssrc[e + 3];
        const float2 qa = ld2<T>(&qvbuf[sa * 256 + c]);
        const float2 va = ld2<T>(&qvbuf[sa * 256 + 128 + c]);
        const float2 qb = ld2<T>(&qvbuf[sb * 256 + c]);
        const float2 vb = ld2<T>(&qvbuf[sb * 256 + 128 + c]);
        const float2 qc = ld2<T>(&qvbuf[sc * 256 + c]);
        const float2 vc = ld2<T>(&qvbuf[sc * 256 + 128 + c]);
        const float2 qd = ld2<T>(&qvbuf[sd * 256 + c]);
        const float2 vd = ld2<T>(&qvbuf[sd * 256 + 128 + c]);
        a0 = fmaf(fmaxf(k2.x + qa.x, 0.f), va.x, a0);
        a1 = fmaf(fmaxf(k2.y + qa.y, 0.f), va.y, a1);
        b0 = fmaf(fmaxf(k2.x + qb.x, 0.f), vb.x, b0);
        b1 = fmaf(fmaxf(k2.y + qb.y, 0.f), vb.y, b1);
        a0 = fmaf(fmaxf(k2.x + qc.x, 0.f), vc.x, a0);
        a1 = fmaf(fmaxf(k2.y + qc.y, 0.f), vc.y, a1);
        b0 = fmaf(fmaxf(k2.x + qd.x, 0.f), vd.x, b0);
        b1 = fmaf(fmaxf(k2.y + qd.y, 0.f), vd.y, b1);
    }
    for (; e < s1; ++e) {
        const long s = ssrc[e];
        const float2 q = ld2<T>(&qvbuf[s * 256 + c]);
        const float2 v = ld2<T>(&qvbuf[s * 256 + 128 + c]);
        a0 = fmaf(fmaxf(k2.x + q.x, 0.f), v.x, a0);
        a1 = fmaf(fmaxf(k2.y + q.y, 0.f), v.y, a1);
    }

    float2* ap = reinterpret_cast<float2*>(&agg[(long)n * 128 + c]);
    const float2 old = *ap;
    *ap = make_float2(old.x + a0 + b0, old.y + a1 + b1);
}

// ---------------------------------------------------------------------------
// Fallback edge kernel (atomic path) — only if ws can't fit CSR.
// ---------------------------------------------------------------------------
template <typename T>
__global__ __launch_bounds__(256) void edge_kernel(
    const int* __restrict__ ei,
    const T* __restrict__ kbuf, const T* __restrict__ qvbuf,
    float* __restrict__ agg, int E)
{
    const int g = (blockIdx.x << 3) + (threadIdx.x >> 5);
    if (g >= E) return;
    const int lane = threadIdx.x & 31;
    const long src = (long)ei[g];
    const long dst = (long)ei[E + g];
    const int c = lane << 2;

    float kd[4], qs[4], vs[4];
    if constexpr (sizeof(T) == 4) {
        const float4 a = *reinterpret_cast<const float4*>(&kbuf[dst * 128 + c]);
        const float4 b = *reinterpret_cast<const float4*>(&qvbuf[src * 256 + c]);
        const float4 d = *reinterpret_cast<const float4*>(&qvbuf[src * 256 + 128 + c]);
        kd[0] = a.x; kd[1] = a.y; kd[2] = a.z; kd[3] = a.w;
        qs[0] = b.x; qs[1] = b.y; qs[2] = b.z; qs[3] = b.w;
        vs[0] = d.x; vs[1] = d.y; vs[2] = d.z; vs[3] = d.w;
    } else {
        const ushort4 a = *reinterpret_cast<const ushort4*>(&kbuf[dst * 128 + c]);
        const ushort4 b = *reinterpret_cast<const ushort4*>(&qvbuf[src * 256 + c]);
        const ushort4 d = *reinterpret_cast<const ushort4*>(&qvbuf[src * 256 + 128 + c]);
        kd[0] = bf2f(a.x); kd[1] = bf2f(a.y); kd[2] = bf2f(a.z); kd[3] = bf2f(a.w);
        qs[0] = bf2f(b.x); qs[1] = bf2f(b.y); qs[2] = bf2f(b.z); qs[3] = bf2f(b.w);
        vs[0] = bf2f(d.x); vs[1] = bf2f(d.y); vs[2] = bf2f(d.z); vs[3] = bf2f(d.w);
    }

    float* p = agg + dst * 128 + c;
#pragma unroll
    for (int j = 0; j < 4; ++j) {
        const float m = fmaxf(kd[j] + qs[j], 0.f) * vs[j];
        unsafeAtomicAdd(p + j, m);
    }
}

// ---------------------------------------------------------------------------
// VALU out kernel — fallback branches only.
// ---------------------------------------------------------------------------
__global__ __launch_bounds__(64) void out_kernel(
    const float* agg, const float* __restrict__ bconv,
    const float* __restrict__ Wlin, const float* __restrict__ blin,
    float* out, int N)
{
    __shared__ float xt[32][DD];
    const int row0 = blockIdx.x * 32;
    const int t = threadIdx.x;

    for (int i = t; i < 32 * (DD / 4); i += 64) {
        const int r  = i >> 5;
        const int c4 = (i & 31) << 2;
        const int gr = row0 + r;
        float4 a = make_float4(0.f, 0.f, 0.f, 0.f);
        if (gr < N) a = *reinterpret_cast<const float4*>(&agg[(long)gr * DD + c4]);
        const float4 b = *reinterpret_cast<const float4*>(&bconv[c4]);
        float4 v;
        const float x0 = a.x + b.x; v.x = x0 >= 0.f ? x0 : 0.01f * x0;
        const float x1 = a.y + b.y; v.y = x1 >= 0.f ? x1 : 0.01f * x1;
        const float x2 = a.z + b.z; v.z = x2 >= 0.f ? x2 : 0.01f * x2;
        const float x3 = a.w + b.w; v.w = x3 >= 0.f ? x3 : 0.01f * x3;
        *reinterpret_cast<float4*>(&xt[r][c4]) = v;
    }
    __syncthreads();

    const int c0 = t;
    const int c1 = t + 64;
    float acc0[32], acc1[32];
#pragma unroll
    for (int r = 0; r < 32; ++r) { acc0[r] = 0.f; acc1[r] = 0.f; }

    for (int k4 = 0; k4 < DD; k4 += 4) {
        const float w00 = Wlin[(k4 + 0) * DD + c0];
        const float w01 = Wlin[(k4 + 1) * DD + c0];
        const float w02 = Wlin[(k4 + 2) * DD + c0];
        const float w03 = Wlin[(k4 + 3) * DD + c0];
        const float w10 = Wlin[(k4 + 0) * DD + c1];
        const float w11 = Wlin[(k4 + 1) * DD + c1];
        const float w12 = Wlin[(k4 + 2) * DD + c1];
        const float w13 = Wlin[(k4 + 3) * DD + c1];
#pragma unroll
        for (int r = 0; r < 32; ++r) {
            const float4 xv = *reinterpret_cast<const float4*>(&xt[r][k4]);
            acc0[r] = fmaf(xv.x, w00, fmaf(xv.y, w01, fmaf(xv.z, w02, fmaf(xv.w, w03, acc0[r]))));
            acc1[r] = fmaf(xv.x, w10, fmaf(xv.y, w11, fmaf(xv.z, w12, fmaf(xv.w, w13, acc1[r]))));
        }
    }

    const float bb0 = blin[c0];
    const float bb1 = blin[c1];
#pragma unroll
    for (int r = 0; r < 32; ++r) {
        const long gr = row0 + r;
        if (gr < N) {
            out[gr * DD + c0] = acc0[r] + bb0;
            out[gr * DD + c1] = acc1[r] + bb1;
        }
    }
}

// ---------------------------------------------------------------------------
extern "C" void kernel_launch(void* const* d_in, const int* in_sizes, int n_in,
                              void* d_out, int out_size, void* d_ws, size_t ws_size,
                              hipStream_t stream)
{
    const float* x     = (const float*)d_in[0];
    const int*   ei    = (const int*)d_in[1];      // int32 (harness converts int64 -> int32)
    const float* Wk    = (const float*)d_in[2];
    const float* bk    = (const float*)d_in[3];
    const float* Wq    = (const float*)d_in[4];
    const float* bq    = (const float*)d_in[5];
    const float* Wv    = (const float*)d_in[6];
    const float* bv    = (const float*)d_in[7];
    const float* Ws    = (const float*)d_in[8];
    const float* bconv = (const float*)d_in[9];
    const float* Wlin  = (const float*)d_in[10];
    const float* blin  = (const float*)d_in[11];

    const int N = in_sizes[0] / DD;
    const int E = in_sizes[1] / 2;

    float* aggf = (float*)d_out;                 // agg lives in d_out
    const int nblk   = (N + 31) / 32;
    const int mblk   = (N + 63) / 64;            // MFMA kernels: 64 rows/block
    const int eblk1  = (E + 255) / 256;
    const int nblk1  = (N + 255) / 256;
    const int gblk   = (N + 3) / 4;
    const int nchunks = (N + 1023) / 1024;

    const int bsum_pad = (nchunks + 255) & ~255;
    size_t csr_ints = (size_t)3 * N + bsum_pad + E;
    csr_ints = (csr_ints + 3) & ~(size_t)3;
    const size_t csr_bytes = csr_ints * sizeof(int);

    const size_t projF32  = (size_t)N * 384 * sizeof(float);
    const size_t projBF16 = (size_t)N * 384 * sizeof(unsigned short);
    const size_t wsplit   = (size_t)2 * 5 * 2048 * 8 * sizeof(unsigned short); // 320KB

    if (ws_size >= csr_bytes + projF32 + wsplit) {
        // ---- MFMA fast path ----
        int* deg    = (int*)d_ws;
        int* off    = deg + N;
        int* cursor = off + N;
        int* bsum   = cursor + N;
        int* ssrc   = bsum + bsum_pad;
        float* kbuf  = (float*)((char*)d_ws + csr_bytes);
        float* qvbuf = kbuf + (size_t)N * 128;
        unsigned short* whi = (unsigned short*)(qvbuf + (size_t)N * 256);
        unsigned short* wlo = whi + (size_t)5 * 2048 * 8;

        split_w_kernel<<<40, 256, 0, stream>>>(Wk, Wq, Wv, Ws, Wlin, whi, wlo);
        proj_mfma_kernel<<<mblk, 256, 0, stream>>>(x, whi, wlo, bk, bq, bv,
                                                   kbuf, qvbuf, aggf, N);
        zero_kernel<<<nblk1, 256, 0, stream>>>(deg, N);
        hist_kernel<<<eblk1, 256, 0, stream>>>(ei, deg, E);
        scanA_kernel<<<nchunks, 1024, 0, stream>>>(deg, off, bsum, N);
        scanB_kernel<<<1, 1024, 0, stream>>>(bsum, nchunks);
        scanC_kernel<<<nblk1, 256, 0, stream>>>(off, cursor, bsum, N);
        scatter_kernel<<<eblk1, 256, 0, stream>>>(ei, cursor, ssrc, E);
        gather_kernel<float><<<gblk, 256, 0, stream>>>(off, deg, ssrc, kbuf, qvbuf, aggf, N);
        out_mfma_kernel<<<mblk, 256, 0, stream>>>(aggf, bconv, whi, wlo, blin, (float*)d_out, N);
    } else if (ws_size >= csr_bytes + projF32) {
        // ---- round-5 proven VALU path ----
        int* deg    = (int*)d_ws;
        int* off    = deg + N;
        int* cursor = off + N;
        int* bsum   = cursor + N;
        int* ssrc   = bsum + bsum_pad;
        float* kbuf  = (float*)((char*)d_ws + csr_bytes);
        float* qvbuf = kbuf + (size_t)N * 128;

        proj_kernel<float><<<nblk, 256, 0, stream>>>(x, Wk, bk, Wq, bq, Wv, bv, Ws,
                                                     kbuf, qvbuf, aggf, N);
        zero_kernel<<<nblk1, 256, 0, stream>>>(deg, N);
        hist_kernel<<<eblk1, 256, 0, stream>>>(ei, deg, E);
        scanA_kernel<<<nchunks, 1024, 0, stream>>>(deg, off, bsum, N);
        scanB_kernel<<<1, 1024, 0, stream>>>(bsum, nchunks);
        scanC_kernel<<<nblk1, 256, 0, stream>>>(off, cursor, bsum, N);
        scatter_kernel<<<eblk1, 256, 0, stream>>>(ei, cursor, ssrc, E);
        gather_kernel<float><<<gblk, 256, 0, stream>>>(off, deg, ssrc, kbuf, qvbuf, aggf, N);
        out_kernel<<<nblk, 64, 0, stream>>>(aggf, bconv, Wlin, blin, (float*)d_out, N);
    } else if (ws_size >= csr_bytes + projBF16) {
        int* deg    = (int*)d_ws;
        int* off    = deg + N;
        int* cursor = off + N;
        int* bsum   = cursor + N;
        int* ssrc   = bsum + bsum_pad;
        unsigned short* kbuf  = (unsigned short*)((char*)d_ws + csr_bytes);
        unsigned short* qvbuf = kbuf + (size_t)N * 128;

        proj_kernel<unsigned short><<<nblk, 256, 0, stream>>>(x, Wk, bk, Wq, bq, Wv, bv, Ws,
                                                              kbuf, qvbuf, aggf, N);
        zero_kernel<<<nblk1, 256, 0, stream>>>(deg, N);
        hist_kernel<<<eblk1, 256, 0, stream>>>(ei, deg, E);
        scanA_kernel<<<nchunks, 1024, 0, stream>>>(deg, off, bsum, N);
        scanB_kernel<<<1, 1024, 0, stream>>>(bsum, nchunks);
        scanC_kernel<<<nblk1, 256, 0, stream>>>(off, cursor, bsum, N);
        scatter_kernel<<<eblk1, 256, 0, stream>>>(ei, cursor, ssrc, E);
        gather_kernel<unsigned short><<<gblk, 256, 0, stream>>>(off, deg, ssrc, kbuf, qvbuf, aggf, N);
        out_kernel<<<nblk, 64, 0, stream>>>(aggf, bconv, Wlin, blin, (float*)d_out, N);
    } else if (ws_size >= projBF16) {
        unsigned short* kbuf  = (unsigned short*)d_ws;
        unsigned short* qvbuf = kbuf + (size_t)N * 128;
        const int eblk8 = (E + 7) / 8;
        proj_kernel<unsigned short><<<nblk, 256, 0, stream>>>(x, Wk, bk, Wq, bq, Wv, bv, Ws,
                                                              kbuf, qvbuf, aggf, N);
        edge_kernel<unsigned short><<<eblk8, 256, 0, stream>>>(ei, kbuf, qvbuf, aggf, E);
        out_kernel<<<nblk, 64, 0, stream>>>(aggf, bconv, Wlin, blin, (float*)d_out, N);
    } else {
        hipMemsetAsync(d_out, 0, (size_t)out_size * sizeof(float), stream);
        return;
    }
}

// Round 8
// 277.994 us; speedup vs baseline: 5.5450x; 1.1993x over previous
//
#include <hip/hip_runtime.h>

#define DD 128

typedef __attribute__((ext_vector_type(8))) short bf16x8;
typedef __attribute__((ext_vector_type(4))) float f32x4;

// ---- bf16 helpers (RNE) ----------------------------------------------------
__device__ inline unsigned short f2bf(float f) {
    unsigned int u = __float_as_uint(f);
    u += 0x7FFFu + ((u >> 16) & 1u);
    return (unsigned short)(u >> 16);
}
__device__ inline float bf2f(unsigned short s) {
    return __uint_as_float(((unsigned int)s) << 16);
}

template <typename T> __device__ inline T cvt(float f);
template <> __device__ inline float cvt<float>(float f) { return f; }
template <> __device__ inline unsigned short cvt<unsigned short>(float f) { return f2bf(f); }

template <typename T> __device__ inline float2 ld2(const T* p);
template <> __device__ inline float2 ld2<float>(const float* p) {
    return *reinterpret_cast<const float2*>(p);
}
template <> __device__ inline float2 ld2<unsigned short>(const unsigned short* p) {
    const ushort2 u = *reinterpret_cast<const ushort2*>(p);
    return make_float2(bf2f(u.x), bf2f(u.y));
}

// ---------------------------------------------------------------------------
// Split-precision MFMA GEMM: x@W ~= hi@Whi + hi@Wlo + lo@Whi (error ~2^-17).
// Fragment layouts validated end-to-end in rounds 6-7.
// ---------------------------------------------------------------------------

// One-shot: 5 weight matrices -> bf16 hi/lo in B-fragment layout.
__global__ __launch_bounds__(256) void split_w_kernel(
    const float* __restrict__ W0, const float* __restrict__ W1,
    const float* __restrict__ W2, const float* __restrict__ W3,
    const float* __restrict__ W4,
    unsigned short* __restrict__ whi, unsigned short* __restrict__ wlo)
{
    const int idx = blockIdx.x * 256 + threadIdx.x;   // 5 * 2048 frags
    if (idx >= 5 * 2048) return;
    const int mat  = idx >> 11;
    const int rem  = idx & 2047;
    const int ks   = rem >> 9;
    const int nt   = (rem >> 6) & 7;
    const int lane = rem & 63;
    const int lr = lane & 15, lg = lane >> 4;
    const float* __restrict__ W = mat == 0 ? W0 : mat == 1 ? W1 : mat == 2 ? W2
                                 : mat == 3 ? W3 : W4;
    const int n = nt * 16 + lr;
    bf16x8 h8, l8;
#pragma unroll
    for (int r = 0; r < 8; ++r) {
        const int k = ks * 32 + lg * 8 + r;
        const float w = W[k * DD + n];
        const unsigned short h = f2bf(w);
        h8[r] = (short)h;
        l8[r] = (short)f2bf(w - bf2f(h));   // exact residual in fp32
    }
    const long base = (long)idx * 8;
    *reinterpret_cast<bf16x8*>(&whi[base]) = h8;
    *reinterpret_cast<bf16x8*>(&wlo[base]) = l8;
}

// Stage 64 rows x 128 cols of fp32 A as hi/lo bf16 fragments in LDS.
template <bool XFORM>
__device__ inline void stage_rows(const float* __restrict__ src,
                                  const float* __restrict__ addv,
                                  int row0, int N, int t,
                                  unsigned short* __restrict__ ldsHi,
                                  unsigned short* __restrict__ ldsLo)
{
    const int m  = t >> 2;            // 0..63 local row
    const int gr = row0 + m;
#pragma unroll
    for (int j = 0; j < 4; ++j) {
        const int o = (t & 3) + j * 4;   // k-octet 0..15
        float v[8];
        if (gr < N) {
            const float4 a = *reinterpret_cast<const float4*>(&src[(long)gr * DD + o * 8]);
            const float4 b = *reinterpret_cast<const float4*>(&src[(long)gr * DD + o * 8 + 4]);
            v[0] = a.x; v[1] = a.y; v[2] = a.z; v[3] = a.w;
            v[4] = b.x; v[5] = b.y; v[6] = b.z; v[7] = b.w;
        } else {
#pragma unroll
            for (int e = 0; e < 8; ++e) v[e] = 0.f;
        }
        if (XFORM) {   // leaky_relu(src + addv) fused into staging
#pragma unroll
            for (int e = 0; e < 8; ++e) {
                const float s = v[e] + addv[o * 8 + e];
                v[e] = s >= 0.f ? s : 0.01f * s;
            }
        }
        bf16x8 h8, l8;
#pragma unroll
        for (int e = 0; e < 8; ++e) {
            const unsigned short h = f2bf(v[e]);
            h8[e] = (short)h;
            l8[e] = (short)f2bf(v[e] - bf2f(h));
        }
        const int rt   = m >> 4;
        const int ks   = o >> 2;
        const int lane = (m & 15) + (o & 3) * 16;
        const int base = ((rt * 4 + ks) * 64 + lane) * 8;
        *reinterpret_cast<bf16x8*>(&ldsHi[base]) = h8;
        *reinterpret_cast<bf16x8*>(&ldsLo[base]) = l8;
    }
}

// ---------------------------------------------------------------------------
// Kernel (MFMA): fused node projections. Wave wv: 0->K(kbuf fp32),
// 1->Q, 2->V (both bf16, channel-interleaved in qvpk: [n][c]={q_c,v_c}),
// 3->Skip(agg fp32, lives in d_out).
// ---------------------------------------------------------------------------
__global__ __launch_bounds__(256) void proj_mfma_kernel(
    const float* __restrict__ x,
    const unsigned short* __restrict__ whi, const unsigned short* __restrict__ wlo,
    const float* __restrict__ bk, const float* __restrict__ bq,
    const float* __restrict__ bv,
    float* __restrict__ kbuf, unsigned short* __restrict__ qvpk,
    float* __restrict__ agg, int N)
{
    __shared__ unsigned short ldsHi[16 * 64 * 8];
    __shared__ unsigned short ldsLo[16 * 64 * 8];
    const int t = threadIdx.x;
    const int row0 = blockIdx.x * 64;

    stage_rows<false>(x, nullptr, row0, N, t, ldsHi, ldsLo);
    __syncthreads();

    const int wv   = t >> 6;
    const int lane = t & 63;
    const int lr = lane & 15;
    const int lg = lane >> 4;
    const float* bias = (wv == 0) ? bk : (wv == 1) ? bq : (wv == 2) ? bv : nullptr;

    for (int cc = 0; cc < 2; ++cc) {            // two 64-col chunks
        f32x4 acc[4][4];
#pragma unroll
        for (int rt = 0; rt < 4; ++rt)
#pragma unroll
            for (int ct = 0; ct < 4; ++ct) acc[rt][ct] = (f32x4){0.f, 0.f, 0.f, 0.f};

#pragma unroll
        for (int ks = 0; ks < 4; ++ks) {
            bf16x8 Ahi[4], Alo[4];
#pragma unroll
            for (int rt = 0; rt < 4; ++rt) {
                const int base = ((rt * 4 + ks) * 64 + lane) * 8;
                Ahi[rt] = *reinterpret_cast<const bf16x8*>(&ldsHi[base]);
                Alo[rt] = *reinterpret_cast<const bf16x8*>(&ldsLo[base]);
            }
#pragma unroll
            for (int ct = 0; ct < 4; ++ct) {
                const long fb = ((long)((wv * 4 + ks) * 8 + (cc * 4 + ct)) * 64 + lane) * 8;
                const bf16x8 Bhi = *reinterpret_cast<const bf16x8*>(&whi[fb]);
                const bf16x8 Blo = *reinterpret_cast<const bf16x8*>(&wlo[fb]);
#pragma unroll
                for (int rt = 0; rt < 4; ++rt) {
                    acc[rt][ct] = __builtin_amdgcn_mfma_f32_16x16x32_bf16(Ahi[rt], Bhi, acc[rt][ct], 0, 0, 0);
                    acc[rt][ct] = __builtin_amdgcn_mfma_f32_16x16x32_bf16(Ahi[rt], Blo, acc[rt][ct], 0, 0, 0);
                    acc[rt][ct] = __builtin_amdgcn_mfma_f32_16x16x32_bf16(Alo[rt], Bhi, acc[rt][ct], 0, 0, 0);
                }
            }
        }
#pragma unroll
        for (int ct = 0; ct < 4; ++ct) {
            const int n_l = cc * 64 + ct * 16 + lr;
            const float bv_ = bias ? bias[n_l] : 0.f;
#pragma unroll
            for (int rt = 0; rt < 4; ++rt) {
#pragma unroll
                for (int r = 0; r < 4; ++r) {
                    const int m = row0 + rt * 16 + lg * 4 + r;
                    if (m < N) {
                        const float val = acc[rt][ct][r] + bv_;
                        if      (wv == 0) kbuf [(long)m * 128 + n_l]         = val;
                        else if (wv == 1) qvpk [(long)m * 256 + 2 * n_l]     = f2bf(val);
                        else if (wv == 2) qvpk [(long)m * 256 + 2 * n_l + 1] = f2bf(val);
                        else              agg  [(long)m * 128 + n_l]         = val;
                    }
                }
            }
        }
    }
}

// ---------------------------------------------------------------------------
// Kernel (MFMA): out = leaky_relu(agg + b_conv) @ Wlin + blin  (agg aliases out)
// ---------------------------------------------------------------------------
__global__ __launch_bounds__(256) void out_mfma_kernel(
    const float* agg, const float* __restrict__ bconv,
    const unsigned short* __restrict__ whi, const unsigned short* __restrict__ wlo,
    const float* __restrict__ blin,
    float* out, int N)
{
    __shared__ unsigned short ldsHi[16 * 64 * 8];
    __shared__ unsigned short ldsLo[16 * 64 * 8];
    const int t = threadIdx.x;
    const int row0 = blockIdx.x * 64;

    stage_rows<true>(agg, bconv, row0, N, t, ldsHi, ldsLo);
    __syncthreads();

    const int wv   = t >> 6;
    const int lane = t & 63;
    const int lr = lane & 15;
    const int lg = lane >> 4;

    f32x4 acc[4][2];
#pragma unroll
    for (int rt = 0; rt < 4; ++rt)
#pragma unroll
        for (int ct = 0; ct < 2; ++ct) acc[rt][ct] = (f32x4){0.f, 0.f, 0.f, 0.f};

#pragma unroll
    for (int ks = 0; ks < 4; ++ks) {
        bf16x8 Ahi[4], Alo[4];
#pragma unroll
        for (int rt = 0; rt < 4; ++rt) {
            const int base = ((rt * 4 + ks) * 64 + lane) * 8;
            Ahi[rt] = *reinterpret_cast<const bf16x8*>(&ldsHi[base]);
            Alo[rt] = *reinterpret_cast<const bf16x8*>(&ldsLo[base]);
        }
#pragma unroll
        for (int ct = 0; ct < 2; ++ct) {
            const long fb = ((long)((16 + ks) * 8 + (wv * 2 + ct)) * 64 + lane) * 8;
            const bf16x8 Bhi = *reinterpret_cast<const bf16x8*>(&whi[fb]);
            const bf16x8 Blo = *reinterpret_cast<const bf16x8*>(&wlo[fb]);
#pragma unroll
            for (int rt = 0; rt < 4; ++rt) {
                acc[rt][ct] = __builtin_amdgcn_mfma_f32_16x16x32_bf16(Ahi[rt], Bhi, acc[rt][ct], 0, 0, 0);
                acc[rt][ct] = __builtin_amdgcn_mfma_f32_16x16x32_bf16(Ahi[rt], Blo, acc[rt][ct], 0, 0, 0);
                acc[rt][ct] = __builtin_amdgcn_mfma_f32_16x16x32_bf16(Alo[rt], Bhi, acc[rt][ct], 0, 0, 0);
            }
        }
    }
#pragma unroll
    for (int ct = 0; ct < 2; ++ct) {
        const int n = wv * 32 + ct * 16 + lr;
        const float bb = blin[n];
#pragma unroll
        for (int rt = 0; rt < 4; ++rt) {
#pragma unroll
            for (int r = 0; r < 4; ++r) {
                const int m = row0 + rt * 16 + lg * 4 + r;
                if (m < N) out[(long)m * 128 + n] = acc[rt][ct][r] + bb;
            }
        }
    }
}

// ---------------------------------------------------------------------------
// Gather (packed): one wave per dst node; lane owns channels (2L, 2L+1).
// Per edge per lane: ONE ushort4 load = {q0,v0,q1,v1} bf16. 8-edge unroll.
// ---------------------------------------------------------------------------
__global__ __launch_bounds__(256) void gather_packed_kernel(
    const int* __restrict__ off, const int* __restrict__ deg,
    const int* __restrict__ ssrc,
    const float* __restrict__ kbuf, const unsigned short* __restrict__ qvpk,
    float* __restrict__ agg, int N)
{
    const int n = blockIdx.x * 4 + (threadIdx.x >> 6);
    if (n >= N) return;
    const int lane = threadIdx.x & 63;

    const int dg = deg[n];
    if (dg == 0) return;
    const int s0 = off[n];
    const int s1 = s0 + dg;

    const float2 k2 = *reinterpret_cast<const float2*>(&kbuf[(long)n * 128 + lane * 2]);
    float a0 = 0.f, a1 = 0.f, b0 = 0.f, b1 = 0.f;

    int e = s0;
    for (; e + 8 <= s1; e += 8) {
        int s[8];
#pragma unroll
        for (int j = 0; j < 8; ++j) s[j] = ssrc[e + j];
        ushort4 u[8];
#pragma unroll
        for (int j = 0; j < 8; ++j)
            u[j] = *reinterpret_cast<const ushort4*>(&qvpk[(long)s[j] * 256 + lane * 4]);
#pragma unroll
        for (int j = 0; j < 8; ++j) {
            const float q0 = bf2f(u[j].x), v0 = bf2f(u[j].y);
            const float q1 = bf2f(u[j].z), v1 = bf2f(u[j].w);
            if (j & 1) {
                b0 = fmaf(fmaxf(k2.x + q0, 0.f), v0, b0);
                b1 = fmaf(fmaxf(k2.y + q1, 0.f), v1, b1);
            } else {
                a0 = fmaf(fmaxf(k2.x + q0, 0.f), v0, a0);
                a1 = fmaf(fmaxf(k2.y + q1, 0.f), v1, a1);
            }
        }
    }
    for (; e < s1; ++e) {
        const int s = ssrc[e];
        const ushort4 u = *reinterpret_cast<const ushort4*>(&qvpk[(long)s * 256 + lane * 4]);
        a0 = fmaf(fmaxf(k2.x + bf2f(u.x), 0.f), bf2f(u.y), a0);
        a1 = fmaf(fmaxf(k2.y + bf2f(u.z), 0.f), bf2f(u.w), a1);
    }

    float2* ap = reinterpret_cast<float2*>(&agg[(long)n * 128 + lane * 2]);
    const float2 old = *ap;
    *ap = make_float2(old.x + a0 + b0, old.y + a1 + b1);
}

// ---------------------------------------------------------------------------
// VALU proj kernel — fallback branches only (old split q/v layout).
// ---------------------------------------------------------------------------
template <typename T>
__global__ __launch_bounds__(256) void proj_kernel(
    const float* __restrict__ x,
    const float* __restrict__ Wk, const float* __restrict__ bk,
    const float* __restrict__ Wq, const float* __restrict__ bq,
    const float* __restrict__ Wv, const float* __restrict__ bv,
    const float* __restrict__ Ws,
    T* __restrict__ kbuf, T* __restrict__ qvbuf, float* __restrict__ agg,
    int N)
{
    __shared__ float xt[32][DD];
    const int row0 = blockIdx.x * 32;
    const int t = threadIdx.x;

    for (int i = t; i < 32 * (DD / 4); i += 256) {
        const int r  = i >> 5;
        const int c4 = (i & 31) << 2;
        const int gr = row0 + r;
        float4 v = make_float4(0.f, 0.f, 0.f, 0.f);
        if (gr < N) v = *reinterpret_cast<const float4*>(&x[(long)gr * DD + c4]);
        *reinterpret_cast<float4*>(&xt[r][c4]) = v;
    }
    __syncthreads();

    const int c0 = t & 127;
    const int hi = t >> 7;
    const float* __restrict__ W0 = hi ? Wq : Wk;
    const float* __restrict__ W1 = hi ? Ws : Wv;
    const float b0 = hi ? bq[c0] : bk[c0];
    const float b1 = hi ? 0.f    : bv[c0];

    float acc0[32], acc1[32];
#pragma unroll
    for (int r = 0; r < 32; ++r) { acc0[r] = 0.f; acc1[r] = 0.f; }

    for (int k4 = 0; k4 < DD; k4 += 4) {
        const float w00 = W0[(k4 + 0) * DD + c0];
        const float w01 = W0[(k4 + 1) * DD + c0];
        const float w02 = W0[(k4 + 2) * DD + c0];
        const float w03 = W0[(k4 + 3) * DD + c0];
        const float w10 = W1[(k4 + 0) * DD + c0];
        const float w11 = W1[(k4 + 1) * DD + c0];
        const float w12 = W1[(k4 + 2) * DD + c0];
        const float w13 = W1[(k4 + 3) * DD + c0];
#pragma unroll
        for (int r = 0; r < 32; ++r) {
            const float4 xv = *reinterpret_cast<const float4*>(&xt[r][k4]);
            acc0[r] = fmaf(xv.x, w00, fmaf(xv.y, w01, fmaf(xv.z, w02, fmaf(xv.w, w03, acc0[r]))));
            acc1[r] = fmaf(xv.x, w10, fmaf(xv.y, w11, fmaf(xv.z, w12, fmaf(xv.w, w13, acc1[r]))));
        }
    }

#pragma unroll
    for (int r = 0; r < 32; ++r) {
        const long gr = row0 + r;
        if (gr < N) {
            if (hi == 0) {
                kbuf [gr * 128 + c0]       = cvt<T>(acc0[r] + b0);
                qvbuf[gr * 256 + 128 + c0] = cvt<T>(acc1[r] + b1);
            } else {
                qvbuf[gr * 256 + c0]       = cvt<T>(acc0[r] + b0);
                agg  [gr * 128 + c0]       = acc1[r];
            }
        }
    }
}

// ---------------------------------------------------------------------------
// CSR construction: zero -> histogram -> 3-phase multi-block scan -> scatter
// ---------------------------------------------------------------------------
__global__ __launch_bounds__(256) void zero_kernel(int* __restrict__ p, int n) {
    const int i = blockIdx.x * 256 + threadIdx.x;
    if (i < n) p[i] = 0;
}

__global__ __launch_bounds__(256) void hist_kernel(
    const int* __restrict__ ei, int* __restrict__ deg, int E)
{
    const int e = blockIdx.x * 256 + threadIdx.x;
    if (e < E) atomicAdd(&deg[ei[E + e]], 1);   // dst
}

__global__ __launch_bounds__(1024) void scanA_kernel(
    const int* __restrict__ deg, int* __restrict__ off,
    int* __restrict__ bsum, int N)
{
    __shared__ int sm[1024];
    const int t = threadIdx.x;
    const int i = blockIdx.x * 1024 + t;
    const int v = (i < N) ? deg[i] : 0;
    int x = v;
    sm[t] = x;
    __syncthreads();
#pragma unroll
    for (int ofs = 1; ofs < 1024; ofs <<= 1) {
        const int y = (t >= ofs) ? sm[t - ofs] : 0;
        __syncthreads();
        x += y;
        sm[t] = x;
        __syncthreads();
    }
    if (i < N) off[i] = x - v;
    if (t == 1023) bsum[blockIdx.x] = x;
}

__global__ __launch_bounds__(1024) void scanB_kernel(int* __restrict__ bsum, int nb)
{
    __shared__ int sm[1024];
    const int t = threadIdx.x;
    const int v = (t < nb) ? bsum[t] : 0;
    int x = v;
    sm[t] = x;
    __syncthreads();
#pragma unroll
    for (int ofs = 1; ofs < 1024; ofs <<= 1) {
        const int y = (t >= ofs) ? sm[t - ofs] : 0;
        __syncthreads();
        x += y;
        sm[t] = x;
        __syncthreads();
    }
    if (t < nb) bsum[t] = x - v;
}

__global__ __launch_bounds__(256) void scanC_kernel(
    int* __restrict__ off, int* __restrict__ cursor,
    const int* __restrict__ bsum, int N)
{
    const int i = blockIdx.x * 256 + threadIdx.x;
    if (i < N) {
        const int o = off[i] + bsum[i >> 10];
        off[i]    = o;
        cursor[i] = o;
    }
}

__global__ __launch_bounds__(256) void scatter_kernel(
    const int* __restrict__ ei, int* __restrict__ cursor,
    int* __restrict__ ssrc, int E)
{
    const int e = blockIdx.x * 256 + threadIdx.x;
    if (e >= E) return;
    const int s = ei[e];
    const int d = ei[E + e];
    const int pos = atomicAdd(&cursor[d], 1);
    ssrc[pos] = s;
}

// ---------------------------------------------------------------------------
// Old-layout gather — fallback branches only.
// ---------------------------------------------------------------------------
template <typename T>
__global__ __launch_bounds__(256) void gather_kernel(
    const int* __restrict__ off, const int* __restrict__ deg,
    const int* __restrict__ ssrc,
    const T* __restrict__ kbuf, const T* __restrict__ qvbuf,
    float* __restrict__ agg, int N)
{
    const int n = blockIdx.x * 4 + (threadIdx.x >> 6);
    if (n >= N) return;
    const int lane = threadIdx.x & 63;
    const int c = lane << 1;

    const int dg = deg[n];
    if (dg == 0) return;
    const int s0 = off[n];
    const int s1 = s0 + dg;

    const float2 k2 = ld2<T>(&kbuf[(long)n * 128 + c]);
    float a0 = 0.f, a1 = 0.f, b0 = 0.f, b1 = 0.f;

    int e = s0;
    for (; e + 4 <= s1; e += 4) {
        const long sa = ssrc[e + 0];
        const long sb = ssrc[e + 1];
        const long sc = ssrc[e + 2];
        const long sd = ssrc[e + 3];
        const float2 qa = ld2<T>(&qvbuf[sa * 256 + c]);
        const float2 va = ld2<T>(&qvbuf[sa * 256 + 128 + c]);
        const float2 qb = ld2<T>(&qvbuf[sb * 256 + c]);
        const float2 vb = ld2<T>(&qvbuf[sb * 256 + 128 + c]);
        const float2 qc = ld2<T>(&qvbuf[sc * 256 + c]);
        const float2 vc = ld2<T>(&qvbuf[sc * 256 + 128 + c]);
        const float2 qd = ld2<T>(&qvbuf[sd * 256 + c]);
        const float2 vd = ld2<T>(&qvbuf[sd * 256 + 128 + c]);
        a0 = fmaf(fmaxf(k2.x + qa.x, 0.f), va.x, a0);
        a1 = fmaf(fmaxf(k2.y + qa.y, 0.f), va.y, a1);
        b0 = fmaf(fmaxf(k2.x + qb.x, 0.f), vb.x, b0);
        b1 = fmaf(fmaxf(k2.y + qb.y, 0.f), vb.y, b1);
        a0 = fmaf(fmaxf(k2.x + qc.x, 0.f), vc.x, a0);
        a1 = fmaf(fmaxf(k2.y + qc.y, 0.f), vc.y, a1);
        b0 = fmaf(fmaxf(k2.x + qd.x, 0.f), vd.x, b0);
        b1 = fmaf(fmaxf(k2.y + qd.y, 0.f), vd.y, b1);
    }
    for (; e < s1; ++e) {
        const long s = ssrc[e];
        const float2 q = ld2<T>(&qvbuf[s * 256 + c]);
        const float2 v = ld2<T>(&qvbuf[s * 256 + 128 + c]);
        a0 = fmaf(fmaxf(k2.x + q.x, 0.f), v.x, a0);
        a1 = fmaf(fmaxf(k2.y + q.y, 0.f), v.y, a1);
    }

    float2* ap = reinterpret_cast<float2*>(&agg[(long)n * 128 + c]);
    const float2 old = *ap;
    *ap = make_float2(old.x + a0 + b0, old.y + a1 + b1);
}

// ---------------------------------------------------------------------------
// Fallback edge kernel (atomic path) — only if ws can't fit CSR.
// ---------------------------------------------------------------------------
template <typename T>
__global__ __launch_bounds__(256) void edge_kernel(
    const int* __restrict__ ei,
    const T* __restrict__ kbuf, const T* __restrict__ qvbuf,
    float* __restrict__ agg, int E)
{
    const int g = (blockIdx.x << 3) + (threadIdx.x >> 5);
    if (g >= E) return;
    const int lane = threadIdx.x & 31;
    const long src = (long)ei[g];
    const long dst = (long)ei[E + g];
    const int c = lane << 2;

    float kd[4], qs[4], vs[4];
    if constexpr (sizeof(T) == 4) {
        const float4 a = *reinterpret_cast<const float4*>(&kbuf[dst * 128 + c]);
        const float4 b = *reinterpret_cast<const float4*>(&qvbuf[src * 256 + c]);
        const float4 d = *reinterpret_cast<const float4*>(&qvbuf[src * 256 + 128 + c]);
        kd[0] = a.x; kd[1] = a.y; kd[2] = a.z; kd[3] = a.w;
        qs[0] = b.x; qs[1] = b.y; qs[2] = b.z; qs[3] = b.w;
        vs[0] = d.x; vs[1] = d.y; vs[2] = d.z; vs[3] = d.w;
    } else {
        const ushort4 a = *reinterpret_cast<const ushort4*>(&kbuf[dst * 128 + c]);
        const ushort4 b = *reinterpret_cast<const ushort4*>(&qvbuf[src * 256 + c]);
        const ushort4 d = *reinterpret_cast<const ushort4*>(&qvbuf[src * 256 + 128 + c]);
        kd[0] = bf2f(a.x); kd[1] = bf2f(a.y); kd[2] = bf2f(a.z); kd[3] = bf2f(a.w);
        qs[0] = bf2f(b.x); qs[1] = bf2f(b.y); qs[2] = bf2f(b.z); qs[3] = bf2f(b.w);
        vs[0] = bf2f(d.x); vs[1] = bf2f(d.y); vs[2] = bf2f(d.z); vs[3] = bf2f(d.w);
    }

    float* p = agg + dst * 128 + c;
#pragma unroll
    for (int j = 0; j < 4; ++j) {
        const float m = fmaxf(kd[j] + qs[j], 0.f) * vs[j];
        unsafeAtomicAdd(p + j, m);
    }
}

// ---------------------------------------------------------------------------
// VALU out kernel — fallback branches only.
// ---------------------------------------------------------------------------
__global__ __launch_bounds__(64) void out_kernel(
    const float* agg, const float* __restrict__ bconv,
    const float* __restrict__ Wlin, const float* __restrict__ blin,
    float* out, int N)
{
    __shared__ float xt[32][DD];
    const int row0 = blockIdx.x * 32;
    const int t = threadIdx.x;

    for (int i = t; i < 32 * (DD / 4); i += 64) {
        const int r  = i >> 5;
        const int c4 = (i & 31) << 2;
        const int gr = row0 + r;
        float4 a = make_float4(0.f, 0.f, 0.f, 0.f);
        if (gr < N) a = *reinterpret_cast<const float4*>(&agg[(long)gr * DD + c4]);
        const float4 b = *reinterpret_cast<const float4*>(&bconv[c4]);
        float4 v;
        const float x0 = a.x + b.x; v.x = x0 >= 0.f ? x0 : 0.01f * x0;
        const float x1 = a.y + b.y; v.y = x1 >= 0.f ? x1 : 0.01f * x1;
        const float x2 = a.z + b.z; v.z = x2 >= 0.f ? x2 : 0.01f * x2;
        const float x3 = a.w + b.w; v.w = x3 >= 0.f ? x3 : 0.01f * x3;
        *reinterpret_cast<float4*>(&xt[r][c4]) = v;
    }
    __syncthreads();

    const int c0 = t;
    const int c1 = t + 64;
    float acc0[32], acc1[32];
#pragma unroll
    for (int r = 0; r < 32; ++r) { acc0[r] = 0.f; acc1[r] = 0.f; }

    for (int k4 = 0; k4 < DD; k4 += 4) {
        const float w00 = Wlin[(k4 + 0) * DD + c0];
        const float w01 = Wlin[(k4 + 1) * DD + c0];
        const float w02 = Wlin[(k4 + 2) * DD + c0];
        const float w03 = Wlin[(k4 + 3) * DD + c0];
        const float w10 = Wlin[(k4 + 0) * DD + c1];
        const float w11 = Wlin[(k4 + 1) * DD + c1];
        const float w12 = Wlin[(k4 + 2) * DD + c1];
        const float w13 = Wlin[(k4 + 3) * DD + c1];
#pragma unroll
        for (int r = 0; r < 32; ++r) {
            const float4 xv = *reinterpret_cast<const float4*>(&xt[r][k4]);
            acc0[r] = fmaf(xv.x, w00, fmaf(xv.y, w01, fmaf(xv.z, w02, fmaf(xv.w, w03, acc0[r]))));
            acc1[r] = fmaf(xv.x, w10, fmaf(xv.y, w11, fmaf(xv.z, w12, fmaf(xv.w, w13, acc1[r]))));
        }
    }

    const float bb0 = blin[c0];
    const float bb1 = blin[c1];
#pragma unroll
    for (int r = 0; r < 32; ++r) {
        const long gr = row0 + r;
        if (gr < N) {
            out[gr * DD + c0] = acc0[r] + bb0;
            out[gr * DD + c1] = acc1[r] + bb1;
        }
    }
}

// ---------------------------------------------------------------------------
extern "C" void kernel_launch(void* const* d_in, const int* in_sizes, int n_in,
                              void* d_out, int out_size, void* d_ws, size_t ws_size,
                              hipStream_t stream)
{
    const float* x     = (const float*)d_in[0];
    const int*   ei    = (const int*)d_in[1];      // int32 (harness converts int64 -> int32)
    const float* Wk    = (const float*)d_in[2];
    const float* bk    = (const float*)d_in[3];
    const float* Wq    = (const float*)d_in[4];
    const float* bq    = (const float*)d_in[5];
    const float* Wv    = (const float*)d_in[6];
    const float* bv    = (const float*)d_in[7];
    const float* Ws    = (const float*)d_in[8];
    const float* bconv = (const float*)d_in[9];
    const float* Wlin  = (const float*)d_in[10];
    const float* blin  = (const float*)d_in[11];

    const int N = in_sizes[0] / DD;
    const int E = in_sizes[1] / 2;

    float* aggf = (float*)d_out;                 // agg lives in d_out
    const int nblk   = (N + 31) / 32;
    const int mblk   = (N + 63) / 64;            // MFMA kernels: 64 rows/block
    const int eblk1  = (E + 255) / 256;
    const int nblk1  = (N + 255) / 256;
    const int gblk   = (N + 3) / 4;
    const int nchunks = (N + 1023) / 1024;

    const int bsum_pad = (nchunks + 255) & ~255;
    size_t csr_ints = (size_t)3 * N + bsum_pad + E;
    csr_ints = (csr_ints + 3) & ~(size_t)3;
    const size_t csr_bytes = csr_ints * sizeof(int);

    const size_t projPK   = (size_t)N * (128 * sizeof(float) + 256 * sizeof(unsigned short)); // k fp32 + qv packed bf16
    const size_t projF32  = (size_t)N * 384 * sizeof(float);
    const size_t projBF16 = (size_t)N * 384 * sizeof(unsigned short);
    const size_t wsplit   = (size_t)2 * 5 * 2048 * 8 * sizeof(unsigned short); // 320KB

    if (ws_size >= csr_bytes + projPK + wsplit) {
        // ---- MFMA + packed-bf16-gather fast path ----
        int* deg    = (int*)d_ws;
        int* off    = deg + N;
        int* cursor = off + N;
        int* bsum   = cursor + N;
        int* ssrc   = bsum + bsum_pad;
        float* kbuf = (float*)((char*)d_ws + csr_bytes);
        unsigned short* qvpk = (unsigned short*)(kbuf + (size_t)N * 128);
        unsigned short* whi  = qvpk + (size_t)N * 256;
        unsigned short* wlo  = whi + (size_t)5 * 2048 * 8;

        split_w_kernel<<<40, 256, 0, stream>>>(Wk, Wq, Wv, Ws, Wlin, whi, wlo);
        proj_mfma_kernel<<<mblk, 256, 0, stream>>>(x, whi, wlo, bk, bq, bv,
                                                   kbuf, qvpk, aggf, N);
        zero_kernel<<<nblk1, 256, 0, stream>>>(deg, N);
        hist_kernel<<<eblk1, 256, 0, stream>>>(ei, deg, E);
        scanA_kernel<<<nchunks, 1024, 0, stream>>>(deg, off, bsum, N);
        scanB_kernel<<<1, 1024, 0, stream>>>(bsum, nchunks);
        scanC_kernel<<<nblk1, 256, 0, stream>>>(off, cursor, bsum, N);
        scatter_kernel<<<eblk1, 256, 0, stream>>>(ei, cursor, ssrc, E);
        gather_packed_kernel<<<gblk, 256, 0, stream>>>(off, deg, ssrc, kbuf, qvpk, aggf, N);
        out_mfma_kernel<<<mblk, 256, 0, stream>>>(aggf, bconv, whi, wlo, blin, (float*)d_out, N);
    } else if (ws_size >= csr_bytes + projF32) {
        // ---- round-5 proven VALU path ----
        int* deg    = (int*)d_ws;
        int* off    = deg + N;
        int* cursor = off + N;
        int* bsum   = cursor + N;
        int* ssrc   = bsum + bsum_pad;
        float* kbuf  = (float*)((char*)d_ws + csr_bytes);
        float* qvbuf = kbuf + (size_t)N * 128;

        proj_kernel<float><<<nblk, 256, 0, stream>>>(x, Wk, bk, Wq, bq, Wv, bv, Ws,
                                                     kbuf, qvbuf, aggf, N);
        zero_kernel<<<nblk1, 256, 0, stream>>>(deg, N);
        hist_kernel<<<eblk1, 256, 0, stream>>>(ei, deg, E);
        scanA_kernel<<<nchunks, 1024, 0, stream>>>(deg, off, bsum, N);
        scanB_kernel<<<1, 1024, 0, stream>>>(bsum, nchunks);
        scanC_kernel<<<nblk1, 256, 0, stream>>>(off, cursor, bsum, N);
        scatter_kernel<<<eblk1, 256, 0, stream>>>(ei, cursor, ssrc, E);
        gather_kernel<float><<<gblk, 256, 0, stream>>>(off, deg, ssrc, kbuf, qvbuf, aggf, N);
        out_kernel<<<nblk, 64, 0, stream>>>(aggf, bconv, Wlin, blin, (float*)d_out, N);
    } else if (ws_size >= csr_bytes + projBF16) {
        int* deg    = (int*)d_ws;
        int* off    = deg + N;
        int* cursor = off + N;
        int* bsum   = cursor + N;
        int* ssrc   = bsum + bsum_pad;
        unsigned short* kbuf  = (unsigned short*)((char*)d_ws + csr_bytes);
        unsigned short* qvbuf = kbuf + (size_t)N * 128;

        proj_kernel<unsigned short><<<nblk, 256, 0, stream>>>(x, Wk, bk, Wq, bq, Wv, bv, Ws,
                                                              kbuf, qvbuf, aggf, N);
        zero_kernel<<<nblk1, 256, 0, stream>>>(deg, N);
        hist_kernel<<<eblk1, 256, 0, stream>>>(ei, deg, E);
        scanA_kernel<<<nchunks, 1024, 0, stream>>>(deg, off, bsum, N);
        scanB_kernel<<<1, 1024, 0, stream>>>(bsum, nchunks);
        scanC_kernel<<<nblk1, 256, 0, stream>>>(off, cursor, bsum, N);
        scatter_kernel<<<eblk1, 256, 0, stream>>>(ei, cursor, ssrc, E);
        gather_kernel<unsigned short><<<gblk, 256, 0, stream>>>(off, deg, ssrc, kbuf, qvbuf, aggf, N);
        out_kernel<<<nblk, 64, 0, stream>>>(aggf, bconv, Wlin, blin, (float*)d_out, N);
    } else if (ws_size >= projBF16) {
        unsigned short* kbuf  = (unsigned short*)d_ws;
        unsigned short* qvbuf = kbuf + (size_t)N * 128;
        const int eblk8 = (E + 7) / 8;
        proj_kernel<unsigned short><<<nblk, 256, 0, stream>>>(x, Wk, bk, Wq, bq, Wv, bv, Ws,
                                                              kbuf, qvbuf, aggf, N);
        edge_kernel<unsigned short><<<eblk8, 256, 0, stream>>>(ei, kbuf, qvbuf, aggf, E);
        out_kernel<<<nblk, 64, 0, stream>>>(aggf, bconv, Wlin, blin, (float*)d_out, N);
    } else {
        hipMemsetAsync(d_out, 0, (size_t)out_size * sizeof(float), stream);
        return;
    }
}

// Round 9
// 257.704 us; speedup vs baseline: 5.9816x; 1.0787x over previous
//
#include <hip/hip_runtime.h>

#define DD 128

typedef __attribute__((ext_vector_type(8))) short bf16x8;
typedef __attribute__((ext_vector_type(4))) float f32x4;

// ---- bf16 helpers (RNE) ----------------------------------------------------
__device__ inline unsigned short f2bf(float f) {
    unsigned int u = __float_as_uint(f);
    u += 0x7FFFu + ((u >> 16) & 1u);
    return (unsigned short)(u >> 16);
}
__device__ inline float bf2f(unsigned short s) {
    return __uint_as_float(((unsigned int)s) << 16);
}

template <typename T> __device__ inline T cvt(float f);
template <> __device__ inline float cvt<float>(float f) { return f; }
template <> __device__ inline unsigned short cvt<unsigned short>(float f) { return f2bf(f); }

template <typename T> __device__ inline float2 ld2(const T* p);
template <> __device__ inline float2 ld2<float>(const float* p) {
    return *reinterpret_cast<const float2*>(p);
}
template <> __device__ inline float2 ld2<unsigned short>(const unsigned short* p) {
    const ushort2 u = *reinterpret_cast<const ushort2*>(p);
    return make_float2(bf2f(u.x), bf2f(u.y));
}

// ---------------------------------------------------------------------------
// Plain-bf16 MFMA GEMM (round 9: hi/lo split dropped — error budget analysis
// says bf16 input rounding adds ~3e-4 std per output, invisible vs 0.0825
// threshold; measured absmax was layout-dominated, not precision-dominated).
// Fragment layouts validated end-to-end in rounds 6-8.
// ---------------------------------------------------------------------------

// One-shot: 5 weight matrices -> bf16 in B-fragment layout.
__global__ __launch_bounds__(256) void split_w_kernel(
    const float* __restrict__ W0, const float* __restrict__ W1,
    const float* __restrict__ W2, const float* __restrict__ W3,
    const float* __restrict__ W4,
    unsigned short* __restrict__ whi)
{
    const int idx = blockIdx.x * 256 + threadIdx.x;   // 5 * 2048 frags
    if (idx >= 5 * 2048) return;
    const int mat  = idx >> 11;
    const int rem  = idx & 2047;
    const int ks   = rem >> 9;
    const int nt   = (rem >> 6) & 7;
    const int lane = rem & 63;
    const int lr = lane & 15, lg = lane >> 4;
    const float* __restrict__ W = mat == 0 ? W0 : mat == 1 ? W1 : mat == 2 ? W2
                                 : mat == 3 ? W3 : W4;
    const int n = nt * 16 + lr;
    bf16x8 h8;
#pragma unroll
    for (int r = 0; r < 8; ++r) {
        const int k = ks * 32 + lg * 8 + r;
        h8[r] = (short)f2bf(W[k * DD + n]);
    }
    *reinterpret_cast<bf16x8*>(&whi[(long)idx * 8]) = h8;
}

// Stage 64 rows x 128 cols of fp32 A as bf16 fragments in LDS.
template <bool XFORM>
__device__ inline void stage_rows(const float* __restrict__ src,
                                  const float* __restrict__ addv,
                                  int row0, int N, int t,
                                  unsigned short* __restrict__ ldsA)
{
    const int m  = t >> 2;            // 0..63 local row
    const int gr = row0 + m;
#pragma unroll
    for (int j = 0; j < 4; ++j) {
        const int o = (t & 3) + j * 4;   // k-octet 0..15
        float v[8];
        if (gr < N) {
            const float4 a = *reinterpret_cast<const float4*>(&src[(long)gr * DD + o * 8]);
            const float4 b = *reinterpret_cast<const float4*>(&src[(long)gr * DD + o * 8 + 4]);
            v[0] = a.x; v[1] = a.y; v[2] = a.z; v[3] = a.w;
            v[4] = b.x; v[5] = b.y; v[6] = b.z; v[7] = b.w;
        } else {
#pragma unroll
            for (int e = 0; e < 8; ++e) v[e] = 0.f;
        }
        if (XFORM) {   // leaky_relu(src + addv) fused into staging
#pragma unroll
            for (int e = 0; e < 8; ++e) {
                const float s = v[e] + addv[o * 8 + e];
                v[e] = s >= 0.f ? s : 0.01f * s;
            }
        }
        bf16x8 h8;
#pragma unroll
        for (int e = 0; e < 8; ++e) h8[e] = (short)f2bf(v[e]);
        const int rt   = m >> 4;
        const int ks   = o >> 2;
        const int lane = (m & 15) + (o & 3) * 16;
        const int base = ((rt * 4 + ks) * 64 + lane) * 8;
        *reinterpret_cast<bf16x8*>(&ldsA[base]) = h8;
    }
}

// ---------------------------------------------------------------------------
// Kernel (MFMA): fused node projections. Wave wv: 0->K(kbuf fp32),
// 1->Q, 2->V (bf16, channel-interleaved qvpk [n][c]={q_c,v_c}), 3->Skip(agg).
// ---------------------------------------------------------------------------
__global__ __launch_bounds__(256) void proj_mfma_kernel(
    const float* __restrict__ x,
    const unsigned short* __restrict__ whi,
    const float* __restrict__ bk, const float* __restrict__ bq,
    const float* __restrict__ bv,
    float* __restrict__ kbuf, unsigned short* __restrict__ qvpk,
    float* __restrict__ agg, int N)
{
    __shared__ unsigned short ldsA[16 * 64 * 8];
    const int t = threadIdx.x;
    const int row0 = blockIdx.x * 64;

    stage_rows<false>(x, nullptr, row0, N, t, ldsA);
    __syncthreads();

    const int wv   = t >> 6;
    const int lane = t & 63;
    const int lr = lane & 15;
    const int lg = lane >> 4;
    const float* bias = (wv == 0) ? bk : (wv == 1) ? bq : (wv == 2) ? bv : nullptr;

    for (int cc = 0; cc < 2; ++cc) {            // two 64-col chunks
        f32x4 acc[4][4];
#pragma unroll
        for (int rt = 0; rt < 4; ++rt)
#pragma unroll
            for (int ct = 0; ct < 4; ++ct) acc[rt][ct] = (f32x4){0.f, 0.f, 0.f, 0.f};

#pragma unroll
        for (int ks = 0; ks < 4; ++ks) {
            bf16x8 A[4];
#pragma unroll
            for (int rt = 0; rt < 4; ++rt)
                A[rt] = *reinterpret_cast<const bf16x8*>(&ldsA[((rt * 4 + ks) * 64 + lane) * 8]);
#pragma unroll
            for (int ct = 0; ct < 4; ++ct) {
                const long fb = ((long)((wv * 4 + ks) * 8 + (cc * 4 + ct)) * 64 + lane) * 8;
                const bf16x8 B = *reinterpret_cast<const bf16x8*>(&whi[fb]);
#pragma unroll
                for (int rt = 0; rt < 4; ++rt)
                    acc[rt][ct] = __builtin_amdgcn_mfma_f32_16x16x32_bf16(A[rt], B, acc[rt][ct], 0, 0, 0);
            }
        }
#pragma unroll
        for (int ct = 0; ct < 4; ++ct) {
            const int n_l = cc * 64 + ct * 16 + lr;
            const float bv_ = bias ? bias[n_l] : 0.f;
#pragma unroll
            for (int rt = 0; rt < 4; ++rt) {
#pragma unroll
                for (int r = 0; r < 4; ++r) {
                    const int m = row0 + rt * 16 + lg * 4 + r;
                    if (m < N) {
                        const float val = acc[rt][ct][r] + bv_;
                        if      (wv == 0) kbuf [(long)m * 128 + n_l]         = val;
                        else if (wv == 1) qvpk [(long)m * 256 + 2 * n_l]     = f2bf(val);
                        else if (wv == 2) qvpk [(long)m * 256 + 2 * n_l + 1] = f2bf(val);
                        else              agg  [(long)m * 128 + n_l]         = val;
                    }
                }
            }
        }
    }
}

// ---------------------------------------------------------------------------
// Kernel (MFMA): out = leaky_relu(agg + b_conv) @ Wlin + blin  (agg aliases out)
// ---------------------------------------------------------------------------
__global__ __launch_bounds__(256) void out_mfma_kernel(
    const float* agg, const float* __restrict__ bconv,
    const unsigned short* __restrict__ whi,
    const float* __restrict__ blin,
    float* out, int N)
{
    __shared__ unsigned short ldsA[16 * 64 * 8];
    const int t = threadIdx.x;
    const int row0 = blockIdx.x * 64;

    stage_rows<true>(agg, bconv, row0, N, t, ldsA);
    __syncthreads();

    const int wv   = t >> 6;
    const int lane = t & 63;
    const int lr = lane & 15;
    const int lg = lane >> 4;

    f32x4 acc[4][2];
#pragma unroll
    for (int rt = 0; rt < 4; ++rt)
#pragma unroll
        for (int ct = 0; ct < 2; ++ct) acc[rt][ct] = (f32x4){0.f, 0.f, 0.f, 0.f};

#pragma unroll
    for (int ks = 0; ks < 4; ++ks) {
        bf16x8 A[4];
#pragma unroll
        for (int rt = 0; rt < 4; ++rt)
            A[rt] = *reinterpret_cast<const bf16x8*>(&ldsA[((rt * 4 + ks) * 64 + lane) * 8]);
#pragma unroll
        for (int ct = 0; ct < 2; ++ct) {
            const long fb = ((long)((16 + ks) * 8 + (wv * 2 + ct)) * 64 + lane) * 8;
            const bf16x8 B = *reinterpret_cast<const bf16x8*>(&whi[fb]);
#pragma unroll
            for (int rt = 0; rt < 4; ++rt)
                acc[rt][ct] = __builtin_amdgcn_mfma_f32_16x16x32_bf16(A[rt], B, acc[rt][ct], 0, 0, 0);
        }
    }
#pragma unroll
    for (int ct = 0; ct < 2; ++ct) {
        const int n = wv * 32 + ct * 16 + lr;
        const float bb = blin[n];
#pragma unroll
        for (int rt = 0; rt < 4; ++rt) {
#pragma unroll
            for (int r = 0; r < 4; ++r) {
                const int m = row0 + rt * 16 + lg * 4 + r;
                if (m < N) out[(long)m * 128 + n] = acc[rt][ct][r] + bb;
            }
        }
    }
}

// ---------------------------------------------------------------------------
// Gather (packed): one wave per dst node; lane owns channels (2L, 2L+1).
// Per edge per lane: ONE ushort4 load = {q0,v0,q1,v1} bf16. 8-edge unroll.
// ---------------------------------------------------------------------------
__global__ __launch_bounds__(256) void gather_packed_kernel(
    const int* __restrict__ off, const int* __restrict__ deg,
    const int* __restrict__ ssrc,
    const float* __restrict__ kbuf, const unsigned short* __restrict__ qvpk,
    float* __restrict__ agg, int N)
{
    const int n = blockIdx.x * 4 + (threadIdx.x >> 6);
    if (n >= N) return;
    const int lane = threadIdx.x & 63;

    const int dg = deg[n];
    if (dg == 0) return;
    const int s0 = off[n];
    const int s1 = s0 + dg;

    const float2 k2 = *reinterpret_cast<const float2*>(&kbuf[(long)n * 128 + lane * 2]);
    float a0 = 0.f, a1 = 0.f, b0 = 0.f, b1 = 0.f;

    int e = s0;
    for (; e + 8 <= s1; e += 8) {
        int s[8];
#pragma unroll
        for (int j = 0; j < 8; ++j) s[j] = ssrc[e + j];
        ushort4 u[8];
#pragma unroll
        for (int j = 0; j < 8; ++j)
            u[j] = *reinterpret_cast<const ushort4*>(&qvpk[(long)s[j] * 256 + lane * 4]);
#pragma unroll
        for (int j = 0; j < 8; ++j) {
            const float q0 = bf2f(u[j].x), v0 = bf2f(u[j].y);
            const float q1 = bf2f(u[j].z), v1 = bf2f(u[j].w);
            if (j & 1) {
                b0 = fmaf(fmaxf(k2.x + q0, 0.f), v0, b0);
                b1 = fmaf(fmaxf(k2.y + q1, 0.f), v1, b1);
            } else {
                a0 = fmaf(fmaxf(k2.x + q0, 0.f), v0, a0);
                a1 = fmaf(fmaxf(k2.y + q1, 0.f), v1, a1);
            }
        }
    }
    for (; e < s1; ++e) {
        const int s = ssrc[e];
        const ushort4 u = *reinterpret_cast<const ushort4*>(&qvpk[(long)s * 256 + lane * 4]);
        a0 = fmaf(fmaxf(k2.x + bf2f(u.x), 0.f), bf2f(u.y), a0);
        a1 = fmaf(fmaxf(k2.y + bf2f(u.z), 0.f), bf2f(u.w), a1);
    }

    float2* ap = reinterpret_cast<float2*>(&agg[(long)n * 128 + lane * 2]);
    const float2 old = *ap;
    *ap = make_float2(old.x + a0 + b0, old.y + a1 + b1);
}

// ---------------------------------------------------------------------------
// VALU proj kernel — fallback branches only (old split q/v layout).
// ---------------------------------------------------------------------------
template <typename T>
__global__ __launch_bounds__(256) void proj_kernel(
    const float* __restrict__ x,
    const float* __restrict__ Wk, const float* __restrict__ bk,
    const float* __restrict__ Wq, const float* __restrict__ bq,
    const float* __restrict__ Wv, const float* __restrict__ bv,
    const float* __restrict__ Ws,
    T* __restrict__ kbuf, T* __restrict__ qvbuf, float* __restrict__ agg,
    int N)
{
    __shared__ float xt[32][DD];
    const int row0 = blockIdx.x * 32;
    const int t = threadIdx.x;

    for (int i = t; i < 32 * (DD / 4); i += 256) {
        const int r  = i >> 5;
        const int c4 = (i & 31) << 2;
        const int gr = row0 + r;
        float4 v = make_float4(0.f, 0.f, 0.f, 0.f);
        if (gr < N) v = *reinterpret_cast<const float4*>(&x[(long)gr * DD + c4]);
        *reinterpret_cast<float4*>(&xt[r][c4]) = v;
    }
    __syncthreads();

    const int c0 = t & 127;
    const int hi = t >> 7;
    const float* __restrict__ W0 = hi ? Wq : Wk;
    const float* __restrict__ W1 = hi ? Ws : Wv;
    const float b0 = hi ? bq[c0] : bk[c0];
    const float b1 = hi ? 0.f    : bv[c0];

    float acc0[32], acc1[32];
#pragma unroll
    for (int r = 0; r < 32; ++r) { acc0[r] = 0.f; acc1[r] = 0.f; }

    for (int k4 = 0; k4 < DD; k4 += 4) {
        const float w00 = W0[(k4 + 0) * DD + c0];
        const float w01 = W0[(k4 + 1) * DD + c0];
        const float w02 = W0[(k4 + 2) * DD + c0];
        const float w03 = W0[(k4 + 3) * DD + c0];
        const float w10 = W1[(k4 + 0) * DD + c0];
        const float w11 = W1[(k4 + 1) * DD + c0];
        const float w12 = W1[(k4 + 2) * DD + c0];
        const float w13 = W1[(k4 + 3) * DD + c0];
#pragma unroll
        for (int r = 0; r < 32; ++r) {
            const float4 xv = *reinterpret_cast<const float4*>(&xt[r][k4]);
            acc0[r] = fmaf(xv.x, w00, fmaf(xv.y, w01, fmaf(xv.z, w02, fmaf(xv.w, w03, acc0[r]))));
            acc1[r] = fmaf(xv.x, w10, fmaf(xv.y, w11, fmaf(xv.z, w12, fmaf(xv.w, w13, acc1[r]))));
        }
    }

#pragma unroll
    for (int r = 0; r < 32; ++r) {
        const long gr = row0 + r;
        if (gr < N) {
            if (hi == 0) {
                kbuf [gr * 128 + c0]       = cvt<T>(acc0[r] + b0);
                qvbuf[gr * 256 + 128 + c0] = cvt<T>(acc1[r] + b1);
            } else {
                qvbuf[gr * 256 + c0]       = cvt<T>(acc0[r] + b0);
                agg  [gr * 128 + c0]       = acc1[r];
            }
        }
    }
}

// ---------------------------------------------------------------------------
// CSR construction: zero -> histogram -> 3-phase multi-block scan -> scatter
// ---------------------------------------------------------------------------
__global__ __launch_bounds__(256) void zero_kernel(int* __restrict__ p, int n) {
    const int i = blockIdx.x * 256 + threadIdx.x;
    if (i < n) p[i] = 0;
}

__global__ __launch_bounds__(256) void hist_kernel(
    const int* __restrict__ ei, int* __restrict__ deg, int E)
{
    const int e = blockIdx.x * 256 + threadIdx.x;
    if (e < E) atomicAdd(&deg[ei[E + e]], 1);   // dst
}

__global__ __launch_bounds__(1024) void scanA_kernel(
    const int* __restrict__ deg, int* __restrict__ off,
    int* __restrict__ bsum, int N)
{
    __shared__ int sm[1024];
    const int t = threadIdx.x;
    const int i = blockIdx.x * 1024 + t;
    const int v = (i < N) ? deg[i] : 0;
    int x = v;
    sm[t] = x;
    __syncthreads();
#pragma unroll
    for (int ofs = 1; ofs < 1024; ofs <<= 1) {
        const int y = (t >= ofs) ? sm[t - ofs] : 0;
        __syncthreads();
        x += y;
        sm[t] = x;
        __syncthreads();
    }
    if (i < N) off[i] = x - v;
    if (t == 1023) bsum[blockIdx.x] = x;
}

__global__ __launch_bounds__(1024) void scanB_kernel(int* __restrict__ bsum, int nb)
{
    __shared__ int sm[1024];
    const int t = threadIdx.x;
    const int v = (t < nb) ? bsum[t] : 0;
    int x = v;
    sm[t] = x;
    __syncthreads();
#pragma unroll
    for (int ofs = 1; ofs < 1024; ofs <<= 1) {
        const int y = (t >= ofs) ? sm[t - ofs] : 0;
        __syncthreads();
        x += y;
        sm[t] = x;
        __syncthreads();
    }
    if (t < nb) bsum[t] = x - v;
}

__global__ __launch_bounds__(256) void scanC_kernel(
    int* __restrict__ off, int* __restrict__ cursor,
    const int* __restrict__ bsum, int N)
{
    const int i = blockIdx.x * 256 + threadIdx.x;
    if (i < N) {
        const int o = off[i] + bsum[i >> 10];
        off[i]    = o;
        cursor[i] = o;
    }
}

__global__ __launch_bounds__(256) void scatter_kernel(
    const int* __restrict__ ei, int* __restrict__ cursor,
    int* __restrict__ ssrc, int E)
{
    const int e = blockIdx.x * 256 + threadIdx.x;
    if (e >= E) return;
    const int s = ei[e];
    const int d = ei[E + e];
    const int pos = atomicAdd(&cursor[d], 1);
    ssrc[pos] = s;
}

// ---------------------------------------------------------------------------
// Old-layout gather — fallback branches only.
// ---------------------------------------------------------------------------
template <typename T>
__global__ __launch_bounds__(256) void gather_kernel(
    const int* __restrict__ off, const int* __restrict__ deg,
    const int* __restrict__ ssrc,
    const T* __restrict__ kbuf, const T* __restrict__ qvbuf,
    float* __restrict__ agg, int N)
{
    const int n = blockIdx.x * 4 + (threadIdx.x >> 6);
    if (n >= N) return;
    const int lane = threadIdx.x & 63;
    const int c = lane << 1;

    const int dg = deg[n];
    if (dg == 0) return;
    const int s0 = off[n];
    const int s1 = s0 + dg;

    const float2 k2 = ld2<T>(&kbuf[(long)n * 128 + c]);
    float a0 = 0.f, a1 = 0.f, b0 = 0.f, b1 = 0.f;

    int e = s0;
    for (; e + 4 <= s1; e += 4) {
        const long sa = ssrc[e + 0];
        const long sb = ssrc[e + 1];
        const long sc = ssrc[e + 2];
        const long sd = ssrc[e + 3];
        const float2 qa = ld2<T>(&qvbuf[sa * 256 + c]);
        const float2 va = ld2<T>(&qvbuf[sa * 256 + 128 + c]);
        const float2 qb = ld2<T>(&qvbuf[sb * 256 + c]);
        const float2 vb = ld2<T>(&qvbuf[sb * 256 + 128 + c]);
        const float2 qc = ld2<T>(&qvbuf[sc * 256 + c]);
        const float2 vc = ld2<T>(&qvbuf[sc * 256 + 128 + c]);
        const float2 qd = ld2<T>(&qvbuf[sd * 256 + c]);
        const float2 vd = ld2<T>(&qvbuf[sd * 256 + 128 + c]);
        a0 = fmaf(fmaxf(k2.x + qa.x, 0.f), va.x, a0);
        a1 = fmaf(fmaxf(k2.y + qa.y, 0.f), va.y, a1);
        b0 = fmaf(fmaxf(k2.x + qb.x, 0.f), vb.x, b0);
        b1 = fmaf(fmaxf(k2.y + qb.y, 0.f), vb.y, b1);
        a0 = fmaf(fmaxf(k2.x + qc.x, 0.f), vc.x, a0);
        a1 = fmaf(fmaxf(k2.y + qc.y, 0.f), vc.y, a1);
        b0 = fmaf(fmaxf(k2.x + qd.x, 0.f), vd.x, b0);
        b1 = fmaf(fmaxf(k2.y + qd.y, 0.f), vd.y, b1);
    }
    for (; e < s1; ++e) {
        const long s = ssrc[e];
        const float2 q = ld2<T>(&qvbuf[s * 256 + c]);
        const float2 v = ld2<T>(&qvbuf[s * 256 + 128 + c]);
        a0 = fmaf(fmaxf(k2.x + q.x, 0.f), v.x, a0);
        a1 = fmaf(fmaxf(k2.y + q.y, 0.f), v.y, a1);
    }

    float2* ap = reinterpret_cast<float2*>(&agg[(long)n * 128 + c]);
    const float2 old = *ap;
    *ap = make_float2(old.x + a0 + b0, old.y + a1 + b1);
}

// ---------------------------------------------------------------------------
// Fallback edge kernel (atomic path) — only if ws can't fit CSR.
// ---------------------------------------------------------------------------
template <typename T>
__global__ __launch_bounds__(256) void edge_kernel(
    const int* __restrict__ ei,
    const T* __restrict__ kbuf, const T* __restrict__ qvbuf,
    float* __restrict__ agg, int E)
{
    const int g = (blockIdx.x << 3) + (threadIdx.x >> 5);
    if (g >= E) return;
    const int lane = threadIdx.x & 31;
    const long src = (long)ei[g];
    const long dst = (long)ei[E + g];
    const int c = lane << 2;

    float kd[4], qs[4], vs[4];
    if constexpr (sizeof(T) == 4) {
        const float4 a = *reinterpret_cast<const float4*>(&kbuf[dst * 128 + c]);
        const float4 b = *reinterpret_cast<const float4*>(&qvbuf[src * 256 + c]);
        const float4 d = *reinterpret_cast<const float4*>(&qvbuf[src * 256 + 128 + c]);
        kd[0] = a.x; kd[1] = a.y; kd[2] = a.z; kd[3] = a.w;
        qs[0] = b.x; qs[1] = b.y; qs[2] = b.z; qs[3] = b.w;
        vs[0] = d.x; vs[1] = d.y; vs[2] = d.z; vs[3] = d.w;
    } else {
        const ushort4 a = *reinterpret_cast<const ushort4*>(&kbuf[dst * 128 + c]);
        const ushort4 b = *reinterpret_cast<const ushort4*>(&qvbuf[src * 256 + c]);
        const ushort4 d = *reinterpret_cast<const ushort4*>(&qvbuf[src * 256 + 128 + c]);
        kd[0] = bf2f(a.x); kd[1] = bf2f(a.y); kd[2] = bf2f(a.z); kd[3] = bf2f(a.w);
        qs[0] = bf2f(b.x); qs[1] = bf2f(b.y); qs[2] = bf2f(b.z); qs[3] = bf2f(b.w);
        vs[0] = bf2f(d.x); vs[1] = bf2f(d.y); vs[2] = bf2f(d.z); vs[3] = bf2f(d.w);
    }

    float* p = agg + dst * 128 + c;
#pragma unroll
    for (int j = 0; j < 4; ++j) {
        const float m = fmaxf(kd[j] + qs[j], 0.f) * vs[j];
        unsafeAtomicAdd(p + j, m);
    }
}

// ---------------------------------------------------------------------------
// VALU out kernel — fallback branches only.
// ---------------------------------------------------------------------------
__global__ __launch_bounds__(64) void out_kernel(
    const float* agg, const float* __restrict__ bconv,
    const float* __restrict__ Wlin, const float* __restrict__ blin,
    float* out, int N)
{
    __shared__ float xt[32][DD];
    const int row0 = blockIdx.x * 32;
    const int t = threadIdx.x;

    for (int i = t; i < 32 * (DD / 4); i += 64) {
        const int r  = i >> 5;
        const int c4 = (i & 31) << 2;
        const int gr = row0 + r;
        float4 a = make_float4(0.f, 0.f, 0.f, 0.f);
        if (gr < N) a = *reinterpret_cast<const float4*>(&agg[(long)gr * DD + c4]);
        const float4 b = *reinterpret_cast<const float4*>(&bconv[c4]);
        float4 v;
        const float x0 = a.x + b.x; v.x = x0 >= 0.f ? x0 : 0.01f * x0;
        const float x1 = a.y + b.y; v.y = x1 >= 0.f ? x1 : 0.01f * x1;
        const float x2 = a.z + b.z; v.z = x2 >= 0.f ? x2 : 0.01f * x2;
        const float x3 = a.w + b.w; v.w = x3 >= 0.f ? x3 : 0.01f * x3;
        *reinterpret_cast<float4*>(&xt[r][c4]) = v;
    }
    __syncthreads();

    const int c0 = t;
    const int c1 = t + 64;
    float acc0[32], acc1[32];
#pragma unroll
    for (int r = 0; r < 32; ++r) { acc0[r] = 0.f; acc1[r] = 0.f; }

    for (int k4 = 0; k4 < DD; k4 += 4) {
        const float w00 = Wlin[(k4 + 0) * DD + c0];
        const float w01 = Wlin[(k4 + 1) * DD + c0];
        const float w02 = Wlin[(k4 + 2) * DD + c0];
        const float w03 = Wlin[(k4 + 3) * DD + c0];
        const float w10 = Wlin[(k4 + 0) * DD + c1];
        const float w11 = Wlin[(k4 + 1) * DD + c1];
        const float w12 = Wlin[(k4 + 2) * DD + c1];
        const float w13 = Wlin[(k4 + 3) * DD + c1];
#pragma unroll
        for (int r = 0; r < 32; ++r) {
            const float4 xv = *reinterpret_cast<const float4*>(&xt[r][k4]);
            acc0[r] = fmaf(xv.x, w00, fmaf(xv.y, w01, fmaf(xv.z, w02, fmaf(xv.w, w03, acc0[r]))));
            acc1[r] = fmaf(xv.x, w10, fmaf(xv.y, w11, fmaf(xv.z, w12, fmaf(xv.w, w13, acc1[r]))));
        }
    }

    const float bb0 = blin[c0];
    const float bb1 = blin[c1];
#pragma unroll
    for (int r = 0; r < 32; ++r) {
        const long gr = row0 + r;
        if (gr < N) {
            out[gr * DD + c0] = acc0[r] + bb0;
            out[gr * DD + c1] = acc1[r] + bb1;
        }
    }
}

// ---------------------------------------------------------------------------
extern "C" void kernel_launch(void* const* d_in, const int* in_sizes, int n_in,
                              void* d_out, int out_size, void* d_ws, size_t ws_size,
                              hipStream_t stream)
{
    const float* x     = (const float*)d_in[0];
    const int*   ei    = (const int*)d_in[1];      // int32 (harness converts int64 -> int32)
    const float* Wk    = (const float*)d_in[2];
    const float* bk    = (const float*)d_in[3];
    const float* Wq    = (const float*)d_in[4];
    const float* bq    = (const float*)d_in[5];
    const float* Wv    = (const float*)d_in[6];
    const float* bv    = (const float*)d_in[7];
    const float* Ws    = (const float*)d_in[8];
    const float* bconv = (const float*)d_in[9];
    const float* Wlin  = (const float*)d_in[10];
    const float* blin  = (const float*)d_in[11];

    const int N = in_sizes[0] / DD;
    const int E = in_sizes[1] / 2;

    float* aggf = (float*)d_out;                 // agg lives in d_out
    const int nblk   = (N + 31) / 32;
    const int mblk   = (N + 63) / 64;            // MFMA kernels: 64 rows/block
    const int eblk1  = (E + 255) / 256;
    const int nblk1  = (N + 255) / 256;
    const int gblk   = (N + 3) / 4;
    const int nchunks = (N + 1023) / 1024;

    const int bsum_pad = (nchunks + 255) & ~255;
    size_t csr_ints = (size_t)3 * N + bsum_pad + E;
    csr_ints = (csr_ints + 3) & ~(size_t)3;
    const size_t csr_bytes = csr_ints * sizeof(int);

    const size_t projPK   = (size_t)N * (128 * sizeof(float) + 256 * sizeof(unsigned short)); // k fp32 + qv packed bf16
    const size_t projF32  = (size_t)N * 384 * sizeof(float);
    const size_t projBF16 = (size_t)N * 384 * sizeof(unsigned short);
    const size_t wsplit   = (size_t)5 * 2048 * 8 * sizeof(unsigned short); // 160KB

    if (ws_size >= csr_bytes + projPK + wsplit) {
        // ---- MFMA + packed-bf16-gather fast path ----
        int* deg    = (int*)d_ws;
        int* off    = deg + N;
        int* cursor = off + N;
        int* bsum   = cursor + N;
        int* ssrc   = bsum + bsum_pad;
        float* kbuf = (float*)((char*)d_ws + csr_bytes);
        unsigned short* qvpk = (unsigned short*)(kbuf + (size_t)N * 128);
        unsigned short* whi  = qvpk + (size_t)N * 256;

        split_w_kernel<<<40, 256, 0, stream>>>(Wk, Wq, Wv, Ws, Wlin, whi);
        proj_mfma_kernel<<<mblk, 256, 0, stream>>>(x, whi, bk, bq, bv,
                                                   kbuf, qvpk, aggf, N);
        zero_kernel<<<nblk1, 256, 0, stream>>>(deg, N);
        hist_kernel<<<eblk1, 256, 0, stream>>>(ei, deg, E);
        scanA_kernel<<<nchunks, 1024, 0, stream>>>(deg, off, bsum, N);
        scanB_kernel<<<1, 1024, 0, stream>>>(bsum, nchunks);
        scanC_kernel<<<nblk1, 256, 0, stream>>>(off, cursor, bsum, N);
        scatter_kernel<<<eblk1, 256, 0, stream>>>(ei, cursor, ssrc, E);
        gather_packed_kernel<<<gblk, 256, 0, stream>>>(off, deg, ssrc, kbuf, qvpk, aggf, N);
        out_mfma_kernel<<<mblk, 256, 0, stream>>>(aggf, bconv, whi, blin, (float*)d_out, N);
    } else if (ws_size >= csr_bytes + projF32) {
        // ---- round-5 proven VALU path ----
        int* deg    = (int*)d_ws;
        int* off    = deg + N;
        int* cursor = off + N;
        int* bsum   = cursor + N;
        int* ssrc   = bsum + bsum_pad;
        float* kbuf  = (float*)((char*)d_ws + csr_bytes);
        float* qvbuf = kbuf + (size_t)N * 128;

        proj_kernel<float><<<nblk, 256, 0, stream>>>(x, Wk, bk, Wq, bq, Wv, bv, Ws,
                                                     kbuf, qvbuf, aggf, N);
        zero_kernel<<<nblk1, 256, 0, stream>>>(deg, N);
        hist_kernel<<<eblk1, 256, 0, stream>>>(ei, deg, E);
        scanA_kernel<<<nchunks, 1024, 0, stream>>>(deg, off, bsum, N);
        scanB_kernel<<<1, 1024, 0, stream>>>(bsum, nchunks);
        scanC_kernel<<<nblk1, 256, 0, stream>>>(off, cursor, bsum, N);
        scatter_kernel<<<eblk1, 256, 0, stream>>>(ei, cursor, ssrc, E);
        gather_kernel<float><<<gblk, 256, 0, stream>>>(off, deg, ssrc, kbuf, qvbuf, aggf, N);
        out_kernel<<<nblk, 64, 0, stream>>>(aggf, bconv, Wlin, blin, (float*)d_out, N);
    } else if (ws_size >= csr_bytes + projBF16) {
        int* deg    = (int*)d_ws;
        int* off    = deg + N;
        int* cursor = off + N;
        int* bsum   = cursor + N;
        int* ssrc   = bsum + bsum_pad;
        unsigned short* kbuf  = (unsigned short*)((char*)d_ws + csr_bytes);
        unsigned short* qvbuf = kbuf + (size_t)N * 128;

        proj_kernel<unsigned short><<<nblk, 256, 0, stream>>>(x, Wk, bk, Wq, bq, Wv, bv, Ws,
                                                              kbuf, qvbuf, aggf, N);
        zero_kernel<<<nblk1, 256, 0, stream>>>(deg, N);
        hist_kernel<<<eblk1, 256, 0, stream>>>(ei, deg, E);
        scanA_kernel<<<nchunks, 1024, 0, stream>>>(deg, off, bsum, N);
        scanB_kernel<<<1, 1024, 0, stream>>>(bsum, nchunks);
        scanC_kernel<<<nblk1, 256, 0, stream>>>(off, cursor, bsum, N);
        scatter_kernel<<<eblk1, 256, 0, stream>>>(ei, cursor, ssrc, E);
        gather_kernel<unsigned short><<<gblk, 256, 0, stream>>>(off, deg, ssrc, kbuf, qvbuf, aggf, N);
        out_kernel<<<nblk, 64, 0, stream>>>(aggf, bconv, Wlin, blin, (float*)d_out, N);
    } else if (ws_size >= projBF16) {
        unsigned short* kbuf  = (unsigned short*)d_ws;
        unsigned short* qvbuf = kbuf + (size_t)N * 128;
        const int eblk8 = (E + 7) / 8;
        proj_kernel<unsigned short><<<nblk, 256, 0, stream>>>(x, Wk, bk, Wq, bq, Wv, bv, Ws,
                                                              kbuf, qvbuf, aggf, N);
        edge_kernel<unsigned short><<<eblk8, 256, 0, stream>>>(ei, kbuf, qvbuf, aggf, E);
        out_kernel<<<nblk, 64, 0, stream>>>(aggf, bconv, Wlin, blin, (float*)d_out, N);
    } else {
        hipMemsetAsync(d_out, 0, (size_t)out_size * sizeof(float), stream);
        return;
    }
}

// Round 10
// 229.627 us; speedup vs baseline: 6.7130x; 1.1223x over previous
//
#include <hip/hip_runtime.h>

#define DD 128

typedef __attribute__((ext_vector_type(8))) short bf16x8;
typedef __attribute__((ext_vector_type(4))) float f32x4;

// ---- bf16 helpers (RNE) ----------------------------------------------------
__device__ inline unsigned short f2bf(float f) {
    unsigned int u = __float_as_uint(f);
    u += 0x7FFFu + ((u >> 16) & 1u);
    return (unsigned short)(u >> 16);
}
__device__ inline float bf2f(unsigned short s) {
    return __uint_as_float(((unsigned int)s) << 16);
}

template <typename T> __device__ inline T cvt(float f);
template <> __device__ inline float cvt<float>(float f) { return f; }
template <> __device__ inline unsigned short cvt<unsigned short>(float f) { return f2bf(f); }

template <typename T> __device__ inline float2 ld2(const T* p);
template <> __device__ inline float2 ld2<float>(const float* p) {
    return *reinterpret_cast<const float2*>(p);
}
template <> __device__ inline float2 ld2<unsigned short>(const unsigned short* p) {
    const ushort2 u = *reinterpret_cast<const ushort2*>(p);
    return make_float2(bf2f(u.x), bf2f(u.y));
}

// ---------------------------------------------------------------------------
// Plain-bf16 MFMA GEMM. Fragment layouts validated end-to-end rounds 6-9.
// Round 10: 8-wave blocks for 2x resident waves/CU (occupancy was the
// binding constraint: 15%, MfmaUtil 3%).
// ---------------------------------------------------------------------------

// One-shot: 5 weight matrices -> bf16 in B-fragment layout.
__global__ __launch_bounds__(256) void split_w_kernel(
    const float* __restrict__ W0, const float* __restrict__ W1,
    const float* __restrict__ W2, const float* __restrict__ W3,
    const float* __restrict__ W4,
    unsigned short* __restrict__ whi)
{
    const int idx = blockIdx.x * 256 + threadIdx.x;   // 5 * 2048 frags
    if (idx >= 5 * 2048) return;
    const int mat  = idx >> 11;
    const int rem  = idx & 2047;
    const int ks   = rem >> 9;
    const int nt   = (rem >> 6) & 7;
    const int lane = rem & 63;
    const int lr = lane & 15, lg = lane >> 4;
    const float* __restrict__ W = mat == 0 ? W0 : mat == 1 ? W1 : mat == 2 ? W2
                                 : mat == 3 ? W3 : W4;
    const int n = nt * 16 + lr;
    bf16x8 h8;
#pragma unroll
    for (int r = 0; r < 8; ++r) {
        const int k = ks * 32 + lg * 8 + r;
        h8[r] = (short)f2bf(W[k * DD + n]);
    }
    *reinterpret_cast<bf16x8*>(&whi[(long)idx * 8]) = h8;
}

// Stage 64 rows x 128 cols of fp32 A as bf16 fragments in LDS (512 threads).
template <bool XFORM>
__device__ inline void stage_rows512(const float* __restrict__ src,
                                     const float* __restrict__ addv,
                                     int row0, int N, int t,
                                     unsigned short* __restrict__ ldsA)
{
    const int m  = t >> 3;            // 0..63 local row
    const int gr = row0 + m;
#pragma unroll
    for (int j = 0; j < 2; ++j) {
        const int o = (t & 7) + j * 8;   // k-octet 0..15
        float v[8];
        if (gr < N) {
            const float4 a = *reinterpret_cast<const float4*>(&src[(long)gr * DD + o * 8]);
            const float4 b = *reinterpret_cast<const float4*>(&src[(long)gr * DD + o * 8 + 4]);
            v[0] = a.x; v[1] = a.y; v[2] = a.z; v[3] = a.w;
            v[4] = b.x; v[5] = b.y; v[6] = b.z; v[7] = b.w;
        } else {
#pragma unroll
            for (int e = 0; e < 8; ++e) v[e] = 0.f;
        }
        if (XFORM) {   // leaky_relu(src + addv) fused into staging
#pragma unroll
            for (int e = 0; e < 8; ++e) {
                const float s = v[e] + addv[o * 8 + e];
                v[e] = s >= 0.f ? s : 0.01f * s;
            }
        }
        bf16x8 h8;
#pragma unroll
        for (int e = 0; e < 8; ++e) h8[e] = (short)f2bf(v[e]);
        const int rt   = m >> 4;
        const int ks   = o >> 2;
        const int lane = (m & 15) + (o & 3) * 16;
        const int base = ((rt * 4 + ks) * 64 + lane) * 8;
        *reinterpret_cast<bf16x8*>(&ldsA[base]) = h8;
    }
}

// ---------------------------------------------------------------------------
// Kernel (MFMA, 512 thr / 8 waves): fused node projections.
// Wave wv: mat = wv>>1 (0=K fp32, 1=Q bf16, 2=V bf16, 3=Skip fp32),
// cc = wv&1 (which 64-col half). Also zeroes deg[] (runs before hist).
// ---------------------------------------------------------------------------
__global__ __launch_bounds__(512) void proj_mfma_kernel(
    const float* __restrict__ x,
    const unsigned short* __restrict__ whi,
    const float* __restrict__ bk, const float* __restrict__ bq,
    const float* __restrict__ bv,
    float* __restrict__ kbuf, unsigned short* __restrict__ qvpk,
    float* __restrict__ agg, int* __restrict__ deg, int N)
{
    __shared__ unsigned short ldsA[16 * 64 * 8];
    const int t = threadIdx.x;
    const int row0 = blockIdx.x * 64;

    // fold-in: zero deg[] for the CSR histogram (grid covers N amply)
    const int gid = blockIdx.x * 512 + t;
    if (gid < N) deg[gid] = 0;

    stage_rows512<false>(x, nullptr, row0, N, t, ldsA);
    __syncthreads();

    const int wv   = t >> 6;
    const int mat  = wv >> 1;
    const int cc   = wv & 1;
    const int lane = t & 63;
    const int lr = lane & 15;
    const int lg = lane >> 4;
    const float* bias = (mat == 0) ? bk : (mat == 1) ? bq : (mat == 2) ? bv : nullptr;

    f32x4 acc[4][4];
#pragma unroll
    for (int rt = 0; rt < 4; ++rt)
#pragma unroll
        for (int ct = 0; ct < 4; ++ct) acc[rt][ct] = (f32x4){0.f, 0.f, 0.f, 0.f};

#pragma unroll
    for (int ks = 0; ks < 4; ++ks) {
        bf16x8 A[4];
#pragma unroll
        for (int rt = 0; rt < 4; ++rt)
            A[rt] = *reinterpret_cast<const bf16x8*>(&ldsA[((rt * 4 + ks) * 64 + lane) * 8]);
#pragma unroll
        for (int ct = 0; ct < 4; ++ct) {
            const long fb = ((long)((mat * 4 + ks) * 8 + (cc * 4 + ct)) * 64 + lane) * 8;
            const bf16x8 B = *reinterpret_cast<const bf16x8*>(&whi[fb]);
#pragma unroll
            for (int rt = 0; rt < 4; ++rt)
                acc[rt][ct] = __builtin_amdgcn_mfma_f32_16x16x32_bf16(A[rt], B, acc[rt][ct], 0, 0, 0);
        }
    }

#pragma unroll
    for (int ct = 0; ct < 4; ++ct) {
        const int n_l = cc * 64 + ct * 16 + lr;
        const float bv_ = bias ? bias[n_l] : 0.f;
#pragma unroll
        for (int rt = 0; rt < 4; ++rt) {
#pragma unroll
            for (int r = 0; r < 4; ++r) {
                const int m = row0 + rt * 16 + lg * 4 + r;
                if (m < N) {
                    const float val = acc[rt][ct][r] + bv_;
                    if      (mat == 0) kbuf [(long)m * 128 + n_l]         = val;
                    else if (mat == 1) qvpk [(long)m * 256 + 2 * n_l]     = f2bf(val);
                    else if (mat == 2) qvpk [(long)m * 256 + 2 * n_l + 1] = f2bf(val);
                    else               agg  [(long)m * 128 + n_l]         = val;
                }
            }
        }
    }
}

// ---------------------------------------------------------------------------
// Kernel (MFMA, 512 thr / 8 waves): out = leaky(agg + b_conv) @ Wlin + blin.
// agg aliases out (block stages its rows before overwriting). Wave wv owns
// cols [wv*16, wv*16+16).
// ---------------------------------------------------------------------------
__global__ __launch_bounds__(512) void out_mfma_kernel(
    const float* agg, const float* __restrict__ bconv,
    const unsigned short* __restrict__ whi,
    const float* __restrict__ blin,
    float* out, int N)
{
    __shared__ unsigned short ldsA[16 * 64 * 8];
    const int t = threadIdx.x;
    const int row0 = blockIdx.x * 64;

    stage_rows512<true>(agg, bconv, row0, N, t, ldsA);
    __syncthreads();

    const int wv   = t >> 6;
    const int lane = t & 63;
    const int lr = lane & 15;
    const int lg = lane >> 4;

    f32x4 acc[4];
#pragma unroll
    for (int rt = 0; rt < 4; ++rt) acc[rt] = (f32x4){0.f, 0.f, 0.f, 0.f};

#pragma unroll
    for (int ks = 0; ks < 4; ++ks) {
        bf16x8 A[4];
#pragma unroll
        for (int rt = 0; rt < 4; ++rt)
            A[rt] = *reinterpret_cast<const bf16x8*>(&ldsA[((rt * 4 + ks) * 64 + lane) * 8]);
        const long fb = ((long)((16 + ks) * 8 + wv) * 64 + lane) * 8;
        const bf16x8 B = *reinterpret_cast<const bf16x8*>(&whi[fb]);
#pragma unroll
        for (int rt = 0; rt < 4; ++rt)
            acc[rt] = __builtin_amdgcn_mfma_f32_16x16x32_bf16(A[rt], B, acc[rt], 0, 0, 0);
    }

    const int n = wv * 16 + lr;
    const float bb = blin[n];
#pragma unroll
    for (int rt = 0; rt < 4; ++rt) {
#pragma unroll
        for (int r = 0; r < 4; ++r) {
            const int m = row0 + rt * 16 + lg * 4 + r;
            if (m < N) out[(long)m * 128 + n] = acc[rt][r] + bb;
        }
    }
}

// ---------------------------------------------------------------------------
// Gather (packed): one wave per dst node; lane owns channels (2L, 2L+1).
// Per edge per lane: ONE ushort4 load = {q0,v0,q1,v1} bf16. 8-edge unroll.
// ---------------------------------------------------------------------------
__global__ __launch_bounds__(256) void gather_packed_kernel(
    const int* __restrict__ off, const int* __restrict__ deg,
    const int* __restrict__ ssrc,
    const float* __restrict__ kbuf, const unsigned short* __restrict__ qvpk,
    float* __restrict__ agg, int N)
{
    const int n = blockIdx.x * 4 + (threadIdx.x >> 6);
    if (n >= N) return;
    const int lane = threadIdx.x & 63;

    const int dg = deg[n];
    if (dg == 0) return;
    const int s0 = off[n];
    const int s1 = s0 + dg;

    const float2 k2 = *reinterpret_cast<const float2*>(&kbuf[(long)n * 128 + lane * 2]);
    float a0 = 0.f, a1 = 0.f, b0 = 0.f, b1 = 0.f;

    int e = s0;
    for (; e + 8 <= s1; e += 8) {
        int s[8];
#pragma unroll
        for (int j = 0; j < 8; ++j) s[j] = ssrc[e + j];
        ushort4 u[8];
#pragma unroll
        for (int j = 0; j < 8; ++j)
            u[j] = *reinterpret_cast<const ushort4*>(&qvpk[(long)s[j] * 256 + lane * 4]);
#pragma unroll
        for (int j = 0; j < 8; ++j) {
            const float q0 = bf2f(u[j].x), v0 = bf2f(u[j].y);
            const float q1 = bf2f(u[j].z), v1 = bf2f(u[j].w);
            if (j & 1) {
                b0 = fmaf(fmaxf(k2.x + q0, 0.f), v0, b0);
                b1 = fmaf(fmaxf(k2.y + q1, 0.f), v1, b1);
            } else {
                a0 = fmaf(fmaxf(k2.x + q0, 0.f), v0, a0);
                a1 = fmaf(fmaxf(k2.y + q1, 0.f), v1, a1);
            }
        }
    }
    for (; e < s1; ++e) {
        const int s = ssrc[e];
        const ushort4 u = *reinterpret_cast<const ushort4*>(&qvpk[(long)s * 256 + lane * 4]);
        a0 = fmaf(fmaxf(k2.x + bf2f(u.x), 0.f), bf2f(u.y), a0);
        a1 = fmaf(fmaxf(k2.y + bf2f(u.z), 0.f), bf2f(u.w), a1);
    }

    float2* ap = reinterpret_cast<float2*>(&agg[(long)n * 128 + lane * 2]);
    const float2 old = *ap;
    *ap = make_float2(old.x + a0 + b0, old.y + a1 + b1);
}

// ---------------------------------------------------------------------------
// VALU proj kernel — fallback branches only (old split q/v layout).
// ---------------------------------------------------------------------------
template <typename T>
__global__ __launch_bounds__(256) void proj_kernel(
    const float* __restrict__ x,
    const float* __restrict__ Wk, const float* __restrict__ bk,
    const float* __restrict__ Wq, const float* __restrict__ bq,
    const float* __restrict__ Wv, const float* __restrict__ bv,
    const float* __restrict__ Ws,
    T* __restrict__ kbuf, T* __restrict__ qvbuf, float* __restrict__ agg,
    int N)
{
    __shared__ float xt[32][DD];
    const int row0 = blockIdx.x * 32;
    const int t = threadIdx.x;

    for (int i = t; i < 32 * (DD / 4); i += 256) {
        const int r  = i >> 5;
        const int c4 = (i & 31) << 2;
        const int gr = row0 + r;
        float4 v = make_float4(0.f, 0.f, 0.f, 0.f);
        if (gr < N) v = *reinterpret_cast<const float4*>(&x[(long)gr * DD + c4]);
        *reinterpret_cast<float4*>(&xt[r][c4]) = v;
    }
    __syncthreads();

    const int c0 = t & 127;
    const int hi = t >> 7;
    const float* __restrict__ W0 = hi ? Wq : Wk;
    const float* __restrict__ W1 = hi ? Ws : Wv;
    const float b0 = hi ? bq[c0] : bk[c0];
    const float b1 = hi ? 0.f    : bv[c0];

    float acc0[32], acc1[32];
#pragma unroll
    for (int r = 0; r < 32; ++r) { acc0[r] = 0.f; acc1[r] = 0.f; }

    for (int k4 = 0; k4 < DD; k4 += 4) {
        const float w00 = W0[(k4 + 0) * DD + c0];
        const float w01 = W0[(k4 + 1) * DD + c0];
        const float w02 = W0[(k4 + 2) * DD + c0];
        const float w03 = W0[(k4 + 3) * DD + c0];
        const float w10 = W1[(k4 + 0) * DD + c0];
        const float w11 = W1[(k4 + 1) * DD + c0];
        const float w12 = W1[(k4 + 2) * DD + c0];
        const float w13 = W1[(k4 + 3) * DD + c0];
#pragma unroll
        for (int r = 0; r < 32; ++r) {
            const float4 xv = *reinterpret_cast<const float4*>(&xt[r][k4]);
            acc0[r] = fmaf(xv.x, w00, fmaf(xv.y, w01, fmaf(xv.z, w02, fmaf(xv.w, w03, acc0[r]))));
            acc1[r] = fmaf(xv.x, w10, fmaf(xv.y, w11, fmaf(xv.z, w12, fmaf(xv.w, w13, acc1[r]))));
        }
    }

#pragma unroll
    for (int r = 0; r < 32; ++r) {
        const long gr = row0 + r;
        if (gr < N) {
            if (hi == 0) {
                kbuf [gr * 128 + c0]       = cvt<T>(acc0[r] + b0);
                qvbuf[gr * 256 + 128 + c0] = cvt<T>(acc1[r] + b1);
            } else {
                qvbuf[gr * 256 + c0]       = cvt<T>(acc0[r] + b0);
                agg  [gr * 128 + c0]       = acc1[r];
            }
        }
    }
}

// ---------------------------------------------------------------------------
// CSR construction: zero -> histogram -> 3-phase multi-block scan -> scatter
// ---------------------------------------------------------------------------
__global__ __launch_bounds__(256) void zero_kernel(int* __restrict__ p, int n) {
    const int i = blockIdx.x * 256 + threadIdx.x;
    if (i < n) p[i] = 0;
}

__global__ __launch_bounds__(256) void hist_kernel(
    const int* __restrict__ ei, int* __restrict__ deg, int E)
{
    const int e = blockIdx.x * 256 + threadIdx.x;
    if (e < E) atomicAdd(&deg[ei[E + e]], 1);   // dst
}

__global__ __launch_bounds__(1024) void scanA_kernel(
    const int* __restrict__ deg, int* __restrict__ off,
    int* __restrict__ bsum, int N)
{
    __shared__ int sm[1024];
    const int t = threadIdx.x;
    const int i = blockIdx.x * 1024 + t;
    const int v = (i < N) ? deg[i] : 0;
    int x = v;
    sm[t] = x;
    __syncthreads();
#pragma unroll
    for (int ofs = 1; ofs < 1024; ofs <<= 1) {
        const int y = (t >= ofs) ? sm[t - ofs] : 0;
        __syncthreads();
        x += y;
        sm[t] = x;
        __syncthreads();
    }
    if (i < N) off[i] = x - v;
    if (t == 1023) bsum[blockIdx.x] = x;
}

__global__ __launch_bounds__(1024) void scanB_kernel(int* __restrict__ bsum, int nb)
{
    __shared__ int sm[1024];
    const int t = threadIdx.x;
    const int v = (t < nb) ? bsum[t] : 0;
    int x = v;
    sm[t] = x;
    __syncthreads();
#pragma unroll
    for (int ofs = 1; ofs < 1024; ofs <<= 1) {
        const int y = (t >= ofs) ? sm[t - ofs] : 0;
        __syncthreads();
        x += y;
        sm[t] = x;
        __syncthreads();
    }
    if (t < nb) bsum[t] = x - v;
}

__global__ __launch_bounds__(256) void scanC_kernel(
    int* __restrict__ off, int* __restrict__ cursor,
    const int* __restrict__ bsum, int N)
{
    const int i = blockIdx.x * 256 + threadIdx.x;
    if (i < N) {
        const int o = off[i] + bsum[i >> 10];
        off[i]    = o;
        cursor[i] = o;
    }
}

__global__ __launch_bounds__(256) void scatter_kernel(
    const int* __restrict__ ei, int* __restrict__ cursor,
    int* __restrict__ ssrc, int E)
{
    const int e = blockIdx.x * 256 + threadIdx.x;
    if (e >= E) return;
    const int s = ei[e];
    const int d = ei[E + e];
    const int pos = atomicAdd(&cursor[d], 1);
    ssrc[pos] = s;
}

// ---------------------------------------------------------------------------
// Old-layout gather — fallback branches only.
// ---------------------------------------------------------------------------
template <typename T>
__global__ __launch_bounds__(256) void gather_kernel(
    const int* __restrict__ off, const int* __restrict__ deg,
    const int* __restrict__ ssrc,
    const T* __restrict__ kbuf, const T* __restrict__ qvbuf,
    float* __restrict__ agg, int N)
{
    const int n = blockIdx.x * 4 + (threadIdx.x >> 6);
    if (n >= N) return;
    const int lane = threadIdx.x & 63;
    const int c = lane << 1;

    const int dg = deg[n];
    if (dg == 0) return;
    const int s0 = off[n];
    const int s1 = s0 + dg;

    const float2 k2 = ld2<T>(&kbuf[(long)n * 128 + c]);
    float a0 = 0.f, a1 = 0.f, b0 = 0.f, b1 = 0.f;

    int e = s0;
    for (; e + 4 <= s1; e += 4) {
        const long sa = ssrc[e + 0];
        const long sb = ssrc[e + 1];
        const long sc = ssrc[e + 2];
        const long sd = ssrc[e + 3];
        const float2 qa = ld2<T>(&qvbuf[sa * 256 + c]);
        const float2 va = ld2<T>(&qvbuf[sa * 256 + 128 + c]);
        const float2 qb = ld2<T>(&qvbuf[sb * 256 + c]);
        const float2 vb = ld2<T>(&qvbuf[sb * 256 + 128 + c]);
        const float2 qc = ld2<T>(&qvbuf[sc * 256 + c]);
        const float2 vc = ld2<T>(&qvbuf[sc * 256 + 128 + c]);
        const float2 qd = ld2<T>(&qvbuf[sd * 256 + c]);
        const float2 vd = ld2<T>(&qvbuf[sd * 256 + 128 + c]);
        a0 = fmaf(fmaxf(k2.x + qa.x, 0.f), va.x, a0);
        a1 = fmaf(fmaxf(k2.y + qa.y, 0.f), va.y, a1);
        b0 = fmaf(fmaxf(k2.x + qb.x, 0.f), vb.x, b0);
        b1 = fmaf(fmaxf(k2.y + qb.y, 0.f), vb.y, b1);
        a0 = fmaf(fmaxf(k2.x + qc.x, 0.f), vc.x, a0);
        a1 = fmaf(fmaxf(k2.y + qc.y, 0.f), vc.y, a1);
        b0 = fmaf(fmaxf(k2.x + qd.x, 0.f), vd.x, b0);
        b1 = fmaf(fmaxf(k2.y + qd.y, 0.f), vd.y, b1);
    }
    for (; e < s1; ++e) {
        const long s = ssrc[e];
        const float2 q = ld2<T>(&qvbuf[s * 256 + c]);
        const float2 v = ld2<T>(&qvbuf[s * 256 + 128 + c]);
        a0 = fmaf(fmaxf(k2.x + q.x, 0.f), v.x, a0);
        a1 = fmaf(fmaxf(k2.y + q.y, 0.f), v.y, a1);
    }

    float2* ap = reinterpret_cast<float2*>(&agg[(long)n * 128 + c]);
    const float2 old = *ap;
    *ap = make_float2(old.x + a0 + b0, old.y + a1 + b1);
}

// ---------------------------------------------------------------------------
// Fallback edge kernel (atomic path) — only if ws can't fit CSR.
// ---------------------------------------------------------------------------
template <typename T>
__global__ __launch_bounds__(256) void edge_kernel(
    const int* __restrict__ ei,
    const T* __restrict__ kbuf, const T* __restrict__ qvbuf,
    float* __restrict__ agg, int E)
{
    const int g = (blockIdx.x << 3) + (threadIdx.x >> 5);
    if (g >= E) return;
    const int lane = threadIdx.x & 31;
    const long src = (long)ei[g];
    const long dst = (long)ei[E + g];
    const int c = lane << 2;

    float kd[4], qs[4], vs[4];
    if constexpr (sizeof(T) == 4) {
        const float4 a = *reinterpret_cast<const float4*>(&kbuf[dst * 128 + c]);
        const float4 b = *reinterpret_cast<const float4*>(&qvbuf[src * 256 + c]);
        const float4 d = *reinterpret_cast<const float4*>(&qvbuf[src * 256 + 128 + c]);
        kd[0] = a.x; kd[1] = a.y; kd[2] = a.z; kd[3] = a.w;
        qs[0] = b.x; qs[1] = b.y; qs[2] = b.z; qs[3] = b.w;
        vs[0] = d.x; vs[1] = d.y; vs[2] = d.z; vs[3] = d.w;
    } else {
        const ushort4 a = *reinterpret_cast<const ushort4*>(&kbuf[dst * 128 + c]);
        const ushort4 b = *reinterpret_cast<const ushort4*>(&qvbuf[src * 256 + c]);
        const ushort4 d = *reinterpret_cast<const ushort4*>(&qvbuf[src * 256 + 128 + c]);
        kd[0] = bf2f(a.x); kd[1] = bf2f(a.y); kd[2] = bf2f(a.z); kd[3] = bf2f(a.w);
        qs[0] = bf2f(b.x); qs[1] = bf2f(b.y); qs[2] = bf2f(b.z); qs[3] = bf2f(b.w);
        vs[0] = bf2f(d.x); vs[1] = bf2f(d.y); vs[2] = bf2f(d.z); vs[3] = bf2f(d.w);
    }

    float* p = agg + dst * 128 + c;
#pragma unroll
    for (int j = 0; j < 4; ++j) {
        const float m = fmaxf(kd[j] + qs[j], 0.f) * vs[j];
        unsafeAtomicAdd(p + j, m);
    }
}

// ---------------------------------------------------------------------------
// VALU out kernel — fallback branches only.
// ---------------------------------------------------------------------------
__global__ __launch_bounds__(64) void out_kernel(
    const float* agg, const float* __restrict__ bconv,
    const float* __restrict__ Wlin, const float* __restrict__ blin,
    float* out, int N)
{
    __shared__ float xt[32][DD];
    const int row0 = blockIdx.x * 32;
    const int t = threadIdx.x;

    for (int i = t; i < 32 * (DD / 4); i += 64) {
        const int r  = i >> 5;
        const int c4 = (i & 31) << 2;
        const int gr = row0 + r;
        float4 a = make_float4(0.f, 0.f, 0.f, 0.f);
        if (gr < N) a = *reinterpret_cast<const float4*>(&agg[(long)gr * DD + c4]);
        const float4 b = *reinterpret_cast<const float4*>(&bconv[c4]);
        float4 v;
        const float x0 = a.x + b.x; v.x = x0 >= 0.f ? x0 : 0.01f * x0;
        const float x1 = a.y + b.y; v.y = x1 >= 0.f ? x1 : 0.01f * x1;
        const float x2 = a.z + b.z; v.z = x2 >= 0.f ? x2 : 0.01f * x2;
        const float x3 = a.w + b.w; v.w = x3 >= 0.f ? x3 : 0.01f * x3;
        *reinterpret_cast<float4*>(&xt[r][c4]) = v;
    }
    __syncthreads();

    const int c0 = t;
    const int c1 = t + 64;
    float acc0[32], acc1[32];
#pragma unroll
    for (int r = 0; r < 32; ++r) { acc0[r] = 0.f; acc1[r] = 0.f; }

    for (int k4 = 0; k4 < DD; k4 += 4) {
        const float w00 = Wlin[(k4 + 0) * DD + c0];
        const float w01 = Wlin[(k4 + 1) * DD + c0];
        const float w02 = Wlin[(k4 + 2) * DD + c0];
        const float w03 = Wlin[(k4 + 3) * DD + c0];
        const float w10 = Wlin[(k4 + 0) * DD + c1];
        const float w11 = Wlin[(k4 + 1) * DD + c1];
        const float w12 = Wlin[(k4 + 2) * DD + c1];
        const float w13 = Wlin[(k4 + 3) * DD + c1];
#pragma unroll
        for (int r = 0; r < 32; ++r) {
            const float4 xv = *reinterpret_cast<const float4*>(&xt[r][k4]);
            acc0[r] = fmaf(xv.x, w00, fmaf(xv.y, w01, fmaf(xv.z, w02, fmaf(xv.w, w03, acc0[r]))));
            acc1[r] = fmaf(xv.x, w10, fmaf(xv.y, w11, fmaf(xv.z, w12, fmaf(xv.w, w13, acc1[r]))));
        }
    }

    const float bb0 = blin[c0];
    const float bb1 = blin[c1];
#pragma unroll
    for (int r = 0; r < 32; ++r) {
        const long gr = row0 + r;
        if (gr < N) {
            out[gr * DD + c0] = acc0[r] + bb0;
            out[gr * DD + c1] = acc1[r] + bb1;
        }
    }
}

// ---------------------------------------------------------------------------
extern "C" void kernel_launch(void* const* d_in, const int* in_sizes, int n_in,
                              void* d_out, int out_size, void* d_ws, size_t ws_size,
                              hipStream_t stream)
{
    const float* x     = (const float*)d_in[0];
    const int*   ei    = (const int*)d_in[1];      // int32 (harness converts int64 -> int32)
    const float* Wk    = (const float*)d_in[2];
    const float* bk    = (const float*)d_in[3];
    const float* Wq    = (const float*)d_in[4];
    const float* bq    = (const float*)d_in[5];
    const float* Wv    = (const float*)d_in[6];
    const float* bv    = (const float*)d_in[7];
    const float* Ws    = (const float*)d_in[8];
    const float* bconv = (const float*)d_in[9];
    const float* Wlin  = (const float*)d_in[10];
    const float* blin  = (const float*)d_in[11];

    const int N = in_sizes[0] / DD;
    const int E = in_sizes[1] / 2;

    float* aggf = (float*)d_out;                 // agg lives in d_out
    const int nblk   = (N + 31) / 32;
    const int mblk   = (N + 63) / 64;            // MFMA kernels: 64 rows/block
    const int eblk1  = (E + 255) / 256;
    const int nblk1  = (N + 255) / 256;
    const int gblk   = (N + 3) / 4;
    const int nchunks = (N + 1023) / 1024;

    const int bsum_pad = (nchunks + 255) & ~255;
    size_t csr_ints = (size_t)3 * N + bsum_pad + E;
    csr_ints = (csr_ints + 3) & ~(size_t)3;
    const size_t csr_bytes = csr_ints * sizeof(int);

    const size_t projPK   = (size_t)N * (128 * sizeof(float) + 256 * sizeof(unsigned short)); // k fp32 + qv packed bf16
    const size_t projF32  = (size_t)N * 384 * sizeof(float);
    const size_t projBF16 = (size_t)N * 384 * sizeof(unsigned short);
    const size_t wsplit   = (size_t)5 * 2048 * 8 * sizeof(unsigned short); // 160KB

    if (ws_size >= csr_bytes + projPK + wsplit) {
        // ---- MFMA + packed-bf16-gather fast path ----
        int* deg    = (int*)d_ws;
        int* off    = deg + N;
        int* cursor = off + N;
        int* bsum   = cursor + N;
        int* ssrc   = bsum + bsum_pad;
        float* kbuf = (float*)((char*)d_ws + csr_bytes);
        unsigned short* qvpk = (unsigned short*)(kbuf + (size_t)N * 128);
        unsigned short* whi  = qvpk + (size_t)N * 256;

        split_w_kernel<<<40, 256, 0, stream>>>(Wk, Wq, Wv, Ws, Wlin, whi);
        proj_mfma_kernel<<<mblk, 512, 0, stream>>>(x, whi, bk, bq, bv,
                                                   kbuf, qvpk, aggf, deg, N);
        hist_kernel<<<eblk1, 256, 0, stream>>>(ei, deg, E);
        scanA_kernel<<<nchunks, 1024, 0, stream>>>(deg, off, bsum, N);
        scanB_kernel<<<1, 1024, 0, stream>>>(bsum, nchunks);
        scanC_kernel<<<nblk1, 256, 0, stream>>>(off, cursor, bsum, N);
        scatter_kernel<<<eblk1, 256, 0, stream>>>(ei, cursor, ssrc, E);
        gather_packed_kernel<<<gblk, 256, 0, stream>>>(off, deg, ssrc, kbuf, qvpk, aggf, N);
        out_mfma_kernel<<<mblk, 512, 0, stream>>>(aggf, bconv, whi, blin, (float*)d_out, N);
    } else if (ws_size >= csr_bytes + projF32) {
        // ---- round-5 proven VALU path ----
        int* deg    = (int*)d_ws;
        int* off    = deg + N;
        int* cursor = off + N;
        int* bsum   = cursor + N;
        int* ssrc   = bsum + bsum_pad;
        float* kbuf  = (float*)((char*)d_ws + csr_bytes);
        float* qvbuf = kbuf + (size_t)N * 128;

        proj_kernel<float><<<nblk, 256, 0, stream>>>(x, Wk, bk, Wq, bq, Wv, bv, Ws,
                                                     kbuf, qvbuf, aggf, N);
        zero_kernel<<<nblk1, 256, 0, stream>>>(deg, N);
        hist_kernel<<<eblk1, 256, 0, stream>>>(ei, deg, E);
        scanA_kernel<<<nchunks, 1024, 0, stream>>>(deg, off, bsum, N);
        scanB_kernel<<<1, 1024, 0, stream>>>(bsum, nchunks);
        scanC_kernel<<<nblk1, 256, 0, stream>>>(off, cursor, bsum, N);
        scatter_kernel<<<eblk1, 256, 0, stream>>>(ei, cursor, ssrc, E);
        gather_kernel<float><<<gblk, 256, 0, stream>>>(off, deg, ssrc, kbuf, qvbuf, aggf, N);
        out_kernel<<<nblk, 64, 0, stream>>>(aggf, bconv, Wlin, blin, (float*)d_out, N);
    } else if (ws_size >= csr_bytes + projBF16) {
        int* deg    = (int*)d_ws;
        int* off    = deg + N;
        int* cursor = off + N;
        int* bsum   = cursor + N;
        int* ssrc   = bsum + bsum_pad;
        unsigned short* kbuf  = (unsigned short*)((char*)d_ws + csr_bytes);
        unsigned short* qvbuf = kbuf + (size_t)N * 128;

        proj_kernel<unsigned short><<<nblk, 256, 0, stream>>>(x, Wk, bk, Wq, bq, Wv, bv, Ws,
                                                              kbuf, qvbuf, aggf, N);
        zero_kernel<<<nblk1, 256, 0, stream>>>(deg, N);
        hist_kernel<<<eblk1, 256, 0, stream>>>(ei, deg, E);
        scanA_kernel<<<nchunks, 1024, 0, stream>>>(deg, off, bsum, N);
        scanB_kernel<<<1, 1024, 0, stream>>>(bsum, nchunks);
        scanC_kernel<<<nblk1, 256, 0, stream>>>(off, cursor, bsum, N);
        scatter_kernel<<<eblk1, 256, 0, stream>>>(ei, cursor, ssrc, E);
        gather_kernel<unsigned short><<<gblk, 256, 0, stream>>>(off, deg, ssrc, kbuf, qvbuf, aggf, N);
        out_kernel<<<nblk, 64, 0, stream>>>(aggf, bconv, Wlin, blin, (float*)d_out, N);
    } else if (ws_size >= projBF16) {
        unsigned short* kbuf  = (unsigned short*)d_ws;
        unsigned short* qvbuf = kbuf + (size_t)N * 128;
        const int eblk8 = (E + 7) / 8;
        proj_kernel<unsigned short><<<nblk, 256, 0, stream>>>(x, Wk, bk, Wq, bq, Wv, bv, Ws,
                                                              kbuf, qvbuf, aggf, N);
        edge_kernel<unsigned short><<<eblk8, 256, 0, stream>>>(ei, kbuf, qvbuf, aggf, E);
        out_kernel<<<nblk, 64, 0, stream>>>(aggf, bconv, Wlin, blin, (float*)d_out, N);
    } else {
        hipMemsetAsync(d_out, 0, (size_t)out_size * sizeof(float), stream);
        return;
    }
}

// Round 11
// 228.964 us; speedup vs baseline: 6.7324x; 1.0029x over previous
//
#include <hip/hip_runtime.h>

#define DD 128

typedef __attribute__((ext_vector_type(8))) short bf16x8;
typedef __attribute__((ext_vector_type(4))) float f32x4;

// ---- bf16 helpers (RNE) ----------------------------------------------------
__device__ inline unsigned short f2bf(float f) {
    unsigned int u = __float_as_uint(f);
    u += 0x7FFFu + ((u >> 16) & 1u);
    return (unsigned short)(u >> 16);
}
__device__ inline float bf2f(unsigned short s) {
    return __uint_as_float(((unsigned int)s) << 16);
}

template <typename T> __device__ inline T cvt(float f);
template <> __device__ inline float cvt<float>(float f) { return f; }
template <> __device__ inline unsigned short cvt<unsigned short>(float f) { return f2bf(f); }

template <typename T> __device__ inline float2 ld2(const T* p);
template <> __device__ inline float2 ld2<float>(const float* p) {
    return *reinterpret_cast<const float2*>(p);
}
template <> __device__ inline float2 ld2<unsigned short>(const unsigned short* p) {
    const ushort2 u = *reinterpret_cast<const ushort2*>(p);
    return make_float2(bf2f(u.x), bf2f(u.y));
}

// ---------------------------------------------------------------------------
// Plain-bf16 MFMA GEMM. Fragment layouts validated end-to-end rounds 6-10.
// Round 11: launch-chain compression (9 -> 6 kernels): zero fused into
// split_w, hist fused into proj as tail blocks, scanA+scanB fused via
// last-block pattern, scanC eliminated (off = local + bsum[chunk] at use).
// ---------------------------------------------------------------------------

// One-shot: weights -> bf16 B-fragment layout; also zeroes deg/cnt2/done.
__global__ __launch_bounds__(256) void split_w_kernel(
    const float* __restrict__ W0, const float* __restrict__ W1,
    const float* __restrict__ W2, const float* __restrict__ W3,
    const float* __restrict__ W4,
    unsigned short* __restrict__ whi,
    int* __restrict__ deg, int* __restrict__ cnt2, int* __restrict__ done,
    int N)
{
    const int gid = blockIdx.x * 256 + threadIdx.x;
    if (gid < N) { deg[gid] = 0; cnt2[gid] = 0; }
    if (gid == 0) *done = 0;

    const int idx = gid;                              // 5 * 2048 frags
    if (idx >= 5 * 2048) return;
    const int mat  = idx >> 11;
    const int rem  = idx & 2047;
    const int ks   = rem >> 9;
    const int nt   = (rem >> 6) & 7;
    const int lane = rem & 63;
    const int lr = lane & 15, lg = lane >> 4;
    const float* __restrict__ W = mat == 0 ? W0 : mat == 1 ? W1 : mat == 2 ? W2
                                 : mat == 3 ? W3 : W4;
    const int n = nt * 16 + lr;
    bf16x8 h8;
#pragma unroll
    for (int r = 0; r < 8; ++r) {
        const int k = ks * 32 + lg * 8 + r;
        h8[r] = (short)f2bf(W[k * DD + n]);
    }
    *reinterpret_cast<bf16x8*>(&whi[(long)idx * 8]) = h8;
}

// Stage 64 rows x 128 cols of fp32 A as bf16 fragments in LDS (512 threads).
template <bool XFORM>
__device__ inline void stage_rows512(const float* __restrict__ src,
                                     const float* __restrict__ addv,
                                     int row0, int N, int t,
                                     unsigned short* __restrict__ ldsA)
{
    const int m  = t >> 3;            // 0..63 local row
    const int gr = row0 + m;
#pragma unroll
    for (int j = 0; j < 2; ++j) {
        const int o = (t & 7) + j * 8;   // k-octet 0..15
        float v[8];
        if (gr < N) {
            const float4 a = *reinterpret_cast<const float4*>(&src[(long)gr * DD + o * 8]);
            const float4 b = *reinterpret_cast<const float4*>(&src[(long)gr * DD + o * 8 + 4]);
            v[0] = a.x; v[1] = a.y; v[2] = a.z; v[3] = a.w;
            v[4] = b.x; v[5] = b.y; v[6] = b.z; v[7] = b.w;
        } else {
#pragma unroll
            for (int e = 0; e < 8; ++e) v[e] = 0.f;
        }
        if (XFORM) {   // leaky_relu(src + addv) fused into staging
#pragma unroll
            for (int e = 0; e < 8; ++e) {
                const float s = v[e] + addv[o * 8 + e];
                v[e] = s >= 0.f ? s : 0.01f * s;
            }
        }
        bf16x8 h8;
#pragma unroll
        for (int e = 0; e < 8; ++e) h8[e] = (short)f2bf(v[e]);
        const int rt   = m >> 4;
        const int ks   = o >> 2;
        const int lane = (m & 15) + (o & 3) * 16;
        const int base = ((rt * 4 + ks) * 64 + lane) * 8;
        *reinterpret_cast<bf16x8*>(&ldsA[base]) = h8;
    }
}

// ---------------------------------------------------------------------------
// Kernel (MFMA, 512 thr / 8 waves): fused node projections + histogram tail.
// Blocks [0, projBlocks): proj. Wave wv: mat = wv>>1 (0=K fp32, 1=Q, 2=V bf16
// packed, 3=Skip), cc = wv&1 (64-col half).
// Blocks [projBlocks, ...): histogram of dst into deg (deg pre-zeroed).
// ---------------------------------------------------------------------------
__global__ __launch_bounds__(512) void proj_mfma_kernel(
    const float* __restrict__ x,
    const unsigned short* __restrict__ whi,
    const float* __restrict__ bk, const float* __restrict__ bq,
    const float* __restrict__ bv,
    float* __restrict__ kbuf, unsigned short* __restrict__ qvpk,
    float* __restrict__ agg,
    const int* __restrict__ ei, int* __restrict__ deg,
    int projBlocks, int E, int N)
{
    __shared__ unsigned short ldsA[16 * 64 * 8];
    const int t = threadIdx.x;

    if (blockIdx.x >= projBlocks) {               // histogram role
        const int e = (blockIdx.x - projBlocks) * 512 + t;
        if (e < E) atomicAdd(&deg[ei[E + e]], 1);
        return;
    }

    const int row0 = blockIdx.x * 64;
    stage_rows512<false>(x, nullptr, row0, N, t, ldsA);
    __syncthreads();

    const int wv   = t >> 6;
    const int mat  = wv >> 1;
    const int cc   = wv & 1;
    const int lane = t & 63;
    const int lr = lane & 15;
    const int lg = lane >> 4;
    const float* bias = (mat == 0) ? bk : (mat == 1) ? bq : (mat == 2) ? bv : nullptr;

    f32x4 acc[4][4];
#pragma unroll
    for (int rt = 0; rt < 4; ++rt)
#pragma unroll
        for (int ct = 0; ct < 4; ++ct) acc[rt][ct] = (f32x4){0.f, 0.f, 0.f, 0.f};

#pragma unroll
    for (int ks = 0; ks < 4; ++ks) {
        bf16x8 A[4];
#pragma unroll
        for (int rt = 0; rt < 4; ++rt)
            A[rt] = *reinterpret_cast<const bf16x8*>(&ldsA[((rt * 4 + ks) * 64 + lane) * 8]);
#pragma unroll
        for (int ct = 0; ct < 4; ++ct) {
            const long fb = ((long)((mat * 4 + ks) * 8 + (cc * 4 + ct)) * 64 + lane) * 8;
            const bf16x8 B = *reinterpret_cast<const bf16x8*>(&whi[fb]);
#pragma unroll
            for (int rt = 0; rt < 4; ++rt)
                acc[rt][ct] = __builtin_amdgcn_mfma_f32_16x16x32_bf16(A[rt], B, acc[rt][ct], 0, 0, 0);
        }
    }

#pragma unroll
    for (int ct = 0; ct < 4; ++ct) {
        const int n_l = cc * 64 + ct * 16 + lr;
        const float bv_ = bias ? bias[n_l] : 0.f;
#pragma unroll
        for (int rt = 0; rt < 4; ++rt) {
#pragma unroll
            for (int r = 0; r < 4; ++r) {
                const int m = row0 + rt * 16 + lg * 4 + r;
                if (m < N) {
                    const float val = acc[rt][ct][r] + bv_;
                    if      (mat == 0) kbuf [(long)m * 128 + n_l]         = val;
                    else if (mat == 1) qvpk [(long)m * 256 + 2 * n_l]     = f2bf(val);
                    else if (mat == 2) qvpk [(long)m * 256 + 2 * n_l + 1] = f2bf(val);
                    else               agg  [(long)m * 128 + n_l]         = val;
                }
            }
        }
    }
}

// ---------------------------------------------------------------------------
// Fused scan: per-chunk exclusive scan (off = chunk-local) + chunk totals in
// bsum; the LAST block (atomic done-counter) exclusive-scans bsum in place.
// Consumers use off[i] + bsum[i>>10]. done pre-zeroed by split_w.
// ---------------------------------------------------------------------------
__global__ __launch_bounds__(1024) void scanAB_kernel(
    const int* __restrict__ deg, int* __restrict__ off,
    int* __restrict__ bsum, int* __restrict__ done, int N, int nb)
{
    __shared__ int sm[1024];
    __shared__ int amLast;
    const int t = threadIdx.x;
    const int i = blockIdx.x * 1024 + t;
    const int v = (i < N) ? deg[i] : 0;
    int x = v;
    sm[t] = x;
    __syncthreads();
#pragma unroll
    for (int ofs = 1; ofs < 1024; ofs <<= 1) {
        const int y = (t >= ofs) ? sm[t - ofs] : 0;
        __syncthreads();
        x += y;
        sm[t] = x;
        __syncthreads();
    }
    if (i < N) off[i] = x - v;
    if (t == 1023) { bsum[blockIdx.x] = x; __threadfence(); }
    __syncthreads();
    if (t == 0) amLast = (atomicAdd(done, 1) == (int)gridDim.x - 1) ? 1 : 0;
    __syncthreads();
    if (!amLast) return;

    // last block: exclusive scan of the nb chunk totals (device-scope reads)
    const int vb = (t < nb) ? atomicAdd(&bsum[t], 0) : 0;
    int xb = vb;
    sm[t] = xb;
    __syncthreads();
#pragma unroll
    for (int ofs = 1; ofs < 1024; ofs <<= 1) {
        const int y = (t >= ofs) ? sm[t - ofs] : 0;
        __syncthreads();
        xb += y;
        sm[t] = xb;
        __syncthreads();
    }
    if (t < nb) bsum[t] = xb - vb;
}

// scatter with on-the-fly global offset: pos = off[d] + bsum[chunk] + cnt2[d]++
__global__ __launch_bounds__(256) void scatter2_kernel(
    const int* __restrict__ ei,
    const int* __restrict__ off, const int* __restrict__ bsum,
    int* __restrict__ cnt2, int* __restrict__ ssrc, int E)
{
    const int e = blockIdx.x * 256 + threadIdx.x;
    if (e >= E) return;
    const int s = ei[e];
    const int d = ei[E + e];
    const int pos = off[d] + bsum[d >> 10] + atomicAdd(&cnt2[d], 1);
    ssrc[pos] = s;
}

// ---------------------------------------------------------------------------
// Kernel (MFMA, 512 thr / 8 waves): out = leaky(agg + b_conv) @ Wlin + blin.
// agg aliases out. Wave wv owns cols [wv*16, wv*16+16).
// ---------------------------------------------------------------------------
__global__ __launch_bounds__(512) void out_mfma_kernel(
    const float* agg, const float* __restrict__ bconv,
    const unsigned short* __restrict__ whi,
    const float* __restrict__ blin,
    float* out, int N)
{
    __shared__ unsigned short ldsA[16 * 64 * 8];
    const int t = threadIdx.x;
    const int row0 = blockIdx.x * 64;

    stage_rows512<true>(agg, bconv, row0, N, t, ldsA);
    __syncthreads();

    const int wv   = t >> 6;
    const int lane = t & 63;
    const int lr = lane & 15;
    const int lg = lane >> 4;

    f32x4 acc[4];
#pragma unroll
    for (int rt = 0; rt < 4; ++rt) acc[rt] = (f32x4){0.f, 0.f, 0.f, 0.f};

#pragma unroll
    for (int ks = 0; ks < 4; ++ks) {
        bf16x8 A[4];
#pragma unroll
        for (int rt = 0; rt < 4; ++rt)
            A[rt] = *reinterpret_cast<const bf16x8*>(&ldsA[((rt * 4 + ks) * 64 + lane) * 8]);
        const long fb = ((long)((16 + ks) * 8 + wv) * 64 + lane) * 8;
        const bf16x8 B = *reinterpret_cast<const bf16x8*>(&whi[fb]);
#pragma unroll
        for (int rt = 0; rt < 4; ++rt)
            acc[rt] = __builtin_amdgcn_mfma_f32_16x16x32_bf16(A[rt], B, acc[rt], 0, 0, 0);
    }

    const int n = wv * 16 + lr;
    const float bb = blin[n];
#pragma unroll
    for (int rt = 0; rt < 4; ++rt) {
#pragma unroll
        for (int r = 0; r < 4; ++r) {
            const int m = row0 + rt * 16 + lg * 4 + r;
            if (m < N) out[(long)m * 128 + n] = acc[rt][r] + bb;
        }
    }
}

// ---------------------------------------------------------------------------
// Gather (packed): one wave per dst node; lane owns channels (2L, 2L+1).
// Per edge per lane: ONE ushort4 load = {q0,v0,q1,v1} bf16. 8-edge unroll.
// ---------------------------------------------------------------------------
__global__ __launch_bounds__(256) void gather_packed_kernel(
    const int* __restrict__ off, const int* __restrict__ bsum,
    const int* __restrict__ deg, const int* __restrict__ ssrc,
    const float* __restrict__ kbuf, const unsigned short* __restrict__ qvpk,
    float* __restrict__ agg, int N)
{
    const int n = blockIdx.x * 4 + (threadIdx.x >> 6);
    if (n >= N) return;
    const int lane = threadIdx.x & 63;

    const int dg = deg[n];
    if (dg == 0) return;
    const int s0 = off[n] + bsum[n >> 10];
    const int s1 = s0 + dg;

    const float2 k2 = *reinterpret_cast<const float2*>(&kbuf[(long)n * 128 + lane * 2]);
    float a0 = 0.f, a1 = 0.f, b0 = 0.f, b1 = 0.f;

    int e = s0;
    for (; e + 8 <= s1; e += 8) {
        int s[8];
#pragma unroll
        for (int j = 0; j < 8; ++j) s[j] = ssrc[e + j];
        ushort4 u[8];
#pragma unroll
        for (int j = 0; j < 8; ++j)
            u[j] = *reinterpret_cast<const ushort4*>(&qvpk[(long)s[j] * 256 + lane * 4]);
#pragma unroll
        for (int j = 0; j < 8; ++j) {
            const float q0 = bf2f(u[j].x), v0 = bf2f(u[j].y);
            const float q1 = bf2f(u[j].z), v1 = bf2f(u[j].w);
            if (j & 1) {
                b0 = fmaf(fmaxf(k2.x + q0, 0.f), v0, b0);
                b1 = fmaf(fmaxf(k2.y + q1, 0.f), v1, b1);
            } else {
                a0 = fmaf(fmaxf(k2.x + q0, 0.f), v0, a0);
                a1 = fmaf(fmaxf(k2.y + q1, 0.f), v1, a1);
            }
        }
    }
    for (; e < s1; ++e) {
        const int s = ssrc[e];
        const ushort4 u = *reinterpret_cast<const ushort4*>(&qvpk[(long)s * 256 + lane * 4]);
        a0 = fmaf(fmaxf(k2.x + bf2f(u.x), 0.f), bf2f(u.y), a0);
        a1 = fmaf(fmaxf(k2.y + bf2f(u.z), 0.f), bf2f(u.w), a1);
    }

    float2* ap = reinterpret_cast<float2*>(&agg[(long)n * 128 + lane * 2]);
    const float2 old = *ap;
    *ap = make_float2(old.x + a0 + b0, old.y + a1 + b1);
}

// ===========================================================================
// Fallback-path kernels (unchanged, proven round-5 structure)
// ===========================================================================
template <typename T>
__global__ __launch_bounds__(256) void proj_kernel(
    const float* __restrict__ x,
    const float* __restrict__ Wk, const float* __restrict__ bk,
    const float* __restrict__ Wq, const float* __restrict__ bq,
    const float* __restrict__ Wv, const float* __restrict__ bv,
    const float* __restrict__ Ws,
    T* __restrict__ kbuf, T* __restrict__ qvbuf, float* __restrict__ agg,
    int N)
{
    __shared__ float xt[32][DD];
    const int row0 = blockIdx.x * 32;
    const int t = threadIdx.x;

    for (int i = t; i < 32 * (DD / 4); i += 256) {
        const int r  = i >> 5;
        const int c4 = (i & 31) << 2;
        const int gr = row0 + r;
        float4 v = make_float4(0.f, 0.f, 0.f, 0.f);
        if (gr < N) v = *reinterpret_cast<const float4*>(&x[(long)gr * DD + c4]);
        *reinterpret_cast<float4*>(&xt[r][c4]) = v;
    }
    __syncthreads();

    const int c0 = t & 127;
    const int hi = t >> 7;
    const float* __restrict__ W0 = hi ? Wq : Wk;
    const float* __restrict__ W1 = hi ? Ws : Wv;
    const float b0 = hi ? bq[c0] : bk[c0];
    const float b1 = hi ? 0.f    : bv[c0];

    float acc0[32], acc1[32];
#pragma unroll
    for (int r = 0; r < 32; ++r) { acc0[r] = 0.f; acc1[r] = 0.f; }

    for (int k4 = 0; k4 < DD; k4 += 4) {
        const float w00 = W0[(k4 + 0) * DD + c0];
        const float w01 = W0[(k4 + 1) * DD + c0];
        const float w02 = W0[(k4 + 2) * DD + c0];
        const float w03 = W0[(k4 + 3) * DD + c0];
        const float w10 = W1[(k4 + 0) * DD + c0];
        const float w11 = W1[(k4 + 1) * DD + c0];
        const float w12 = W1[(k4 + 2) * DD + c0];
        const float w13 = W1[(k4 + 3) * DD + c0];
#pragma unroll
        for (int r = 0; r < 32; ++r) {
            const float4 xv = *reinterpret_cast<const float4*>(&xt[r][k4]);
            acc0[r] = fmaf(xv.x, w00, fmaf(xv.y, w01, fmaf(xv.z, w02, fmaf(xv.w, w03, acc0[r]))));
            acc1[r] = fmaf(xv.x, w10, fmaf(xv.y, w11, fmaf(xv.z, w12, fmaf(xv.w, w13, acc1[r]))));
        }
    }

#pragma unroll
    for (int r = 0; r < 32; ++r) {
        const long gr = row0 + r;
        if (gr < N) {
            if (hi == 0) {
                kbuf [gr * 128 + c0]       = cvt<T>(acc0[r] + b0);
                qvbuf[gr * 256 + 128 + c0] = cvt<T>(acc1[r] + b1);
            } else {
                qvbuf[gr * 256 + c0]       = cvt<T>(acc0[r] + b0);
                agg  [gr * 128 + c0]       = acc1[r];
            }
        }
    }
}

__global__ __launch_bounds__(256) void zero_kernel(int* __restrict__ p, int n) {
    const int i = blockIdx.x * 256 + threadIdx.x;
    if (i < n) p[i] = 0;
}

__global__ __launch_bounds__(256) void hist_kernel(
    const int* __restrict__ ei, int* __restrict__ deg, int E)
{
    const int e = blockIdx.x * 256 + threadIdx.x;
    if (e < E) atomicAdd(&deg[ei[E + e]], 1);
}

__global__ __launch_bounds__(1024) void scanA_kernel(
    const int* __restrict__ deg, int* __restrict__ off,
    int* __restrict__ bsum, int N)
{
    __shared__ int sm[1024];
    const int t = threadIdx.x;
    const int i = blockIdx.x * 1024 + t;
    const int v = (i < N) ? deg[i] : 0;
    int x = v;
    sm[t] = x;
    __syncthreads();
#pragma unroll
    for (int ofs = 1; ofs < 1024; ofs <<= 1) {
        const int y = (t >= ofs) ? sm[t - ofs] : 0;
        __syncthreads();
        x += y;
        sm[t] = x;
        __syncthreads();
    }
    if (i < N) off[i] = x - v;
    if (t == 1023) bsum[blockIdx.x] = x;
}

__global__ __launch_bounds__(1024) void scanB_kernel(int* __restrict__ bsum, int nb)
{
    __shared__ int sm[1024];
    const int t = threadIdx.x;
    const int v = (t < nb) ? bsum[t] : 0;
    int x = v;
    sm[t] = x;
    __syncthreads();
#pragma unroll
    for (int ofs = 1; ofs < 1024; ofs <<= 1) {
        const int y = (t >= ofs) ? sm[t - ofs] : 0;
        __syncthreads();
        x += y;
        sm[t] = x;
        __syncthreads();
    }
    if (t < nb) bsum[t] = x - v;
}

__global__ __launch_bounds__(256) void scanC_kernel(
    int* __restrict__ off, int* __restrict__ cursor,
    const int* __restrict__ bsum, int N)
{
    const int i = blockIdx.x * 256 + threadIdx.x;
    if (i < N) {
        const int o = off[i] + bsum[i >> 10];
        off[i]    = o;
        cursor[i] = o;
    }
}

__global__ __launch_bounds__(256) void scatter_kernel(
    const int* __restrict__ ei, int* __restrict__ cursor,
    int* __restrict__ ssrc, int E)
{
    const int e = blockIdx.x * 256 + threadIdx.x;
    if (e >= E) return;
    const int s = ei[e];
    const int d = ei[E + e];
    const int pos = atomicAdd(&cursor[d], 1);
    ssrc[pos] = s;
}

template <typename T>
__global__ __launch_bounds__(256) void gather_kernel(
    const int* __restrict__ off, const int* __restrict__ deg,
    const int* __restrict__ ssrc,
    const T* __restrict__ kbuf, const T* __restrict__ qvbuf,
    float* __restrict__ agg, int N)
{
    const int n = blockIdx.x * 4 + (threadIdx.x >> 6);
    if (n >= N) return;
    const int lane = threadIdx.x & 63;
    const int c = lane << 1;

    const int dg = deg[n];
    if (dg == 0) return;
    const int s0 = off[n];
    const int s1 = s0 + dg;

    const float2 k2 = ld2<T>(&kbuf[(long)n * 128 + c]);
    float a0 = 0.f, a1 = 0.f, b0 = 0.f, b1 = 0.f;

    int e = s0;
    for (; e + 4 <= s1; e += 4) {
        const long sa = ssrc[e + 0];
        const long sb = ssrc[e + 1];
        const long sc = ssrc[e + 2];
        const long sd = ssrc[e + 3];
        const float2 qa = ld2<T>(&qvbuf[sa * 256 + c]);
        const float2 va = ld2<T>(&qvbuf[sa * 256 + 128 + c]);
        const float2 qb = ld2<T>(&qvbuf[sb * 256 + c]);
        const float2 vb = ld2<T>(&qvbuf[sb * 256 + 128 + c]);
        const float2 qc = ld2<T>(&qvbuf[sc * 256 + c]);
        const float2 vc = ld2<T>(&qvbuf[sc * 256 + 128 + c]);
        const float2 qd = ld2<T>(&qvbuf[sd * 256 + c]);
        const float2 vd = ld2<T>(&qvbuf[sd * 256 + 128 + c]);
        a0 = fmaf(fmaxf(k2.x + qa.x, 0.f), va.x, a0);
        a1 = fmaf(fmaxf(k2.y + qa.y, 0.f), va.y, a1);
        b0 = fmaf(fmaxf(k2.x + qb.x, 0.f), vb.x, b0);
        b1 = fmaf(fmaxf(k2.y + qb.y, 0.f), vb.y, b1);
        a0 = fmaf(fmaxf(k2.x + qc.x, 0.f), vc.x, a0);
        a1 = fmaf(fmaxf(k2.y + qc.y, 0.f), vc.y, a1);
        b0 = fmaf(fmaxf(k2.x + qd.x, 0.f), vd.x, b0);
        b1 = fmaf(fmaxf(k2.y + qd.y, 0.f), vd.y, b1);
    }
    for (; e < s1; ++e) {
        const long s = ssrc[e];
        const float2 q = ld2<T>(&qvbuf[s * 256 + c]);
        const float2 v = ld2<T>(&qvbuf[s * 256 + 128 + c]);
        a0 = fmaf(fmaxf(k2.x + q.x, 0.f), v.x, a0);
        a1 = fmaf(fmaxf(k2.y + q.y, 0.f), v.y, a1);
    }

    float2* ap = reinterpret_cast<float2*>(&agg[(long)n * 128 + c]);
    const float2 old = *ap;
    *ap = make_float2(old.x + a0 + b0, old.y + a1 + b1);
}

template <typename T>
__global__ __launch_bounds__(256) void edge_kernel(
    const int* __restrict__ ei,
    const T* __restrict__ kbuf, const T* __restrict__ qvbuf,
    float* __restrict__ agg, int E)
{
    const int g = (blockIdx.x << 3) + (threadIdx.x >> 5);
    if (g >= E) return;
    const int lane = threadIdx.x & 31;
    const long src = (long)ei[g];
    const long dst = (long)ei[E + g];
    const int c = lane << 2;

    float kd[4], qs[4], vs[4];
    if constexpr (sizeof(T) == 4) {
        const float4 a = *reinterpret_cast<const float4*>(&kbuf[dst * 128 + c]);
        const float4 b = *reinterpret_cast<const float4*>(&qvbuf[src * 256 + c]);
        const float4 d = *reinterpret_cast<const float4*>(&qvbuf[src * 256 + 128 + c]);
        kd[0] = a.x; kd[1] = a.y; kd[2] = a.z; kd[3] = a.w;
        qs[0] = b.x; qs[1] = b.y; qs[2] = b.z; qs[3] = b.w;
        vs[0] = d.x; vs[1] = d.y; vs[2] = d.z; vs[3] = d.w;
    } else {
        const ushort4 a = *reinterpret_cast<const ushort4*>(&kbuf[dst * 128 + c]);
        const ushort4 b = *reinterpret_cast<const ushort4*>(&qvbuf[src * 256 + c]);
        const ushort4 d = *reinterpret_cast<const ushort4*>(&qvbuf[src * 256 + 128 + c]);
        kd[0] = bf2f(a.x); kd[1] = bf2f(a.y); kd[2] = bf2f(a.z); kd[3] = bf2f(a.w);
        qs[0] = bf2f(b.x); qs[1] = bf2f(b.y); qs[2] = bf2f(b.z); qs[3] = bf2f(b.w);
        vs[0] = bf2f(d.x); vs[1] = bf2f(d.y); vs[2] = bf2f(d.z); vs[3] = bf2f(d.w);
    }

    float* p = agg + dst * 128 + c;
#pragma unroll
    for (int j = 0; j < 4; ++j) {
        const float m = fmaxf(kd[j] + qs[j], 0.f) * vs[j];
        unsafeAtomicAdd(p + j, m);
    }
}

__global__ __launch_bounds__(64) void out_kernel(
    const float* agg, const float* __restrict__ bconv,
    const float* __restrict__ Wlin, const float* __restrict__ blin,
    float* out, int N)
{
    __shared__ float xt[32][DD];
    const int row0 = blockIdx.x * 32;
    const int t = threadIdx.x;

    for (int i = t; i < 32 * (DD / 4); i += 64) {
        const int r  = i >> 5;
        const int c4 = (i & 31) << 2;
        const int gr = row0 + r;
        float4 a = make_float4(0.f, 0.f, 0.f, 0.f);
        if (gr < N) a = *reinterpret_cast<const float4*>(&agg[(long)gr * DD + c4]);
        const float4 b = *reinterpret_cast<const float4*>(&bconv[c4]);
        float4 v;
        const float x0 = a.x + b.x; v.x = x0 >= 0.f ? x0 : 0.01f * x0;
        const float x1 = a.y + b.y; v.y = x1 >= 0.f ? x1 : 0.01f * x1;
        const float x2 = a.z + b.z; v.z = x2 >= 0.f ? x2 : 0.01f * x2;
        const float x3 = a.w + b.w; v.w = x3 >= 0.f ? x3 : 0.01f * x3;
        *reinterpret_cast<float4*>(&xt[r][c4]) = v;
    }
    __syncthreads();

    const int c0 = t;
    const int c1 = t + 64;
    float acc0[32], acc1[32];
#pragma unroll
    for (int r = 0; r < 32; ++r) { acc0[r] = 0.f; acc1[r] = 0.f; }

    for (int k4 = 0; k4 < DD; k4 += 4) {
        const float w00 = Wlin[(k4 + 0) * DD + c0];
        const float w01 = Wlin[(k4 + 1) * DD + c0];
        const float w02 = Wlin[(k4 + 2) * DD + c0];
        const float w03 = Wlin[(k4 + 3) * DD + c0];
        const float w10 = Wlin[(k4 + 0) * DD + c1];
        const float w11 = Wlin[(k4 + 1) * DD + c1];
        const float w12 = Wlin[(k4 + 2) * DD + c1];
        const float w13 = Wlin[(k4 + 3) * DD + c1];
#pragma unroll
        for (int r = 0; r < 32; ++r) {
            const float4 xv = *reinterpret_cast<const float4*>(&xt[r][k4]);
            acc0[r] = fmaf(xv.x, w00, fmaf(xv.y, w01, fmaf(xv.z, w02, fmaf(xv.w, w03, acc0[r]))));
            acc1[r] = fmaf(xv.x, w10, fmaf(xv.y, w11, fmaf(xv.z, w12, fmaf(xv.w, w13, acc1[r]))));
        }
    }

    const float bb0 = blin[c0];
    const float bb1 = blin[c1];
#pragma unroll
    for (int r = 0; r < 32; ++r) {
        const long gr = row0 + r;
        if (gr < N) {
            out[gr * DD + c0] = acc0[r] + bb0;
            out[gr * DD + c1] = acc1[r] + bb1;
        }
    }
}

// ---------------------------------------------------------------------------
extern "C" void kernel_launch(void* const* d_in, const int* in_sizes, int n_in,
                              void* d_out, int out_size, void* d_ws, size_t ws_size,
                              hipStream_t stream)
{
    const float* x     = (const float*)d_in[0];
    const int*   ei    = (const int*)d_in[1];      // int32 (harness converts int64 -> int32)
    const float* Wk    = (const float*)d_in[2];
    const float* bk    = (const float*)d_in[3];
    const float* Wq    = (const float*)d_in[4];
    const float* bq    = (const float*)d_in[5];
    const float* Wv    = (const float*)d_in[6];
    const float* bv    = (const float*)d_in[7];
    const float* Ws    = (const float*)d_in[8];
    const float* bconv = (const float*)d_in[9];
    const float* Wlin  = (const float*)d_in[10];
    const float* blin  = (const float*)d_in[11];

    const int N = in_sizes[0] / DD;
    const int E = in_sizes[1] / 2;

    float* aggf = (float*)d_out;                 // agg lives in d_out
    const int nblk    = (N + 31) / 32;
    const int mblk    = (N + 63) / 64;           // MFMA kernels: 64 rows/block
    const int eblk1   = (E + 255) / 256;
    const int nblk1   = (N + 255) / 256;
    const int gblk    = (N + 3) / 4;
    const int nchunks = (N + 1023) / 1024;       // <= 1024
    const int hblk    = (E + 511) / 512;         // hist tail blocks (512 thr)

    const int bsum_pad = (nchunks + 255) & ~255;

    // fast-path CSR layout: deg | off | cnt2 | bsum(bsum_pad) | done(256) | ssrc
    size_t csrF_ints = (size_t)3 * N + bsum_pad + 256 + E;
    csrF_ints = (csrF_ints + 3) & ~(size_t)3;
    const size_t csrF_bytes = csrF_ints * sizeof(int);

    // fallback CSR layout (round-5): deg | off | cursor | bsum | ssrc
    size_t csrO_ints = (size_t)3 * N + bsum_pad + E;
    csrO_ints = (csrO_ints + 3) & ~(size_t)3;
    const size_t csrO_bytes = csrO_ints * sizeof(int);

    const size_t projPK   = (size_t)N * (128 * sizeof(float) + 256 * sizeof(unsigned short));
    const size_t projF32  = (size_t)N * 384 * sizeof(float);
    const size_t projBF16 = (size_t)N * 384 * sizeof(unsigned short);
    const size_t wsplit   = (size_t)5 * 2048 * 8 * sizeof(unsigned short); // 160KB

    if (ws_size >= csrF_bytes + projPK + wsplit) {
        // ---- MFMA + packed-bf16-gather fast path (6 launches) ----
        int* deg  = (int*)d_ws;
        int* off  = deg + N;
        int* cnt2 = off + N;
        int* bsum = cnt2 + N;
        int* done = bsum + bsum_pad;
        int* ssrc = done + 256;
        float* kbuf = (float*)((char*)d_ws + csrF_bytes);
        unsigned short* qvpk = (unsigned short*)(kbuf + (size_t)N * 128);
        unsigned short* whi  = qvpk + (size_t)N * 256;

        const int swblk = (N + 255) / 256;       // covers zeroing and frags
        split_w_kernel<<<swblk, 256, 0, stream>>>(Wk, Wq, Wv, Ws, Wlin, whi,
                                                  deg, cnt2, done, N);
        proj_mfma_kernel<<<mblk + hblk, 512, 0, stream>>>(x, whi, bk, bq, bv,
                                                          kbuf, qvpk, aggf,
                                                          ei, deg, mblk, E, N);
        scanAB_kernel<<<nchunks, 1024, 0, stream>>>(deg, off, bsum, done, N, nchunks);
        scatter2_kernel<<<eblk1, 256, 0, stream>>>(ei, off, bsum, cnt2, ssrc, E);
        gather_packed_kernel<<<gblk, 256, 0, stream>>>(off, bsum, deg, ssrc, kbuf, qvpk, aggf, N);
        out_mfma_kernel<<<mblk, 512, 0, stream>>>(aggf, bconv, whi, blin, (float*)d_out, N);
    } else if (ws_size >= csrO_bytes + projF32) {
        // ---- round-5 proven VALU path ----
        int* deg    = (int*)d_ws;
        int* off    = deg + N;
        int* cursor = off + N;
        int* bsum   = cursor + N;
        int* ssrc   = bsum + bsum_pad;
        float* kbuf  = (float*)((char*)d_ws + csrO_bytes);
        float* qvbuf = kbuf + (size_t)N * 128;

        proj_kernel<float><<<nblk, 256, 0, stream>>>(x, Wk, bk, Wq, bq, Wv, bv, Ws,
                                                     kbuf, qvbuf, aggf, N);
        zero_kernel<<<nblk1, 256, 0, stream>>>(deg, N);
        hist_kernel<<<eblk1, 256, 0, stream>>>(ei, deg, E);
        scanA_kernel<<<nchunks, 1024, 0, stream>>>(deg, off, bsum, N);
        scanB_kernel<<<1, 1024, 0, stream>>>(bsum, nchunks);
        scanC_kernel<<<nblk1, 256, 0, stream>>>(off, cursor, bsum, N);
        scatter_kernel<<<eblk1, 256, 0, stream>>>(ei, cursor, ssrc, E);
        gather_kernel<float><<<gblk, 256, 0, stream>>>(off, deg, ssrc, kbuf, qvbuf, aggf, N);
        out_kernel<<<nblk, 64, 0, stream>>>(aggf, bconv, Wlin, blin, (float*)d_out, N);
    } else if (ws_size >= csrO_bytes + projBF16) {
        int* deg    = (int*)d_ws;
        int* off    = deg + N;
        int* cursor = off + N;
        int* bsum   = cursor + N;
        int* ssrc   = bsum + bsum_pad;
        unsigned short* kbuf  = (unsigned short*)((char*)d_ws + csrO_bytes);
        unsigned short* qvbuf = kbuf + (size_t)N * 128;

        proj_kernel<unsigned short><<<nblk, 256, 0, stream>>>(x, Wk, bk, Wq, bq, Wv, bv, Ws,
                                                              kbuf, qvbuf, aggf, N);
        zero_kernel<<<nblk1, 256, 0, stream>>>(deg, N);
        hist_kernel<<<eblk1, 256, 0, stream>>>(ei, deg, E);
        scanA_kernel<<<nchunks, 1024, 0, stream>>>(deg, off, bsum, N);
        scanB_kernel<<<1, 1024, 0, stream>>>(bsum, nchunks);
        scanC_kernel<<<nblk1, 256, 0, stream>>>(off, cursor, bsum, N);
        scatter_kernel<<<eblk1, 256, 0, stream>>>(ei, cursor, ssrc, E);
        gather_kernel<unsigned short><<<gblk, 256, 0, stream>>>(off, deg, ssrc, kbuf, qvbuf, aggf, N);
        out_kernel<<<nblk, 64, 0, stream>>>(aggf, bconv, Wlin, blin, (float*)d_out, N);
    } else if (ws_size >= projBF16) {
        unsigned short* kbuf  = (unsigned short*)d_ws;
        unsigned short* qvbuf = kbuf + (size_t)N * 128;
        const int eblk8 = (E + 7) / 8;
        proj_kernel<unsigned short><<<nblk, 256, 0, stream>>>(x, Wk, bk, Wq, bq, Wv, bv, Ws,
                                                              kbuf, qvbuf, aggf, N);
        edge_kernel<unsigned short><<<eblk8, 256, 0, stream>>>(ei, kbuf, qvbuf, aggf, E);
        out_kernel<<<nblk, 64, 0, stream>>>(aggf, bconv, Wlin, blin, (float*)d_out, N);
    } else {
        hipMemsetAsync(d_out, 0, (size_t)out_size * sizeof(float), stream);
        return;
    }
}